// Round 9
// baseline (244.854 us; speedup 1.0000x reference)
//
#include <hip/hip_runtime.h>

// Swin cross-attention pipeline v9 for MI355X.
// v8 -> v9: swin_win widened to 512 threads / 8 waves per window (d-split
// 8-way, 32-row slabs). Same 70.6KB LDS => still 2 blocks/CU but 16 waves/CU
// (vs 8), and KV-interleave accumulator pressure halves (64 regs) giving the
// compiler prefetch headroom. Attacks the measured exposed-latency regime
// (v8: MfmaUtil 8.5%, VALUBusy 8.8%, HBM 6%, Occ 15%).
// LDS aliasing unchanged: A = K -> P -> O -> out ; B = Q -> V^T.

using bf16x8 = __attribute__((ext_vector_type(8))) __bf16;
using f32x4  = __attribute__((ext_vector_type(4))) float;
using u16x4  = __attribute__((ext_vector_type(4))) unsigned short;
using u16x8  = __attribute__((ext_vector_type(8))) unsigned short;

__device__ __forceinline__ unsigned short f2bf(float f){
  unsigned int x = __float_as_uint(f);
  x += 0x7FFFu + ((x >> 16) & 1u);          // RNE
  return (unsigned short)(x >> 16);
}
__device__ __forceinline__ float bf2f(unsigned short u){
  return __uint_as_float((unsigned int)u << 16);
}
__device__ __forceinline__ void store_bf4(unsigned short* dst, f32x4 v){
  u16x4 o;
  o[0]=f2bf(v[0]); o[1]=f2bf(v[1]); o[2]=f2bf(v[2]); o[3]=f2bf(v[3]);
  *reinterpret_cast<u16x4*>(dst) = o;
}

#define MFMA16 __builtin_amdgcn_mfma_f32_16x16x32_bf16

__global__ void wcvt_kernel(const float* __restrict__ w1,
                            const float* __restrict__ w2,
                            unsigned short* __restrict__ dst){
  int i = blockIdx.x * 256 + threadIdx.x;
  const float4* src = (i < 262144) ? (reinterpret_cast<const float4*>(w1) + i)
                                   : (reinterpret_cast<const float4*>(w2) + (i - 262144));
  float4 v = *src;
  u16x4 o; o[0]=f2bf(v.x); o[1]=f2bf(v.y); o[2]=f2bf(v.z); o[3]=f2bf(v.w);
  reinterpret_cast<u16x4*>(dst)[i] = o;
}

// ---- transpose fp32 [C,HW] -> bf16 Ft[token][c] -----------------------------
__global__ __launch_bounds__(256, 2) void xpose_kernel(
    const float* __restrict__ g0, const float* __restrict__ g1,
    const float* __restrict__ g2, const float* __restrict__ g3,
    unsigned short* __restrict__ Ft)
{
  __shared__ float T[64][65];
  int bid = blockIdx.x;
  int r; const float* feat; int Hl; size_t tbase;
  if (bid < 4096){ r = bid;        feat = g0; Hl = 128; tbase = 0; }
  else if (bid < 5120){ r = bid - 4096; feat = g1; Hl = 64;  tbase = 65536; }
  else if (bid < 5376){ r = bid - 5120; feat = g2; Hl = 32;  tbase = 81920; }
  else { r = bid - 5376; feat = g3; Hl = 16;  tbase = 86016; }
  size_t HW = (size_t)Hl * Hl;
  int hw64 = (int)(HW >> 6);
  int bat = r / (4 * hw64);
  int r2 = r - bat * 4 * hw64;
  int ct = r2 / hw64, hwt = r2 - ct * hw64;

  const float* src = feat + (size_t)bat * HW * 256 + (size_t)(ct * 64) * HW + (size_t)hwt * 64;
  int tid = threadIdx.x;
  int cq = tid >> 4, hw0 = (tid & 15) * 4;
  #pragma unroll
  for (int p = 0; p < 4; ++p){
    int c = p * 16 + cq;
    const float* sp = src + (size_t)c * HW + hw0;
    float4 v = *reinterpret_cast<const float4*>(sp);
    T[c][hw0] = v.x; T[c][hw0+1] = v.y; T[c][hw0+2] = v.z; T[c][hw0+3] = v.w;
  }
  __syncthreads();
  unsigned short* dst = Ft + (tbase + (size_t)bat * HW + (size_t)hwt * 64) * 256 + ct * 64;
  #pragma unroll
  for (int p = 0; p < 2; ++p){
    int id = p * 256 + tid;
    int t = id >> 3, c0 = (id & 7) * 8;
    u16x8 o;
    #pragma unroll
    for (int j = 0; j < 8; ++j) o[j] = f2bf(T[c0 + j][t]);
    *reinterpret_cast<u16x8*>(dst + (size_t)t * 256 + c0) = o;
  }
}

// ---- transpose back: Gt[token][c] bf16 -> fp32 out [C,HW], ALL 4 batches ----
__global__ __launch_bounds__(256, 2) void untrans_kernel(
    const unsigned short* __restrict__ Gt, float* __restrict__ outb)
{
  __shared__ float T[64][65];
  int bid = blockIdx.x;
  int r; int Hl; size_t tbase, ooff;
  if (bid < 4096){ r = bid;        Hl = 128; tbase = 0;     ooff = 0; }
  else if (bid < 5120){ r = bid - 4096; Hl = 64; tbase = 65536; ooff = 16777216; }
  else if (bid < 5376){ r = bid - 5120; Hl = 32; tbase = 81920; ooff = 20971520; }
  else { r = bid - 5376; Hl = 16; tbase = 86016; ooff = 22020096; }
  size_t HW = (size_t)Hl * Hl;
  int hw64 = (int)(HW >> 6);
  int bat = r / (4 * hw64);
  int r2 = r - bat * 4 * hw64;
  int ct = r2 / hw64, hwt = r2 - ct * hw64;

  const unsigned short* src = Gt + (tbase + (size_t)bat * HW + (size_t)hwt * 64) * 256 + ct * 64;
  int tid = threadIdx.x;
  #pragma unroll
  for (int p = 0; p < 2; ++p){
    int id = p * 256 + tid;
    int t = id >> 3, c0 = (id & 7) * 8;
    u16x8 v = *reinterpret_cast<const u16x8*>(src + (size_t)t * 256 + c0);
    #pragma unroll
    for (int j = 0; j < 8; ++j) T[t][c0 + j] = bf2f(v[j]);
  }
  __syncthreads();
  float* dst = outb + ooff + (size_t)bat * HW * 256 + (size_t)(ct * 64) * HW + (size_t)hwt * 64;
  int cq = tid >> 4, hw0 = (tid & 15) * 4;
  #pragma unroll
  for (int p = 0; p < 4; ++p){
    int c = p * 16 + cq;
    float4 v;
    v.x = T[hw0][c]; v.y = T[hw0+1][c]; v.z = T[hw0+2][c]; v.w = T[hw0+3][c];
    *reinterpret_cast<float4*>(dst + (size_t)c * HW + hw0) = v;
  }
}

// ---- window geometry --------------------------------------------------------
struct WinGeo { int H, W, b, lvl; size_t HW, winoff, tbase, ooff; };

__device__ __forceinline__ WinGeo decode_win(int win){
  WinGeo g; int wloc;
  if (win < 512){ g.lvl = 0; wloc = win;      g.H = 128; g.tbase = 0;     g.ooff = 0; }
  else if (win < 640){ g.lvl = 1; wloc = win - 512; g.H = 64; g.tbase = 65536; g.ooff = 16777216; }
  else if (win < 672){ g.lvl = 2; wloc = win - 640; g.H = 32; g.tbase = 81920; g.ooff = 20971520; }
  else { g.lvl = 3; wloc = win - 672; g.H = 16; g.tbase = 86016; g.ooff = 22020096; }
  g.W = g.H; g.HW = (size_t)g.H * g.W;
  int nww = g.H >> 3, npb = nww * nww;
  g.b = wloc / npb;
  int r = wloc - g.b * npb;
  int wh = r / nww, ww = r - wh * nww;
  g.winoff = (size_t)(wh * 8) * g.W + (size_t)(ww * 8);
  return g;
}

// ---- v9: fully fused per-window kernel, 8 waves -----------------------------
__global__ __launch_bounds__(512, 4) void swin_win(
    const unsigned short* __restrict__ Ft, const unsigned short* __restrict__ Gtin,
    const unsigned short* __restrict__ wball,
    unsigned short* __restrict__ Gt, int phase)
{
  __shared__ alignas(16) unsigned short A[64*264];   // K -> P -> O -> out
  __shared__ alignas(16) unsigned short B[256*72];   // Q ([64][264] view) -> V^T
  int win = blockIdx.x;
  WinGeo g = decode_win(win);
  int tid = threadIdx.x;
  int w = tid >> 6, l = tid & 63, l15 = l & 15, l4 = l >> 4;
  int wd = w * 32;            // 32-row output slab per wave
  int h = w >> 2, tc = w & 3; // QK^T mapping: head h, t-quarter tc

  int batx = (phase == 0) ? g.b : g.b + 2;
  const unsigned short* Sx = Ft + (g.tbase + (size_t)batx * g.HW) * 256;
  const unsigned short* Sy = (phase == 0)
      ? Ft + (g.tbase + (size_t)(g.b + 2) * g.HW) * 256
      : Gtin + (g.tbase + (size_t)g.b * g.HW) * 256;
  unsigned short* Gout = Gt + (g.tbase + (size_t)batx * g.HW) * 256;

  size_t rowo[4];
  #pragma unroll
  for (int ni = 0; ni < 4; ++ni){
    int t = ni * 16 + l15;
    rowo[ni] = ((size_t)g.winoff + (size_t)(t >> 3) * g.W + (t & 7)) * 256;
  }
  const unsigned short* Wbase = wball + ((size_t)(phase * 16 + g.lvl * 4) << 16);
  const unsigned short* Wq = Wbase;
  const unsigned short* Wk = Wbase + 65536;
  const unsigned short* Wv = Wbase + 131072;
  const unsigned short* Wo = Wbase + 196608;

  // ---- K & V GEMMs interleaved, shared Sy fragments ----
  f32x4 av[4][2];
  {
    f32x4 ak[2][4];
    #pragma unroll
    for (int i = 0; i < 2; ++i)
      #pragma unroll
      for (int j = 0; j < 4; ++j) ak[i][j] = f32x4{0.f,0.f,0.f,0.f};
    #pragma unroll
    for (int i = 0; i < 4; ++i)
      #pragma unroll
      for (int j = 0; j < 2; ++j) av[i][j] = f32x4{0.f,0.f,0.f,0.f};
    #pragma unroll
    for (int ks = 0; ks < 8; ++ks){
      int k0 = ks * 32 + l4 * 8;
      bf16x8 tf[4], kf[2], vf[2];
      #pragma unroll
      for (int i = 0; i < 4; ++i)
        tf[i] = *reinterpret_cast<const bf16x8*>(Sy + rowo[i] + k0);
      #pragma unroll
      for (int i = 0; i < 2; ++i){
        kf[i] = *reinterpret_cast<const bf16x8*>(Wk + (size_t)((wd + i*16 + l15) * 256 + k0));
        vf[i] = *reinterpret_cast<const bf16x8*>(Wv + (size_t)((wd + i*16 + l15) * 256 + k0));
      }
      __builtin_amdgcn_s_setprio(1);
      #pragma unroll
      for (int mi = 0; mi < 2; ++mi)
        #pragma unroll
        for (int ni = 0; ni < 4; ++ni)
          ak[mi][ni] = MFMA16(kf[mi], tf[ni], ak[mi][ni], 0, 0, 0);
      #pragma unroll
      for (int mi = 0; mi < 4; ++mi)
        #pragma unroll
        for (int ni = 0; ni < 2; ++ni)
          av[mi][ni] = MFMA16(tf[mi], vf[ni], av[mi][ni], 0, 0, 0);
      __builtin_amdgcn_s_setprio(0);
    }
    // K[t][d] -> A
    #pragma unroll
    for (int mi = 0; mi < 2; ++mi){
      int d0 = wd + mi*16 + l4*4;
      #pragma unroll
      for (int ni = 0; ni < 4; ++ni)
        store_bf4(&A[(ni*16 + l15) * 264 + d0], ak[mi][ni]);
    }
  }
  // av stays in registers until after S.

  // ---- Q GEMM -> B ([64][264] view) ----
  {
    f32x4 aq[2][4];
    #pragma unroll
    for (int i = 0; i < 2; ++i)
      #pragma unroll
      for (int j = 0; j < 4; ++j) aq[i][j] = f32x4{0.f,0.f,0.f,0.f};
    #pragma unroll
    for (int ks = 0; ks < 8; ++ks){
      int k0 = ks * 32 + l4 * 8;
      bf16x8 tf[4], wf[2];
      #pragma unroll
      for (int i = 0; i < 4; ++i)
        tf[i] = *reinterpret_cast<const bf16x8*>(Sx + rowo[i] + k0);
      #pragma unroll
      for (int i = 0; i < 2; ++i)
        wf[i] = *reinterpret_cast<const bf16x8*>(Wq + (size_t)((wd + i*16 + l15) * 256 + k0));
      __builtin_amdgcn_s_setprio(1);
      #pragma unroll
      for (int mi = 0; mi < 2; ++mi)
        #pragma unroll
        for (int ni = 0; ni < 4; ++ni)
          aq[mi][ni] = MFMA16(wf[mi], tf[ni], aq[mi][ni], 0, 0, 0);
      __builtin_amdgcn_s_setprio(0);
    }
    #pragma unroll
    for (int mi = 0; mi < 2; ++mi){
      int d0 = wd + mi*16 + l4*4;
      #pragma unroll
      for (int ni = 0; ni < 4; ++ni)
        store_bf4(&B[(ni*16 + l15) * 264 + d0], aq[mi][ni]);
    }
  }
  __syncthreads();   // sync0: K(A), Q(B) visible

  // ---- S^T[u][t] for head h, t-quarter tc ----
  f32x4 s[4];
  #pragma unroll
  for (int i = 0; i < 4; ++i) s[i] = f32x4{0.f,0.f,0.f,0.f};
  #pragma unroll
  for (int ks = 0; ks < 4; ++ks){
    int k0 = h * 128 + ks * 32 + l4 * 8;
    bf16x8 a[4], bb;
    #pragma unroll
    for (int mi = 0; mi < 4; ++mi)
      a[mi] = *reinterpret_cast<const bf16x8*>(&A[(mi*16 + l15) * 264 + k0]);
    bb = *reinterpret_cast<const bf16x8*>(&B[(tc*16 + l15) * 264 + k0]);
    __builtin_amdgcn_s_setprio(1);
    #pragma unroll
    for (int mi = 0; mi < 4; ++mi)
      s[mi] = MFMA16(a[mi], bb, s[mi], 0, 0, 0);
    __builtin_amdgcn_s_setprio(0);
  }
  __syncthreads();   // sync1: K,Q reads done; A free for P, B free for V^T

  // ---- V^T (from registers) -> B ----
  #pragma unroll
  for (int mi = 0; mi < 4; ++mi){
    int u0 = mi*16 + l4*4;
    #pragma unroll
    for (int ni = 0; ni < 2; ++ni)
      store_bf4(&B[(wd + ni*16 + l15) * 72 + u0], av[mi][ni]);
  }

  // ---- softmax over u (per column t = tc*16 + l15), P -> A ----
  const float SCL = 0.08838834764831845f;   // 1/sqrt(128)
  {
    float m = s[0][0];
    #pragma unroll
    for (int mi = 0; mi < 4; ++mi)
      #pragma unroll
      for (int reg = 0; reg < 4; ++reg) m = fmaxf(m, s[mi][reg]);
    m = fmaxf(m, __shfl_xor(m, 16));
    m = fmaxf(m, __shfl_xor(m, 32));
    float sum = 0.f;
    #pragma unroll
    for (int mi = 0; mi < 4; ++mi)
      #pragma unroll
      for (int reg = 0; reg < 4; ++reg){
        float e = __expf((s[mi][reg] - m) * SCL);
        s[mi][reg] = e; sum += e;
      }
    sum += __shfl_xor(sum, 16);
    sum += __shfl_xor(sum, 32);
    float rs = 1.0f / sum;
    int t = tc*16 + l15;
    #pragma unroll
    for (int mi = 0; mi < 4; ++mi){
      f32x4 pv;
      #pragma unroll
      for (int reg = 0; reg < 4; ++reg) pv[reg] = s[mi][reg] * rs;
      store_bf4(&A[h * 4608 + t * 72 + mi*16 + l4*4], pv);
    }
  }
  __syncthreads();   // sync2: P(A), V^T(B) visible

  // ---- O^T[c][t] = V^T * P^T (both from LDS); head of c-slab: h = w>>2 ----
  f32x4 acc[2][4];
  #pragma unroll
  for (int i = 0; i < 2; ++i)
    #pragma unroll
    for (int j = 0; j < 4; ++j) acc[i][j] = f32x4{0.f,0.f,0.f,0.f};
  #pragma unroll
  for (int ks = 0; ks < 2; ++ks){
    int k0 = ks * 32 + l4 * 8;
    bf16x8 a[2], bb[4];
    #pragma unroll
    for (int mi = 0; mi < 2; ++mi)
      a[mi] = *reinterpret_cast<const bf16x8*>(&B[(wd + mi*16 + l15) * 72 + k0]);
    #pragma unroll
    for (int ni = 0; ni < 4; ++ni)
      bb[ni] = *reinterpret_cast<const bf16x8*>(&A[h * 4608 + (ni*16 + l15) * 72 + k0]);
    __builtin_amdgcn_s_setprio(1);
    #pragma unroll
    for (int mi = 0; mi < 2; ++mi)
      #pragma unroll
      for (int ni = 0; ni < 4; ++ni)
        acc[mi][ni] = MFMA16(a[mi], bb[ni], acc[mi][ni], 0, 0, 0);
    __builtin_amdgcn_s_setprio(0);
  }
  __syncthreads();   // sync3: P reads done; A free for O
  #pragma unroll
  for (int mi = 0; mi < 2; ++mi){
    int c0 = wd + mi*16 + l4*4;
    #pragma unroll
    for (int ni = 0; ni < 4; ++ni)
      store_bf4(&A[(ni*16 + l15) * 264 + c0], acc[mi][ni]);
  }
  __syncthreads();   // sync4: O(A) visible

  // ---- out^T = Wo * o^T ----
  #pragma unroll
  for (int i = 0; i < 2; ++i)
    #pragma unroll
    for (int j = 0; j < 4; ++j) acc[i][j] = f32x4{0.f,0.f,0.f,0.f};
  #pragma unroll
  for (int ks = 0; ks < 8; ++ks){
    int k0 = ks * 32 + l4 * 8;
    bf16x8 a[2], bb[4];
    #pragma unroll
    for (int mi = 0; mi < 2; ++mi)
      a[mi] = *reinterpret_cast<const bf16x8*>(Wo + (size_t)((wd + mi*16 + l15) * 256 + k0));
    #pragma unroll
    for (int ni = 0; ni < 4; ++ni)
      bb[ni] = *reinterpret_cast<const bf16x8*>(&A[(ni*16 + l15) * 264 + k0]);
    __builtin_amdgcn_s_setprio(1);
    #pragma unroll
    for (int mi = 0; mi < 2; ++mi)
      #pragma unroll
      for (int ni = 0; ni < 4; ++ni)
        acc[mi][ni] = MFMA16(a[mi], bb[ni], acc[mi][ni], 0, 0, 0);
    __builtin_amdgcn_s_setprio(0);
  }
  __syncthreads();   // sync5: O reads done; A free for out tile
  #pragma unroll
  for (int mi = 0; mi < 2; ++mi){
    int c0 = wd + mi*16 + l4*4;
    #pragma unroll
    for (int ni = 0; ni < 4; ++ni)
      store_bf4(&A[(ni*16 + l15) * 264 + c0], acc[mi][ni]);
  }
  __syncthreads();   // sync6: out(A) visible

  // ---- fused flush: out + residual, relu, 16B coalesced -> Gt ----
  #pragma unroll
  for (int p = 0; p < 4; ++p){
    int id = p * 512 + tid;
    int t = id >> 5, c = (id & 31) * 8;
    size_t ro = ((size_t)g.winoff + (size_t)(t >> 3) * g.W + (t & 7)) * 256 + c;
    u16x8 ov = *reinterpret_cast<const u16x8*>(&A[t * 264 + c]);
    u16x8 rv = *reinterpret_cast<const u16x8*>(Sx + ro);
    u16x8 o;
    #pragma unroll
    for (int j = 0; j < 8; ++j)
      o[j] = f2bf(fmaxf(bf2f(ov[j]) + bf2f(rv[j]), 0.f));
    *reinterpret_cast<u16x8*>(Gout + ro) = o;
  }
}

// ======================= round-1 fused fallback ==============================
__global__ __launch_bounds__(256, 1) void swin_phase(
    const float* __restrict__ g0, const float* __restrict__ g1,
    const float* __restrict__ g2, const float* __restrict__ g3,
    const unsigned short* __restrict__ wball,
    float* __restrict__ outb, int phase)
{
  __shared__ alignas(16) unsigned short R0[64*264];
  __shared__ alignas(16) unsigned short R1[64*264];
  __shared__ alignas(16) unsigned short R2[256*72];
  __shared__ alignas(16) unsigned short R3[64*264];

  int bid = blockIdx.x;
  WinGeo g = decode_win(bid);
  const float* feat = (g.lvl == 0) ? g0 : (g.lvl == 1) ? g1 : (g.lvl == 2) ? g2 : g3;
  size_t CHW = g.HW * 256;

  const float* xsrc; const float* ysrc; float* outp;
  if (phase == 0){
    xsrc = feat + (size_t)g.b * CHW + g.winoff;
    ysrc = feat + (size_t)(g.b + 2) * CHW + g.winoff;
    outp = outb + g.ooff + (size_t)g.b * CHW + g.winoff;
  } else {
    xsrc = feat + (size_t)(g.b + 2) * CHW + g.winoff;
    ysrc = outb + g.ooff + (size_t)g.b * CHW + g.winoff;
    outp = outb + g.ooff + (size_t)(g.b + 2) * CHW + g.winoff;
  }
  const unsigned short* Wq = wball + ((size_t)(phase * 16 + g.lvl * 4) << 16);
  const unsigned short* Wk = Wq + 65536;
  const unsigned short* Wv = Wq + 2 * 65536;
  const unsigned short* Wo = Wq + 3 * 65536;

  int tid = threadIdx.x;
  int w = tid >> 6, l = tid & 63, l15 = l & 15, l4 = l >> 4, wd = w * 64;
  int hi0 = l >> 3, wi0 = l & 7;

  {
    const float* p0 = ysrc + (size_t)hi0 * g.W + wi0;
    #pragma unroll
    for (int oc = 0; oc < 8; ++oc){
      int c0 = (oc * 4 + w) * 8;
      const float* p = p0 + (size_t)c0 * g.HW;
      u16x8 uv;
      #pragma unroll
      for (int j = 0; j < 8; ++j) uv[j] = f2bf(p[(size_t)j * g.HW]);
      *reinterpret_cast<u16x8*>(&R0[l * 264 + c0]) = uv;
    }
  }
  __syncthreads();
  {
    f32x4 acc[4][4];
    #pragma unroll
    for (int i = 0; i < 4; ++i)
      #pragma unroll
      for (int j = 0; j < 4; ++j) acc[i][j] = f32x4{0.f,0.f,0.f,0.f};
    #pragma unroll
    for (int ks = 0; ks < 8; ++ks){
      int k0 = ks * 32 + l4 * 8;
      bf16x8 a[4], bb[4];
      #pragma unroll
      for (int mi = 0; mi < 4; ++mi)
        a[mi] = *reinterpret_cast<const bf16x8*>(Wk + (size_t)((wd + mi*16 + l15) * 256 + k0));
      #pragma unroll
      for (int ni = 0; ni < 4; ++ni)
        bb[ni] = *reinterpret_cast<const bf16x8*>(&R0[(ni*16 + l15) * 264 + k0]);
      #pragma unroll
      for (int mi = 0; mi < 4; ++mi)
        #pragma unroll
        for (int ni = 0; ni < 4; ++ni)
          acc[mi][ni] = MFMA16(a[mi], bb[ni], acc[mi][ni], 0, 0, 0);
    }
    #pragma unroll
    for (int mi = 0; mi < 4; ++mi){
      int d0 = wd + mi*16 + l4*4;
      #pragma unroll
      for (int ni = 0; ni < 4; ++ni)
        store_bf4(&R1[(ni*16 + l15) * 264 + d0], acc[mi][ni]);
    }
  }
  {
    f32x4 acc[4][4];
    #pragma unroll
    for (int i = 0; i < 4; ++i)
      #pragma unroll
      for (int j = 0; j < 4; ++j) acc[i][j] = f32x4{0.f,0.f,0.f,0.f};
    #pragma unroll
    for (int ks = 0; ks < 8; ++ks){
      int k0 = ks * 32 + l4 * 8;
      bf16x8 a[4], bb[4];
      #pragma unroll
      for (int mi = 0; mi < 4; ++mi)
        a[mi] = *reinterpret_cast<const bf16x8*>(&R0[(mi*16 + l15) * 264 + k0]);
      #pragma unroll
      for (int ni = 0; ni < 4; ++ni)
        bb[ni] = *reinterpret_cast<const bf16x8*>(Wv + (size_t)((wd + ni*16 + l15) * 256 + k0));
      #pragma unroll
      for (int mi = 0; mi < 4; ++mi)
        #pragma unroll
        for (int ni = 0; ni < 4; ++ni)
          acc[mi][ni] = MFMA16(a[mi], bb[ni], acc[mi][ni], 0, 0, 0);
    }
    #pragma unroll
    for (int mi = 0; mi < 4; ++mi){
      int u0 = mi*16 + l4*4;
      #pragma unroll
      for (int ni = 0; ni < 4; ++ni)
        store_bf4(&R2[(wd + ni*16 + l15) * 72 + u0], acc[mi][ni]);
    }
  }
  __syncthreads();
  {
    const float* p0 = xsrc + (size_t)hi0 * g.W + wi0;
    #pragma unroll
    for (int oc = 0; oc < 8; ++oc){
      int c0 = (oc * 4 + w) * 8;
      const float* p = p0 + (size_t)c0 * g.HW;
      u16x8 uv;
      #pragma unroll
      for (int j = 0; j < 8; ++j) uv[j] = f2bf(p[(size_t)j * g.HW]);
      *reinterpret_cast<u16x8*>(&R0[l * 264 + c0]) = uv;
    }
  }
  __syncthreads();
  {
    f32x4 acc[4][4];
    #pragma unroll
    for (int i = 0; i < 4; ++i)
      #pragma unroll
      for (int j = 0; j < 4; ++j) acc[i][j] = f32x4{0.f,0.f,0.f,0.f};
    #pragma unroll
    for (int ks = 0; ks < 8; ++ks){
      int k0 = ks * 32 + l4 * 8;
      bf16x8 a[4], bb[4];
      #pragma unroll
      for (int mi = 0; mi < 4; ++mi)
        a[mi] = *reinterpret_cast<const bf16x8*>(Wq + (size_t)((wd + mi*16 + l15) * 256 + k0));
      #pragma unroll
      for (int ni = 0; ni < 4; ++ni)
        bb[ni] = *reinterpret_cast<const bf16x8*>(&R0[(ni*16 + l15) * 264 + k0]);
      #pragma unroll
      for (int mi = 0; mi < 4; ++mi)
        #pragma unroll
        for (int ni = 0; ni < 4; ++ni)
          acc[mi][ni] = MFMA16(a[mi], bb[ni], acc[mi][ni], 0, 0, 0);
    }
    #pragma unroll
    for (int mi = 0; mi < 4; ++mi){
      int d0 = wd + mi*16 + l4*4;
      #pragma unroll
      for (int ni = 0; ni < 4; ++ni)
        store_bf4(&R3[(ni*16 + l15) * 264 + d0], acc[mi][ni]);
    }
  }
  __syncthreads();

  int h = w >> 1, tc = w & 1;
  {
    f32x4 s[4][2];
    #pragma unroll
    for (int i = 0; i < 4; ++i){ s[i][0] = f32x4{0.f,0.f,0.f,0.f}; s[i][1] = f32x4{0.f,0.f,0.f,0.f}; }
    #pragma unroll
    for (int ks = 0; ks < 4; ++ks){
      int k0 = h * 128 + ks * 32 + l4 * 8;
      bf16x8 a[4], bb[2];
      #pragma unroll
      for (int mi = 0; mi < 4; ++mi)
        a[mi] = *reinterpret_cast<const bf16x8*>(&R1[(mi*16 + l15) * 264 + k0]);
      #pragma unroll
      for (int ni = 0; ni < 2; ++ni)
        bb[ni] = *reinterpret_cast<const bf16x8*>(&R3[(tc*32 + ni*16 + l15) * 264 + k0]);
      #pragma unroll
      for (int mi = 0; mi < 4; ++mi)
        #pragma unroll
        for (int ni = 0; ni < 2; ++ni)
          s[mi][ni] = MFMA16(a[mi], bb[ni], s[mi][ni], 0, 0, 0);
    }
    __syncthreads();
    const float SCL = 0.08838834764831845f;
    unsigned short* P = R1;
    #pragma unroll
    for (int ni = 0; ni < 2; ++ni){
      float m = s[0][ni][0];
      #pragma unroll
      for (int mi = 0; mi < 4; ++mi)
        #pragma unroll
        for (int reg = 0; reg < 4; ++reg) m = fmaxf(m, s[mi][ni][reg]);
      m = fmaxf(m, __shfl_xor(m, 16));
      m = fmaxf(m, __shfl_xor(m, 32));
      float sum = 0.f;
      #pragma unroll
      for (int mi = 0; mi < 4; ++mi)
        #pragma unroll
        for (int reg = 0; reg < 4; ++reg){
          float e = __expf((s[mi][ni][reg] - m) * SCL);
          s[mi][ni][reg] = e; sum += e;
        }
      sum += __shfl_xor(sum, 16);
      sum += __shfl_xor(sum, 32);
      float rs = 1.0f / sum;
      int t = tc*32 + ni*16 + l15;
      #pragma unroll
      for (int mi = 0; mi < 4; ++mi){
        f32x4 pv;
        #pragma unroll
        for (int reg = 0; reg < 4; ++reg) pv[reg] = s[mi][ni][reg] * rs;
        store_bf4(&P[h * 4608 + t * 72 + mi*16 + l4*4], pv);
      }
    }
  }
  __syncthreads();
  {
    int wdh = h * 128 + tc * 64;
    f32x4 acc[4][4];
    #pragma unroll
    for (int i = 0; i < 4; ++i)
      #pragma unroll
      for (int j = 0; j < 4; ++j) acc[i][j] = f32x4{0.f,0.f,0.f,0.f};
    const unsigned short* P = R1;
    #pragma unroll
    for (int ks = 0; ks < 2; ++ks){
      int k0 = ks * 32 + l4 * 8;
      bf16x8 a[4], bb[4];
      #pragma unroll
      for (int mi = 0; mi < 4; ++mi)
        a[mi] = *reinterpret_cast<const bf16x8*>(&R2[(wdh + mi*16 + l15) * 72 + k0]);
      #pragma unroll
      for (int ni = 0; ni < 4; ++ni)
        bb[ni] = *reinterpret_cast<const bf16x8*>(&P[h * 4608 + (ni*16 + l15) * 72 + k0]);
      #pragma unroll
      for (int mi = 0; mi < 4; ++mi)
        #pragma unroll
        for (int ni = 0; ni < 4; ++ni)
          acc[mi][ni] = MFMA16(a[mi], bb[ni], acc[mi][ni], 0, 0, 0);
    }
    #pragma unroll
    for (int mi = 0; mi < 4; ++mi){
      int c0 = wdh + mi*16 + l4*4;
      #pragma unroll
      for (int ni = 0; ni < 4; ++ni)
        store_bf4(&R0[(ni*16 + l15) * 264 + c0], acc[mi][ni]);
    }
  }
  __syncthreads();
  {
    f32x4 acc[4][4];
    #pragma unroll
    for (int i = 0; i < 4; ++i)
      #pragma unroll
      for (int j = 0; j < 4; ++j) acc[i][j] = f32x4{0.f,0.f,0.f,0.f};
    #pragma unroll
    for (int ks = 0; ks < 8; ++ks){
      int k0 = ks * 32 + l4 * 8;
      bf16x8 a[4], bb[4];
      #pragma unroll
      for (int mi = 0; mi < 4; ++mi)
        a[mi] = *reinterpret_cast<const bf16x8*>(Wo + (size_t)((wd + mi*16 + l15) * 256 + k0));
      #pragma unroll
      for (int ni = 0; ni < 4; ++ni)
        bb[ni] = *reinterpret_cast<const bf16x8*>(&R0[(ni*16 + l15) * 264 + k0]);
      #pragma unroll
      for (int mi = 0; mi < 4; ++mi)
        #pragma unroll
        for (int ni = 0; ni < 4; ++ni)
          acc[mi][ni] = MFMA16(a[mi], bb[ni], acc[mi][ni], 0, 0, 0);
    }
    #pragma unroll
    for (int mi = 0; mi < 4; ++mi){
      #pragma unroll
      for (int ni = 0; ni < 4; ++ni){
        int t = ni*16 + l15, thi = t >> 3, twi = t & 7;
        size_t base = (size_t)(wd + mi*16 + l4*4) * g.HW + (size_t)thi * g.W + twi;
        #pragma unroll
        for (int reg = 0; reg < 4; ++reg){
          float res = xsrc[base + (size_t)reg * g.HW];
          float v = acc[mi][ni][reg] + res;
          outp[base + (size_t)reg * g.HW] = fmaxf(v, 0.f);
        }
      }
    }
  }
}

extern "C" void kernel_launch(void* const* d_in, const int* in_sizes, int n_in,
                              void* d_out, int out_size, void* d_ws, size_t ws_size,
                              hipStream_t stream) {
  (void)in_sizes; (void)n_in; (void)out_size;
  const float* f0 = (const float*)d_in[0];
  const float* f1 = (const float*)d_in[1];
  const float* f2 = (const float*)d_in[2];
  const float* f3 = (const float*)d_in[3];
  const float* w1 = (const float*)d_in[4];
  const float* w2 = (const float*)d_in[5];
  float* out = (float*)d_out;

  unsigned short* wbf = (unsigned short*)d_ws;
  const size_t WBF_B = 4194304;       // 2*16*65536 bf16
  const size_t FT_B  = 44564480;      // 87040 tokens * 256 * 2B
  const size_t need  = WBF_B + 2 * FT_B;   // 93,323,264

  wcvt_kernel<<<2048, 256, 0, stream>>>(w1, w2, wbf);

  if (ws_size >= need){
    char* base = (char*)d_ws + WBF_B;
    unsigned short* Ft = (unsigned short*)(base);
    unsigned short* Gt = (unsigned short*)(base + FT_B);

    xpose_kernel<<<5440, 256, 0, stream>>>(f0, f1, f2, f3, Ft);
    for (int phase = 0; phase < 2; ++phase)
      swin_win<<<680, 512, 0, stream>>>(Ft, Gt, wbf, Gt, phase);
    untrans_kernel<<<5440, 256, 0, stream>>>(Gt, out);
  } else {
    swin_phase<<<680, 256, 0, stream>>>(f0, f1, f2, f3, wbf, out, 0);
    swin_phase<<<680, 256, 0, stream>>>(f0, f1, f2, f3, wbf, out, 1);
  }
}

// Round 10
// 222.420 us; speedup vs baseline: 1.1009x; 1.1009x over previous
//
#include <hip/hip_runtime.h>

// Swin cross-attention pipeline v10 for MI355X.
// v9 regressed: launch_bounds(512,4) capped VGPR at 64 -> spills (WRITE 22->50MB).
// v10 = v8 structure (256 thr / 4 waves / 2 blocks/CU / 70.6KB LDS, no spills)
// with the K and Q GEMM k-loops MERGED into one loop of two independent
// accumulator chains + two independent load streams (Sy for K, Sx for Q).
// This gives the scheduler cross-chain ILP to hide L3 latency (v8 is ~90%
// stall: MfmaUtil 8.5%, VALU 8.8%, HBM 6%). V runs as its own loop after
// (Sy re-read is L1/L2-hot); av live range shrinks vs v8.
// launch_bounds(256,2) => VGPR budget 256 (merged loop needs ~200).

using bf16x8 = __attribute__((ext_vector_type(8))) __bf16;
using f32x4  = __attribute__((ext_vector_type(4))) float;
using u16x4  = __attribute__((ext_vector_type(4))) unsigned short;
using u16x8  = __attribute__((ext_vector_type(8))) unsigned short;

__device__ __forceinline__ unsigned short f2bf(float f){
  unsigned int x = __float_as_uint(f);
  x += 0x7FFFu + ((x >> 16) & 1u);          // RNE
  return (unsigned short)(x >> 16);
}
__device__ __forceinline__ float bf2f(unsigned short u){
  return __uint_as_float((unsigned int)u << 16);
}
__device__ __forceinline__ void store_bf4(unsigned short* dst, f32x4 v){
  u16x4 o;
  o[0]=f2bf(v[0]); o[1]=f2bf(v[1]); o[2]=f2bf(v[2]); o[3]=f2bf(v[3]);
  *reinterpret_cast<u16x4*>(dst) = o;
}

#define MFMA16 __builtin_amdgcn_mfma_f32_16x16x32_bf16

__global__ void wcvt_kernel(const float* __restrict__ w1,
                            const float* __restrict__ w2,
                            unsigned short* __restrict__ dst){
  int i = blockIdx.x * 256 + threadIdx.x;
  const float4* src = (i < 262144) ? (reinterpret_cast<const float4*>(w1) + i)
                                   : (reinterpret_cast<const float4*>(w2) + (i - 262144));
  float4 v = *src;
  u16x4 o; o[0]=f2bf(v.x); o[1]=f2bf(v.y); o[2]=f2bf(v.z); o[3]=f2bf(v.w);
  reinterpret_cast<u16x4*>(dst)[i] = o;
}

// ---- transpose fp32 [C,HW] -> bf16 Ft[token][c] -----------------------------
__global__ __launch_bounds__(256, 2) void xpose_kernel(
    const float* __restrict__ g0, const float* __restrict__ g1,
    const float* __restrict__ g2, const float* __restrict__ g3,
    unsigned short* __restrict__ Ft)
{
  __shared__ float T[64][65];
  int bid = blockIdx.x;
  int r; const float* feat; int Hl; size_t tbase;
  if (bid < 4096){ r = bid;        feat = g0; Hl = 128; tbase = 0; }
  else if (bid < 5120){ r = bid - 4096; feat = g1; Hl = 64;  tbase = 65536; }
  else if (bid < 5376){ r = bid - 5120; feat = g2; Hl = 32;  tbase = 81920; }
  else { r = bid - 5376; feat = g3; Hl = 16;  tbase = 86016; }
  size_t HW = (size_t)Hl * Hl;
  int hw64 = (int)(HW >> 6);
  int bat = r / (4 * hw64);
  int r2 = r - bat * 4 * hw64;
  int ct = r2 / hw64, hwt = r2 - ct * hw64;

  const float* src = feat + (size_t)bat * HW * 256 + (size_t)(ct * 64) * HW + (size_t)hwt * 64;
  int tid = threadIdx.x;
  int cq = tid >> 4, hw0 = (tid & 15) * 4;
  #pragma unroll
  for (int p = 0; p < 4; ++p){
    int c = p * 16 + cq;
    const float* sp = src + (size_t)c * HW + hw0;
    float4 v = *reinterpret_cast<const float4*>(sp);
    T[c][hw0] = v.x; T[c][hw0+1] = v.y; T[c][hw0+2] = v.z; T[c][hw0+3] = v.w;
  }
  __syncthreads();
  unsigned short* dst = Ft + (tbase + (size_t)bat * HW + (size_t)hwt * 64) * 256 + ct * 64;
  #pragma unroll
  for (int p = 0; p < 2; ++p){
    int id = p * 256 + tid;
    int t = id >> 3, c0 = (id & 7) * 8;
    u16x8 o;
    #pragma unroll
    for (int j = 0; j < 8; ++j) o[j] = f2bf(T[c0 + j][t]);
    *reinterpret_cast<u16x8*>(dst + (size_t)t * 256 + c0) = o;
  }
}

// ---- transpose back: Gt[token][c] bf16 -> fp32 out [C,HW], ALL 4 batches ----
__global__ __launch_bounds__(256, 2) void untrans_kernel(
    const unsigned short* __restrict__ Gt, float* __restrict__ outb)
{
  __shared__ float T[64][65];
  int bid = blockIdx.x;
  int r; int Hl; size_t tbase, ooff;
  if (bid < 4096){ r = bid;        Hl = 128; tbase = 0;     ooff = 0; }
  else if (bid < 5120){ r = bid - 4096; Hl = 64; tbase = 65536; ooff = 16777216; }
  else if (bid < 5376){ r = bid - 5120; Hl = 32; tbase = 81920; ooff = 20971520; }
  else { r = bid - 5376; Hl = 16; tbase = 86016; ooff = 22020096; }
  size_t HW = (size_t)Hl * Hl;
  int hw64 = (int)(HW >> 6);
  int bat = r / (4 * hw64);
  int r2 = r - bat * 4 * hw64;
  int ct = r2 / hw64, hwt = r2 - ct * hw64;

  const unsigned short* src = Gt + (tbase + (size_t)bat * HW + (size_t)hwt * 64) * 256 + ct * 64;
  int tid = threadIdx.x;
  #pragma unroll
  for (int p = 0; p < 2; ++p){
    int id = p * 256 + tid;
    int t = id >> 3, c0 = (id & 7) * 8;
    u16x8 v = *reinterpret_cast<const u16x8*>(src + (size_t)t * 256 + c0);
    #pragma unroll
    for (int j = 0; j < 8; ++j) T[t][c0 + j] = bf2f(v[j]);
  }
  __syncthreads();
  float* dst = outb + ooff + (size_t)bat * HW * 256 + (size_t)(ct * 64) * HW + (size_t)hwt * 64;
  int cq = tid >> 4, hw0 = (tid & 15) * 4;
  #pragma unroll
  for (int p = 0; p < 4; ++p){
    int c = p * 16 + cq;
    float4 v;
    v.x = T[hw0][c]; v.y = T[hw0+1][c]; v.z = T[hw0+2][c]; v.w = T[hw0+3][c];
    *reinterpret_cast<float4*>(dst + (size_t)c * HW + hw0) = v;
  }
}

// ---- window geometry --------------------------------------------------------
struct WinGeo { int H, W, b, lvl; size_t HW, winoff, tbase, ooff; };

__device__ __forceinline__ WinGeo decode_win(int win){
  WinGeo g; int wloc;
  if (win < 512){ g.lvl = 0; wloc = win;      g.H = 128; g.tbase = 0;     g.ooff = 0; }
  else if (win < 640){ g.lvl = 1; wloc = win - 512; g.H = 64; g.tbase = 65536; g.ooff = 16777216; }
  else if (win < 672){ g.lvl = 2; wloc = win - 640; g.H = 32; g.tbase = 81920; g.ooff = 20971520; }
  else { g.lvl = 3; wloc = win - 672; g.H = 16; g.tbase = 86016; g.ooff = 22020096; }
  g.W = g.H; g.HW = (size_t)g.H * g.W;
  int nww = g.H >> 3, npb = nww * nww;
  g.b = wloc / npb;
  int r = wloc - g.b * npb;
  int wh = r / nww, ww = r - wh * nww;
  g.winoff = (size_t)(wh * 8) * g.W + (size_t)(ww * 8);
  return g;
}

// ---- v10: fully fused per-window kernel, K+Q merged k-loop ------------------
__global__ __launch_bounds__(256, 2) void swin_win(
    const unsigned short* __restrict__ Ft, const unsigned short* __restrict__ Gtin,
    const unsigned short* __restrict__ wball,
    unsigned short* __restrict__ Gt, int phase)
{
  __shared__ alignas(16) unsigned short A[64*264];   // K -> P -> O -> out
  __shared__ alignas(16) unsigned short B[256*72];   // Q ([64][264] view) -> V^T
  int win = blockIdx.x;
  WinGeo g = decode_win(win);
  int tid = threadIdx.x;
  int w = tid >> 6, l = tid & 63, l15 = l & 15, l4 = l >> 4, wd = w * 64;
  int h = w >> 1, tc = w & 1;

  int batx = (phase == 0) ? g.b : g.b + 2;
  const unsigned short* Sx = Ft + (g.tbase + (size_t)batx * g.HW) * 256;
  const unsigned short* Sy = (phase == 0)
      ? Ft + (g.tbase + (size_t)(g.b + 2) * g.HW) * 256
      : Gtin + (g.tbase + (size_t)g.b * g.HW) * 256;
  unsigned short* Gout = Gt + (g.tbase + (size_t)batx * g.HW) * 256;

  size_t rowo[4];
  #pragma unroll
  for (int ni = 0; ni < 4; ++ni){
    int t = ni * 16 + l15;
    rowo[ni] = ((size_t)g.winoff + (size_t)(t >> 3) * g.W + (t & 7)) * 256;
  }
  const unsigned short* Wbase = wball + ((size_t)(phase * 16 + g.lvl * 4) << 16);
  const unsigned short* Wq = Wbase;
  const unsigned short* Wk = Wbase + 65536;
  const unsigned short* Wv = Wbase + 131072;
  const unsigned short* Wo = Wbase + 196608;

  // ---- K & Q GEMMs merged: two independent chains, two load streams ----
  {
    f32x4 ak[4][4], aq[4][4];
    #pragma unroll
    for (int i = 0; i < 4; ++i)
      #pragma unroll
      for (int j = 0; j < 4; ++j){ ak[i][j] = f32x4{0.f,0.f,0.f,0.f}; aq[i][j] = f32x4{0.f,0.f,0.f,0.f}; }
    #pragma unroll
    for (int ks = 0; ks < 8; ++ks){
      int k0 = ks * 32 + l4 * 8;
      bf16x8 ty[4], tx[4], kf[4], qf[4];
      #pragma unroll
      for (int i = 0; i < 4; ++i){
        ty[i] = *reinterpret_cast<const bf16x8*>(Sy + rowo[i] + k0);
        tx[i] = *reinterpret_cast<const bf16x8*>(Sx + rowo[i] + k0);
        kf[i] = *reinterpret_cast<const bf16x8*>(Wk + (size_t)((wd + i*16 + l15) * 256 + k0));
        qf[i] = *reinterpret_cast<const bf16x8*>(Wq + (size_t)((wd + i*16 + l15) * 256 + k0));
      }
      __builtin_amdgcn_s_setprio(1);
      #pragma unroll
      for (int mi = 0; mi < 4; ++mi)
        #pragma unroll
        for (int ni = 0; ni < 4; ++ni){
          ak[mi][ni] = MFMA16(kf[mi], ty[ni], ak[mi][ni], 0, 0, 0);
          aq[mi][ni] = MFMA16(qf[mi], tx[ni], aq[mi][ni], 0, 0, 0);
        }
      __builtin_amdgcn_s_setprio(0);
    }
    // K[t][d] -> A ; Q[t][d] -> B
    #pragma unroll
    for (int mi = 0; mi < 4; ++mi){
      int d0 = wd + mi*16 + l4*4;
      #pragma unroll
      for (int ni = 0; ni < 4; ++ni){
        store_bf4(&A[(ni*16 + l15) * 264 + d0], ak[mi][ni]);
        store_bf4(&B[(ni*16 + l15) * 264 + d0], aq[mi][ni]);
      }
    }
  }

  // ---- V GEMM (Sy now L1/L2-hot); av stays in registers until after S ----
  f32x4 av[4][4];
  {
    #pragma unroll
    for (int i = 0; i < 4; ++i)
      #pragma unroll
      for (int j = 0; j < 4; ++j) av[i][j] = f32x4{0.f,0.f,0.f,0.f};
    #pragma unroll
    for (int ks = 0; ks < 8; ++ks){
      int k0 = ks * 32 + l4 * 8;
      bf16x8 ty[4], vf[4];
      #pragma unroll
      for (int i = 0; i < 4; ++i){
        ty[i] = *reinterpret_cast<const bf16x8*>(Sy + rowo[i] + k0);
        vf[i] = *reinterpret_cast<const bf16x8*>(Wv + (size_t)((wd + i*16 + l15) * 256 + k0));
      }
      __builtin_amdgcn_s_setprio(1);
      #pragma unroll
      for (int mi = 0; mi < 4; ++mi)
        #pragma unroll
        for (int ni = 0; ni < 4; ++ni)
          av[mi][ni] = MFMA16(ty[mi], vf[ni], av[mi][ni], 0, 0, 0);
      __builtin_amdgcn_s_setprio(0);
    }
  }
  __syncthreads();   // sync0: K(A), Q(B) visible

  // ---- S^T[u][t] per head from LDS K,Q ----
  f32x4 s[4][2];
  #pragma unroll
  for (int i = 0; i < 4; ++i){ s[i][0] = f32x4{0.f,0.f,0.f,0.f}; s[i][1] = f32x4{0.f,0.f,0.f,0.f}; }
  #pragma unroll
  for (int ks = 0; ks < 4; ++ks){
    int k0 = h * 128 + ks * 32 + l4 * 8;
    bf16x8 a[4], bb[2];
    #pragma unroll
    for (int mi = 0; mi < 4; ++mi)
      a[mi] = *reinterpret_cast<const bf16x8*>(&A[(mi*16 + l15) * 264 + k0]);
    #pragma unroll
    for (int ni = 0; ni < 2; ++ni)
      bb[ni] = *reinterpret_cast<const bf16x8*>(&B[(tc*32 + ni*16 + l15) * 264 + k0]);
    __builtin_amdgcn_s_setprio(1);
    #pragma unroll
    for (int mi = 0; mi < 4; ++mi)
      #pragma unroll
      for (int ni = 0; ni < 2; ++ni)
        s[mi][ni] = MFMA16(a[mi], bb[ni], s[mi][ni], 0, 0, 0);
    __builtin_amdgcn_s_setprio(0);
  }
  __syncthreads();   // sync1: K,Q reads done; A free for P, B free for V^T

  // ---- V^T (from registers) -> B ----
  #pragma unroll
  for (int mi = 0; mi < 4; ++mi){
    int u0 = mi*16 + l4*4;
    #pragma unroll
    for (int ni = 0; ni < 4; ++ni)
      store_bf4(&B[(wd + ni*16 + l15) * 72 + u0], av[mi][ni]);
  }

  // ---- softmax over u (per column t), P -> A ----
  const float SCL = 0.08838834764831845f;   // 1/sqrt(128)
  #pragma unroll
  for (int ni = 0; ni < 2; ++ni){
    float m = s[0][ni][0];
    #pragma unroll
    for (int mi = 0; mi < 4; ++mi)
      #pragma unroll
      for (int reg = 0; reg < 4; ++reg) m = fmaxf(m, s[mi][ni][reg]);
    m = fmaxf(m, __shfl_xor(m, 16));
    m = fmaxf(m, __shfl_xor(m, 32));
    float sum = 0.f;
    #pragma unroll
    for (int mi = 0; mi < 4; ++mi)
      #pragma unroll
      for (int reg = 0; reg < 4; ++reg){
        float e = __expf((s[mi][ni][reg] - m) * SCL);
        s[mi][ni][reg] = e; sum += e;
      }
    sum += __shfl_xor(sum, 16);
    sum += __shfl_xor(sum, 32);
    float rs = 1.0f / sum;
    int t = tc*32 + ni*16 + l15;
    #pragma unroll
    for (int mi = 0; mi < 4; ++mi){
      f32x4 pv;
      #pragma unroll
      for (int reg = 0; reg < 4; ++reg) pv[reg] = s[mi][ni][reg] * rs;
      store_bf4(&A[h * 4608 + t * 72 + mi*16 + l4*4], pv);
    }
  }
  __syncthreads();   // sync2: P(A), V^T(B) visible

  // ---- O^T[c][t] = V^T * P^T (both from LDS) ----
  f32x4 acc[4][4];
  #pragma unroll
  for (int i = 0; i < 4; ++i)
    #pragma unroll
    for (int j = 0; j < 4; ++j) acc[i][j] = f32x4{0.f,0.f,0.f,0.f};
  #pragma unroll
  for (int ks = 0; ks < 2; ++ks){
    int k0 = ks * 32 + l4 * 8;
    bf16x8 a[4], bb[4];
    #pragma unroll
    for (int mi = 0; mi < 4; ++mi)
      a[mi] = *reinterpret_cast<const bf16x8*>(&B[(wd + mi*16 + l15) * 72 + k0]);
    #pragma unroll
    for (int ni = 0; ni < 4; ++ni)
      bb[ni] = *reinterpret_cast<const bf16x8*>(&A[h * 4608 + (ni*16 + l15) * 72 + k0]);
    __builtin_amdgcn_s_setprio(1);
    #pragma unroll
    for (int mi = 0; mi < 4; ++mi)
      #pragma unroll
      for (int ni = 0; ni < 4; ++ni)
        acc[mi][ni] = MFMA16(a[mi], bb[ni], acc[mi][ni], 0, 0, 0);
    __builtin_amdgcn_s_setprio(0);
  }
  __syncthreads();   // sync3: P reads done; A free for O
  #pragma unroll
  for (int mi = 0; mi < 4; ++mi){
    int c0 = wd + mi*16 + l4*4;
    #pragma unroll
    for (int ni = 0; ni < 4; ++ni)
      store_bf4(&A[(ni*16 + l15) * 264 + c0], acc[mi][ni]);
  }
  __syncthreads();   // sync4: O(A) visible

  // ---- out^T = Wo * o^T ----
  #pragma unroll
  for (int i = 0; i < 4; ++i)
    #pragma unroll
    for (int j = 0; j < 4; ++j) acc[i][j] = f32x4{0.f,0.f,0.f,0.f};
  #pragma unroll
  for (int ks = 0; ks < 8; ++ks){
    int k0 = ks * 32 + l4 * 8;
    bf16x8 a[4], bb[4];
    #pragma unroll
    for (int mi = 0; mi < 4; ++mi)
      a[mi] = *reinterpret_cast<const bf16x8*>(Wo + (size_t)((wd + mi*16 + l15) * 256 + k0));
    #pragma unroll
    for (int ni = 0; ni < 4; ++ni)
      bb[ni] = *reinterpret_cast<const bf16x8*>(&A[(ni*16 + l15) * 264 + k0]);
    __builtin_amdgcn_s_setprio(1);
    #pragma unroll
    for (int mi = 0; mi < 4; ++mi)
      #pragma unroll
      for (int ni = 0; ni < 4; ++ni)
        acc[mi][ni] = MFMA16(a[mi], bb[ni], acc[mi][ni], 0, 0, 0);
    __builtin_amdgcn_s_setprio(0);
  }
  __syncthreads();   // sync5: O reads done; A free for out tile
  #pragma unroll
  for (int mi = 0; mi < 4; ++mi){
    int c0 = wd + mi*16 + l4*4;
    #pragma unroll
    for (int ni = 0; ni < 4; ++ni)
      store_bf4(&A[(ni*16 + l15) * 264 + c0], acc[mi][ni]);
  }
  __syncthreads();   // sync6: out(A) visible

  // ---- fused flush: out + residual, relu, 16B coalesced -> Gt ----
  #pragma unroll
  for (int p = 0; p < 8; ++p){
    int id = p * 256 + tid;
    int t = id >> 5, c = (id & 31) * 8;
    size_t ro = ((size_t)g.winoff + (size_t)(t >> 3) * g.W + (t & 7)) * 256 + c;
    u16x8 ov = *reinterpret_cast<const u16x8*>(&A[t * 264 + c]);
    u16x8 rv = *reinterpret_cast<const u16x8*>(Sx + ro);
    u16x8 o;
    #pragma unroll
    for (int j = 0; j < 8; ++j)
      o[j] = f2bf(fmaxf(bf2f(ov[j]) + bf2f(rv[j]), 0.f));
    *reinterpret_cast<u16x8*>(Gout + ro) = o;
  }
}

// ======================= round-1 fused fallback ==============================
__global__ __launch_bounds__(256, 1) void swin_phase(
    const float* __restrict__ g0, const float* __restrict__ g1,
    const float* __restrict__ g2, const float* __restrict__ g3,
    const unsigned short* __restrict__ wball,
    float* __restrict__ outb, int phase)
{
  __shared__ alignas(16) unsigned short R0[64*264];
  __shared__ alignas(16) unsigned short R1[64*264];
  __shared__ alignas(16) unsigned short R2[256*72];
  __shared__ alignas(16) unsigned short R3[64*264];

  int bid = blockIdx.x;
  WinGeo g = decode_win(bid);
  const float* feat = (g.lvl == 0) ? g0 : (g.lvl == 1) ? g1 : (g.lvl == 2) ? g2 : g3;
  size_t CHW = g.HW * 256;

  const float* xsrc; const float* ysrc; float* outp;
  if (phase == 0){
    xsrc = feat + (size_t)g.b * CHW + g.winoff;
    ysrc = feat + (size_t)(g.b + 2) * CHW + g.winoff;
    outp = outb + g.ooff + (size_t)g.b * CHW + g.winoff;
  } else {
    xsrc = feat + (size_t)(g.b + 2) * CHW + g.winoff;
    ysrc = outb + g.ooff + (size_t)g.b * CHW + g.winoff;
    outp = outb + g.ooff + (size_t)(g.b + 2) * CHW + g.winoff;
  }
  const unsigned short* Wq = wball + ((size_t)(phase * 16 + g.lvl * 4) << 16);
  const unsigned short* Wk = Wq + 65536;
  const unsigned short* Wv = Wq + 2 * 65536;
  const unsigned short* Wo = Wq + 3 * 65536;

  int tid = threadIdx.x;
  int w = tid >> 6, l = tid & 63, l15 = l & 15, l4 = l >> 4, wd = w * 64;
  int hi0 = l >> 3, wi0 = l & 7;

  {
    const float* p0 = ysrc + (size_t)hi0 * g.W + wi0;
    #pragma unroll
    for (int oc = 0; oc < 8; ++oc){
      int c0 = (oc * 4 + w) * 8;
      const float* p = p0 + (size_t)c0 * g.HW;
      u16x8 uv;
      #pragma unroll
      for (int j = 0; j < 8; ++j) uv[j] = f2bf(p[(size_t)j * g.HW]);
      *reinterpret_cast<u16x8*>(&R0[l * 264 + c0]) = uv;
    }
  }
  __syncthreads();
  {
    f32x4 acc[4][4];
    #pragma unroll
    for (int i = 0; i < 4; ++i)
      #pragma unroll
      for (int j = 0; j < 4; ++j) acc[i][j] = f32x4{0.f,0.f,0.f,0.f};
    #pragma unroll
    for (int ks = 0; ks < 8; ++ks){
      int k0 = ks * 32 + l4 * 8;
      bf16x8 a[4], bb[4];
      #pragma unroll
      for (int mi = 0; mi < 4; ++mi)
        a[mi] = *reinterpret_cast<const bf16x8*>(Wk + (size_t)((wd + mi*16 + l15) * 256 + k0));
      #pragma unroll
      for (int ni = 0; ni < 4; ++ni)
        bb[ni] = *reinterpret_cast<const bf16x8*>(&R0[(ni*16 + l15) * 264 + k0]);
      #pragma unroll
      for (int mi = 0; mi < 4; ++mi)
        #pragma unroll
        for (int ni = 0; ni < 4; ++ni)
          acc[mi][ni] = MFMA16(a[mi], bb[ni], acc[mi][ni], 0, 0, 0);
    }
    #pragma unroll
    for (int mi = 0; mi < 4; ++mi){
      int d0 = wd + mi*16 + l4*4;
      #pragma unroll
      for (int ni = 0; ni < 4; ++ni)
        store_bf4(&R1[(ni*16 + l15) * 264 + d0], acc[mi][ni]);
    }
  }
  {
    f32x4 acc[4][4];
    #pragma unroll
    for (int i = 0; i < 4; ++i)
      #pragma unroll
      for (int j = 0; j < 4; ++j) acc[i][j] = f32x4{0.f,0.f,0.f,0.f};
    #pragma unroll
    for (int ks = 0; ks < 8; ++ks){
      int k0 = ks * 32 + l4 * 8;
      bf16x8 a[4], bb[4];
      #pragma unroll
      for (int mi = 0; mi < 4; ++mi)
        a[mi] = *reinterpret_cast<const bf16x8*>(&R0[(mi*16 + l15) * 264 + k0]);
      #pragma unroll
      for (int ni = 0; ni < 4; ++ni)
        bb[ni] = *reinterpret_cast<const bf16x8*>(Wv + (size_t)((wd + ni*16 + l15) * 256 + k0));
      #pragma unroll
      for (int mi = 0; mi < 4; ++mi)
        #pragma unroll
        for (int ni = 0; ni < 4; ++ni)
          acc[mi][ni] = MFMA16(a[mi], bb[ni], acc[mi][ni], 0, 0, 0);
    }
    #pragma unroll
    for (int mi = 0; mi < 4; ++mi){
      int u0 = mi*16 + l4*4;
      #pragma unroll
      for (int ni = 0; ni < 4; ++ni)
        store_bf4(&R2[(wd + ni*16 + l15) * 72 + u0], acc[mi][ni]);
    }
  }
  __syncthreads();
  {
    const float* p0 = xsrc + (size_t)hi0 * g.W + wi0;
    #pragma unroll
    for (int oc = 0; oc < 8; ++oc){
      int c0 = (oc * 4 + w) * 8;
      const float* p = p0 + (size_t)c0 * g.HW;
      u16x8 uv;
      #pragma unroll
      for (int j = 0; j < 8; ++j) uv[j] = f2bf(p[(size_t)j * g.HW]);
      *reinterpret_cast<u16x8*>(&R0[l * 264 + c0]) = uv;
    }
  }
  __syncthreads();
  {
    f32x4 acc[4][4];
    #pragma unroll
    for (int i = 0; i < 4; ++i)
      #pragma unroll
      for (int j = 0; j < 4; ++j) acc[i][j] = f32x4{0.f,0.f,0.f,0.f};
    #pragma unroll
    for (int ks = 0; ks < 8; ++ks){
      int k0 = ks * 32 + l4 * 8;
      bf16x8 a[4], bb[4];
      #pragma unroll
      for (int mi = 0; mi < 4; ++mi)
        a[mi] = *reinterpret_cast<const bf16x8*>(Wq + (size_t)((wd + mi*16 + l15) * 256 + k0));
      #pragma unroll
      for (int ni = 0; ni < 4; ++ni)
        bb[ni] = *reinterpret_cast<const bf16x8*>(&R0[(ni*16 + l15) * 264 + k0]);
      #pragma unroll
      for (int mi = 0; mi < 4; ++mi)
        #pragma unroll
        for (int ni = 0; ni < 4; ++ni)
          acc[mi][ni] = MFMA16(a[mi], bb[ni], acc[mi][ni], 0, 0, 0);
    }
    #pragma unroll
    for (int mi = 0; mi < 4; ++mi){
      int d0 = wd + mi*16 + l4*4;
      #pragma unroll
      for (int ni = 0; ni < 4; ++ni)
        store_bf4(&R3[(ni*16 + l15) * 264 + d0], acc[mi][ni]);
    }
  }
  __syncthreads();

  int h = w >> 1, tc = w & 1;
  {
    f32x4 s[4][2];
    #pragma unroll
    for (int i = 0; i < 4; ++i){ s[i][0] = f32x4{0.f,0.f,0.f,0.f}; s[i][1] = f32x4{0.f,0.f,0.f,0.f}; }
    #pragma unroll
    for (int ks = 0; ks < 4; ++ks){
      int k0 = h * 128 + ks * 32 + l4 * 8;
      bf16x8 a[4], bb[2];
      #pragma unroll
      for (int mi = 0; mi < 4; ++mi)
        a[mi] = *reinterpret_cast<const bf16x8*>(&R1[(mi*16 + l15) * 264 + k0]);
      #pragma unroll
      for (int ni = 0; ni < 2; ++ni)
        bb[ni] = *reinterpret_cast<const bf16x8*>(&R3[(tc*32 + ni*16 + l15) * 264 + k0]);
      #pragma unroll
      for (int mi = 0; mi < 4; ++mi)
        #pragma unroll
        for (int ni = 0; ni < 2; ++ni)
          s[mi][ni] = MFMA16(a[mi], bb[ni], s[mi][ni], 0, 0, 0);
    }
    __syncthreads();
    const float SCL = 0.08838834764831845f;
    unsigned short* P = R1;
    #pragma unroll
    for (int ni = 0; ni < 2; ++ni){
      float m = s[0][ni][0];
      #pragma unroll
      for (int mi = 0; mi < 4; ++mi)
        #pragma unroll
        for (int reg = 0; reg < 4; ++reg) m = fmaxf(m, s[mi][ni][reg]);
      m = fmaxf(m, __shfl_xor(m, 16));
      m = fmaxf(m, __shfl_xor(m, 32));
      float sum = 0.f;
      #pragma unroll
      for (int mi = 0; mi < 4; ++mi)
        #pragma unroll
        for (int reg = 0; reg < 4; ++reg){
          float e = __expf((s[mi][ni][reg] - m) * SCL);
          s[mi][ni][reg] = e; sum += e;
        }
      sum += __shfl_xor(sum, 16);
      sum += __shfl_xor(sum, 32);
      float rs = 1.0f / sum;
      int t = tc*32 + ni*16 + l15;
      #pragma unroll
      for (int mi = 0; mi < 4; ++mi){
        f32x4 pv;
        #pragma unroll
        for (int reg = 0; reg < 4; ++reg) pv[reg] = s[mi][ni][reg] * rs;
        store_bf4(&P[h * 4608 + t * 72 + mi*16 + l4*4], pv);
      }
    }
  }
  __syncthreads();
  {
    int wdh = h * 128 + tc * 64;
    f32x4 acc[4][4];
    #pragma unroll
    for (int i = 0; i < 4; ++i)
      #pragma unroll
      for (int j = 0; j < 4; ++j) acc[i][j] = f32x4{0.f,0.f,0.f,0.f};
    const unsigned short* P = R1;
    #pragma unroll
    for (int ks = 0; ks < 2; ++ks){
      int k0 = ks * 32 + l4 * 8;
      bf16x8 a[4], bb[4];
      #pragma unroll
      for (int mi = 0; mi < 4; ++mi)
        a[mi] = *reinterpret_cast<const bf16x8*>(&R2[(wdh + mi*16 + l15) * 72 + k0]);
      #pragma unroll
      for (int ni = 0; ni < 4; ++ni)
        bb[ni] = *reinterpret_cast<const bf16x8*>(&P[h * 4608 + (ni*16 + l15) * 72 + k0]);
      #pragma unroll
      for (int mi = 0; mi < 4; ++mi)
        #pragma unroll
        for (int ni = 0; ni < 4; ++ni)
          acc[mi][ni] = MFMA16(a[mi], bb[ni], acc[mi][ni], 0, 0, 0);
    }
    #pragma unroll
    for (int mi = 0; mi < 4; ++mi){
      int c0 = wdh + mi*16 + l4*4;
      #pragma unroll
      for (int ni = 0; ni < 4; ++ni)
        store_bf4(&R0[(ni*16 + l15) * 264 + c0], acc[mi][ni]);
    }
  }
  __syncthreads();
  {
    f32x4 acc[4][4];
    #pragma unroll
    for (int i = 0; i < 4; ++i)
      #pragma unroll
      for (int j = 0; j < 4; ++j) acc[i][j] = f32x4{0.f,0.f,0.f,0.f};
    #pragma unroll
    for (int ks = 0; ks < 8; ++ks){
      int k0 = ks * 32 + l4 * 8;
      bf16x8 a[4], bb[4];
      #pragma unroll
      for (int mi = 0; mi < 4; ++mi)
        a[mi] = *reinterpret_cast<const bf16x8*>(Wo + (size_t)((wd + mi*16 + l15) * 256 + k0));
      #pragma unroll
      for (int ni = 0; ni < 4; ++ni)
        bb[ni] = *reinterpret_cast<const bf16x8*>(&R0[(ni*16 + l15) * 264 + k0]);
      #pragma unroll
      for (int mi = 0; mi < 4; ++mi)
        #pragma unroll
        for (int ni = 0; ni < 4; ++ni)
          acc[mi][ni] = MFMA16(a[mi], bb[ni], acc[mi][ni], 0, 0, 0);
    }
    #pragma unroll
    for (int mi = 0; mi < 4; ++mi){
      #pragma unroll
      for (int ni = 0; ni < 4; ++ni){
        int t = ni*16 + l15, thi = t >> 3, twi = t & 7;
        size_t base = (size_t)(wd + mi*16 + l4*4) * g.HW + (size_t)thi * g.W + twi;
        #pragma unroll
        for (int reg = 0; reg < 4; ++reg){
          float res = xsrc[base + (size_t)reg * g.HW];
          float v = acc[mi][ni][reg] + res;
          outp[base + (size_t)reg * g.HW] = fmaxf(v, 0.f);
        }
      }
    }
  }
}

extern "C" void kernel_launch(void* const* d_in, const int* in_sizes, int n_in,
                              void* d_out, int out_size, void* d_ws, size_t ws_size,
                              hipStream_t stream) {
  (void)in_sizes; (void)n_in; (void)out_size;
  const float* f0 = (const float*)d_in[0];
  const float* f1 = (const float*)d_in[1];
  const float* f2 = (const float*)d_in[2];
  const float* f3 = (const float*)d_in[3];
  const float* w1 = (const float*)d_in[4];
  const float* w2 = (const float*)d_in[5];
  float* out = (float*)d_out;

  unsigned short* wbf = (unsigned short*)d_ws;
  const size_t WBF_B = 4194304;       // 2*16*65536 bf16
  const size_t FT_B  = 44564480;      // 87040 tokens * 256 * 2B
  const size_t need  = WBF_B + 2 * FT_B;   // 93,323,264

  wcvt_kernel<<<2048, 256, 0, stream>>>(w1, w2, wbf);

  if (ws_size >= need){
    char* base = (char*)d_ws + WBF_B;
    unsigned short* Ft = (unsigned short*)(base);
    unsigned short* Gt = (unsigned short*)(base + FT_B);

    xpose_kernel<<<5440, 256, 0, stream>>>(f0, f1, f2, f3, Ft);
    for (int phase = 0; phase < 2; ++phase)
      swin_win<<<680, 256, 0, stream>>>(Ft, Gt, wbf, Gt, phase);
    untrans_kernel<<<5440, 256, 0, stream>>>(Gt, out);
  } else {
    swin_phase<<<680, 256, 0, stream>>>(f0, f1, f2, f3, wbf, out, 0);
    swin_phase<<<680, 256, 0, stream>>>(f0, f1, f2, f3, wbf, out, 1);
  }
}

// Round 11
// 220.525 us; speedup vs baseline: 1.1103x; 1.0086x over previous
//
#include <hip/hip_runtime.h>

// Swin cross-attention pipeline v11 for MI355X.
// v10 regressed (K+Q merge lengthened the serial chain). v11 = v8's proven
// per-phase choreography with two structural fixes:
//  (1) Phase A + Phase B fused per window (windows partition identically in
//      both phases, so f1' window i is produced by the same block): phase A's
//      flush writes f1' back into LDS A; phase B's K/V GEMM reads tokens from
//      LDS. Removes the inter-phase dispatch barrier + one grid tail + the
//      f1' global re-read.
//  (2) Grid balanced at 512 blocks (=2/CU exactly): blocks b%3==0 (b<504)
//      process window 512+b/3 as a second window. One scheduling round
//      instead of two (v8/v10: 680 blocks over 512 slots = 2 rounds, second
//      at 33% utilization).
// LDS regions unchanged: A[64*264] 33.8KB, B[256*72] 36.9KB -> 2 blocks/CU.

using bf16x8 = __attribute__((ext_vector_type(8))) __bf16;
using f32x4  = __attribute__((ext_vector_type(4))) float;
using u16x4  = __attribute__((ext_vector_type(4))) unsigned short;
using u16x8  = __attribute__((ext_vector_type(8))) unsigned short;

__device__ __forceinline__ unsigned short f2bf(float f){
  unsigned int x = __float_as_uint(f);
  x += 0x7FFFu + ((x >> 16) & 1u);          // RNE
  return (unsigned short)(x >> 16);
}
__device__ __forceinline__ float bf2f(unsigned short u){
  return __uint_as_float((unsigned int)u << 16);
}
__device__ __forceinline__ void store_bf4(unsigned short* dst, f32x4 v){
  u16x4 o;
  o[0]=f2bf(v[0]); o[1]=f2bf(v[1]); o[2]=f2bf(v[2]); o[3]=f2bf(v[3]);
  *reinterpret_cast<u16x4*>(dst) = o;
}

#define MFMA16 __builtin_amdgcn_mfma_f32_16x16x32_bf16

__global__ void wcvt_kernel(const float* __restrict__ w1,
                            const float* __restrict__ w2,
                            unsigned short* __restrict__ dst){
  int i = blockIdx.x * 256 + threadIdx.x;
  const float4* src = (i < 262144) ? (reinterpret_cast<const float4*>(w1) + i)
                                   : (reinterpret_cast<const float4*>(w2) + (i - 262144));
  float4 v = *src;
  u16x4 o; o[0]=f2bf(v.x); o[1]=f2bf(v.y); o[2]=f2bf(v.z); o[3]=f2bf(v.w);
  reinterpret_cast<u16x4*>(dst)[i] = o;
}

// ---- transpose fp32 [C,HW] -> bf16 Ft[token][c] -----------------------------
__global__ __launch_bounds__(256, 2) void xpose_kernel(
    const float* __restrict__ g0, const float* __restrict__ g1,
    const float* __restrict__ g2, const float* __restrict__ g3,
    unsigned short* __restrict__ Ft)
{
  __shared__ float T[64][65];
  int bid = blockIdx.x;
  int r; const float* feat; int Hl; size_t tbase;
  if (bid < 4096){ r = bid;        feat = g0; Hl = 128; tbase = 0; }
  else if (bid < 5120){ r = bid - 4096; feat = g1; Hl = 64;  tbase = 65536; }
  else if (bid < 5376){ r = bid - 5120; feat = g2; Hl = 32;  tbase = 81920; }
  else { r = bid - 5376; feat = g3; Hl = 16;  tbase = 86016; }
  size_t HW = (size_t)Hl * Hl;
  int hw64 = (int)(HW >> 6);
  int bat = r / (4 * hw64);
  int r2 = r - bat * 4 * hw64;
  int ct = r2 / hw64, hwt = r2 - ct * hw64;

  const float* src = feat + (size_t)bat * HW * 256 + (size_t)(ct * 64) * HW + (size_t)hwt * 64;
  int tid = threadIdx.x;
  int cq = tid >> 4, hw0 = (tid & 15) * 4;
  #pragma unroll
  for (int p = 0; p < 4; ++p){
    int c = p * 16 + cq;
    const float* sp = src + (size_t)c * HW + hw0;
    float4 v = *reinterpret_cast<const float4*>(sp);
    T[c][hw0] = v.x; T[c][hw0+1] = v.y; T[c][hw0+2] = v.z; T[c][hw0+3] = v.w;
  }
  __syncthreads();
  unsigned short* dst = Ft + (tbase + (size_t)bat * HW + (size_t)hwt * 64) * 256 + ct * 64;
  #pragma unroll
  for (int p = 0; p < 2; ++p){
    int id = p * 256 + tid;
    int t = id >> 3, c0 = (id & 7) * 8;
    u16x8 o;
    #pragma unroll
    for (int j = 0; j < 8; ++j) o[j] = f2bf(T[c0 + j][t]);
    *reinterpret_cast<u16x8*>(dst + (size_t)t * 256 + c0) = o;
  }
}

// ---- transpose back: Gt[token][c] bf16 -> fp32 out [C,HW], ALL 4 batches ----
__global__ __launch_bounds__(256, 2) void untrans_kernel(
    const unsigned short* __restrict__ Gt, float* __restrict__ outb)
{
  __shared__ float T[64][65];
  int bid = blockIdx.x;
  int r; int Hl; size_t tbase, ooff;
  if (bid < 4096){ r = bid;        Hl = 128; tbase = 0;     ooff = 0; }
  else if (bid < 5120){ r = bid - 4096; Hl = 64; tbase = 65536; ooff = 16777216; }
  else if (bid < 5376){ r = bid - 5120; Hl = 32; tbase = 81920; ooff = 20971520; }
  else { r = bid - 5376; Hl = 16; tbase = 86016; ooff = 22020096; }
  size_t HW = (size_t)Hl * Hl;
  int hw64 = (int)(HW >> 6);
  int bat = r / (4 * hw64);
  int r2 = r - bat * 4 * hw64;
  int ct = r2 / hw64, hwt = r2 - ct * hw64;

  const unsigned short* src = Gt + (tbase + (size_t)bat * HW + (size_t)hwt * 64) * 256 + ct * 64;
  int tid = threadIdx.x;
  #pragma unroll
  for (int p = 0; p < 2; ++p){
    int id = p * 256 + tid;
    int t = id >> 3, c0 = (id & 7) * 8;
    u16x8 v = *reinterpret_cast<const u16x8*>(src + (size_t)t * 256 + c0);
    #pragma unroll
    for (int j = 0; j < 8; ++j) T[t][c0 + j] = bf2f(v[j]);
  }
  __syncthreads();
  float* dst = outb + ooff + (size_t)bat * HW * 256 + (size_t)(ct * 64) * HW + (size_t)hwt * 64;
  int cq = tid >> 4, hw0 = (tid & 15) * 4;
  #pragma unroll
  for (int p = 0; p < 4; ++p){
    int c = p * 16 + cq;
    float4 v;
    v.x = T[hw0][c]; v.y = T[hw0+1][c]; v.z = T[hw0+2][c]; v.w = T[hw0+3][c];
    *reinterpret_cast<float4*>(dst + (size_t)c * HW + hw0) = v;
  }
}

// ---- window geometry --------------------------------------------------------
struct WinGeo { int H, W, b, lvl; size_t HW, winoff, tbase, ooff; };

__device__ __forceinline__ WinGeo decode_win(int win){
  WinGeo g; int wloc;
  if (win < 512){ g.lvl = 0; wloc = win;      g.H = 128; g.tbase = 0;     g.ooff = 0; }
  else if (win < 640){ g.lvl = 1; wloc = win - 512; g.H = 64; g.tbase = 65536; g.ooff = 16777216; }
  else if (win < 672){ g.lvl = 2; wloc = win - 640; g.H = 32; g.tbase = 81920; g.ooff = 20971520; }
  else { g.lvl = 3; wloc = win - 672; g.H = 16; g.tbase = 86016; g.ooff = 22020096; }
  g.W = g.H; g.HW = (size_t)g.H * g.W;
  int nww = g.H >> 3, npb = nww * nww;
  g.b = wloc / npb;
  int r = wloc - g.b * npb;
  int wh = r / nww, ww = r - wh * nww;
  g.winoff = (size_t)(wh * 8) * g.W + (size_t)(ww * 8);
  return g;
}

// ---- v11: fully fused double-phase per-window kernel ------------------------
__global__ __launch_bounds__(256, 2) void swin_fused(
    const unsigned short* __restrict__ Ft,
    const unsigned short* __restrict__ wball,
    unsigned short* __restrict__ Gt)
{
  __shared__ alignas(16) unsigned short A[64*264];   // K/Q' -> P -> O -> out -> f1'
  __shared__ alignas(16) unsigned short B[256*72];   // Q/K' ([64][264] view) -> V^T
  int bid = blockIdx.x;
  int tid = threadIdx.x;
  int w = tid >> 6, l = tid & 63, l15 = l & 15, l4 = l >> 4, wd = w * 64;
  int h = w >> 1, tc = w & 1;
  const float SCL = 0.08838834764831845f;   // 1/sqrt(128)

  int nwin = ((bid % 3) == 0 && bid < 504) ? 2 : 1;
  for (int wi = 0; wi < nwin; ++wi){
    if (wi) __syncthreads();
    int win = wi ? (512 + bid / 3) : bid;
    WinGeo g = decode_win(win);
    const unsigned short* Sx = Ft + (g.tbase + (size_t)g.b * g.HW) * 256;         // f1
    const unsigned short* Sy = Ft + (g.tbase + (size_t)(g.b + 2) * g.HW) * 256;   // f2
    unsigned short* GoutA = Gt + (g.tbase + (size_t)g.b * g.HW) * 256;
    unsigned short* GoutB = Gt + (g.tbase + (size_t)(g.b + 2) * g.HW) * 256;

    size_t rowo[4];
    #pragma unroll
    for (int ni = 0; ni < 4; ++ni){
      int t = ni * 16 + l15;
      rowo[ni] = ((size_t)g.winoff + (size_t)(t >> 3) * g.W + (t & 7)) * 256;
    }
    const unsigned short* W1 = wball + ((size_t)(g.lvl * 4) << 16);          // phase A weights
    const unsigned short* W2 = wball + ((size_t)(16 + g.lvl * 4) << 16);     // phase B weights

    // ======================= PHASE A =======================
    {
      // ---- K & V GEMMs (tokens = Sy global); K->A, V acc in regs ----
      f32x4 av[4][4];
      {
        f32x4 ak[4][4];
        #pragma unroll
        for (int i = 0; i < 4; ++i)
          #pragma unroll
          for (int j = 0; j < 4; ++j){ ak[i][j] = f32x4{0.f,0.f,0.f,0.f}; av[i][j] = f32x4{0.f,0.f,0.f,0.f}; }
        #pragma unroll
        for (int ks = 0; ks < 8; ++ks){
          int k0 = ks * 32 + l4 * 8;
          bf16x8 tf[4], kf[4], vf[4];
          #pragma unroll
          for (int i = 0; i < 4; ++i){
            tf[i] = *reinterpret_cast<const bf16x8*>(Sy + rowo[i] + k0);
            kf[i] = *reinterpret_cast<const bf16x8*>(W1 + 65536 + (size_t)((wd + i*16 + l15) * 256 + k0));
            vf[i] = *reinterpret_cast<const bf16x8*>(W1 + 131072 + (size_t)((wd + i*16 + l15) * 256 + k0));
          }
          __builtin_amdgcn_s_setprio(1);
          #pragma unroll
          for (int mi = 0; mi < 4; ++mi)
            #pragma unroll
            for (int ni = 0; ni < 4; ++ni){
              ak[mi][ni] = MFMA16(kf[mi], tf[ni], ak[mi][ni], 0, 0, 0);
              av[mi][ni] = MFMA16(tf[mi], vf[ni], av[mi][ni], 0, 0, 0);
            }
          __builtin_amdgcn_s_setprio(0);
        }
        #pragma unroll
        for (int mi = 0; mi < 4; ++mi){
          int d0 = wd + mi*16 + l4*4;
          #pragma unroll
          for (int ni = 0; ni < 4; ++ni)
            store_bf4(&A[(ni*16 + l15) * 264 + d0], ak[mi][ni]);
        }
      }
      // ---- Q GEMM (tokens = Sx global) -> B ----
      {
        f32x4 aq[4][4];
        #pragma unroll
        for (int i = 0; i < 4; ++i)
          #pragma unroll
          for (int j = 0; j < 4; ++j) aq[i][j] = f32x4{0.f,0.f,0.f,0.f};
        #pragma unroll
        for (int ks = 0; ks < 8; ++ks){
          int k0 = ks * 32 + l4 * 8;
          bf16x8 tf[4], wf[4];
          #pragma unroll
          for (int i = 0; i < 4; ++i){
            tf[i] = *reinterpret_cast<const bf16x8*>(Sx + rowo[i] + k0);
            wf[i] = *reinterpret_cast<const bf16x8*>(W1 + (size_t)((wd + i*16 + l15) * 256 + k0));
          }
          __builtin_amdgcn_s_setprio(1);
          #pragma unroll
          for (int mi = 0; mi < 4; ++mi)
            #pragma unroll
            for (int ni = 0; ni < 4; ++ni)
              aq[mi][ni] = MFMA16(wf[mi], tf[ni], aq[mi][ni], 0, 0, 0);
          __builtin_amdgcn_s_setprio(0);
        }
        #pragma unroll
        for (int mi = 0; mi < 4; ++mi){
          int d0 = wd + mi*16 + l4*4;
          #pragma unroll
          for (int ni = 0; ni < 4; ++ni)
            store_bf4(&B[(ni*16 + l15) * 264 + d0], aq[mi][ni]);
        }
      }
      __syncthreads();   // K(A), Q(B) visible

      // ---- S^T[u][t]: a=K(A), b=Q(B) ----
      f32x4 s[4][2];
      #pragma unroll
      for (int i = 0; i < 4; ++i){ s[i][0] = f32x4{0.f,0.f,0.f,0.f}; s[i][1] = f32x4{0.f,0.f,0.f,0.f}; }
      #pragma unroll
      for (int ks = 0; ks < 4; ++ks){
        int k0 = h * 128 + ks * 32 + l4 * 8;
        bf16x8 a[4], bb[2];
        #pragma unroll
        for (int mi = 0; mi < 4; ++mi)
          a[mi] = *reinterpret_cast<const bf16x8*>(&A[(mi*16 + l15) * 264 + k0]);
        #pragma unroll
        for (int ni = 0; ni < 2; ++ni)
          bb[ni] = *reinterpret_cast<const bf16x8*>(&B[(tc*32 + ni*16 + l15) * 264 + k0]);
        __builtin_amdgcn_s_setprio(1);
        #pragma unroll
        for (int mi = 0; mi < 4; ++mi)
          #pragma unroll
          for (int ni = 0; ni < 2; ++ni)
            s[mi][ni] = MFMA16(a[mi], bb[ni], s[mi][ni], 0, 0, 0);
        __builtin_amdgcn_s_setprio(0);
      }
      __syncthreads();   // K,Q consumed; A free for P, B free for V^T

      // ---- V^T (regs) -> B ----
      #pragma unroll
      for (int mi = 0; mi < 4; ++mi){
        int u0 = mi*16 + l4*4;
        #pragma unroll
        for (int ni = 0; ni < 4; ++ni)
          store_bf4(&B[(wd + ni*16 + l15) * 72 + u0], av[mi][ni]);
      }
      // ---- softmax -> P(A 72-view) ----
      #pragma unroll
      for (int ni = 0; ni < 2; ++ni){
        float m = s[0][ni][0];
        #pragma unroll
        for (int mi = 0; mi < 4; ++mi)
          #pragma unroll
          for (int reg = 0; reg < 4; ++reg) m = fmaxf(m, s[mi][ni][reg]);
        m = fmaxf(m, __shfl_xor(m, 16));
        m = fmaxf(m, __shfl_xor(m, 32));
        float sum = 0.f;
        #pragma unroll
        for (int mi = 0; mi < 4; ++mi)
          #pragma unroll
          for (int reg = 0; reg < 4; ++reg){
            float e = __expf((s[mi][ni][reg] - m) * SCL);
            s[mi][ni][reg] = e; sum += e;
          }
        sum += __shfl_xor(sum, 16);
        sum += __shfl_xor(sum, 32);
        float rs = 1.0f / sum;
        int t = tc*32 + ni*16 + l15;
        #pragma unroll
        for (int mi = 0; mi < 4; ++mi){
          f32x4 pv;
          #pragma unroll
          for (int reg = 0; reg < 4; ++reg) pv[reg] = s[mi][ni][reg] * rs;
          store_bf4(&A[h * 4608 + t * 72 + mi*16 + l4*4], pv);
        }
      }
      __syncthreads();   // P(A), V^T(B) visible

      // ---- O^T = V^T * P^T ----
      f32x4 acc[4][4];
      #pragma unroll
      for (int i = 0; i < 4; ++i)
        #pragma unroll
        for (int j = 0; j < 4; ++j) acc[i][j] = f32x4{0.f,0.f,0.f,0.f};
      #pragma unroll
      for (int ks = 0; ks < 2; ++ks){
        int k0 = ks * 32 + l4 * 8;
        bf16x8 a[4], bb[4];
        #pragma unroll
        for (int mi = 0; mi < 4; ++mi)
          a[mi] = *reinterpret_cast<const bf16x8*>(&B[(wd + mi*16 + l15) * 72 + k0]);
        #pragma unroll
        for (int ni = 0; ni < 4; ++ni)
          bb[ni] = *reinterpret_cast<const bf16x8*>(&A[h * 4608 + (ni*16 + l15) * 72 + k0]);
        __builtin_amdgcn_s_setprio(1);
        #pragma unroll
        for (int mi = 0; mi < 4; ++mi)
          #pragma unroll
          for (int ni = 0; ni < 4; ++ni)
            acc[mi][ni] = MFMA16(a[mi], bb[ni], acc[mi][ni], 0, 0, 0);
        __builtin_amdgcn_s_setprio(0);
      }
      __syncthreads();   // P consumed; A free for O
      #pragma unroll
      for (int mi = 0; mi < 4; ++mi){
        int c0 = wd + mi*16 + l4*4;
        #pragma unroll
        for (int ni = 0; ni < 4; ++ni)
          store_bf4(&A[(ni*16 + l15) * 264 + c0], acc[mi][ni]);
      }
      __syncthreads();   // O(A) visible

      // ---- out^T = Wo * o^T ----
      #pragma unroll
      for (int i = 0; i < 4; ++i)
        #pragma unroll
        for (int j = 0; j < 4; ++j) acc[i][j] = f32x4{0.f,0.f,0.f,0.f};
      #pragma unroll
      for (int ks = 0; ks < 8; ++ks){
        int k0 = ks * 32 + l4 * 8;
        bf16x8 a[4], bb[4];
        #pragma unroll
        for (int mi = 0; mi < 4; ++mi)
          a[mi] = *reinterpret_cast<const bf16x8*>(W1 + 196608 + (size_t)((wd + mi*16 + l15) * 256 + k0));
        #pragma unroll
        for (int ni = 0; ni < 4; ++ni)
          bb[ni] = *reinterpret_cast<const bf16x8*>(&A[(ni*16 + l15) * 264 + k0]);
        __builtin_amdgcn_s_setprio(1);
        #pragma unroll
        for (int mi = 0; mi < 4; ++mi)
          #pragma unroll
          for (int ni = 0; ni < 4; ++ni)
            acc[mi][ni] = MFMA16(a[mi], bb[ni], acc[mi][ni], 0, 0, 0);
        __builtin_amdgcn_s_setprio(0);
      }
      __syncthreads();   // O consumed; A free for out tile
      #pragma unroll
      for (int mi = 0; mi < 4; ++mi){
        int c0 = wd + mi*16 + l4*4;
        #pragma unroll
        for (int ni = 0; ni < 4; ++ni)
          store_bf4(&A[(ni*16 + l15) * 264 + c0], acc[mi][ni]);
      }
      __syncthreads();   // out(A) visible

      // ---- flush: f1' = relu(out + f1) -> Gt AND write back into A ----
      #pragma unroll
      for (int p = 0; p < 8; ++p){
        int id = p * 256 + tid;
        int t = id >> 5, c = (id & 31) * 8;
        size_t ro = ((size_t)g.winoff + (size_t)(t >> 3) * g.W + (t & 7)) * 256 + c;
        u16x8 ov = *reinterpret_cast<const u16x8*>(&A[t * 264 + c]);
        u16x8 rv = *reinterpret_cast<const u16x8*>(Sx + ro);
        u16x8 o;
        #pragma unroll
        for (int j = 0; j < 8; ++j)
          o[j] = f2bf(fmaxf(bf2f(ov[j]) + bf2f(rv[j]), 0.f));
        *reinterpret_cast<u16x8*>(GoutA + ro) = o;
        *reinterpret_cast<u16x8*>(&A[t * 264 + c]) = o;   // f1' stays in LDS
      }
      __syncthreads();   // f1'(A) visible
    }

    // ======================= PHASE B =======================
    {
      // ---- K2 & V2 GEMMs (tokens = f1' in LDS A); K2->B, V2 acc in regs ----
      f32x4 av[4][4];
      {
        f32x4 ak[4][4];
        #pragma unroll
        for (int i = 0; i < 4; ++i)
          #pragma unroll
          for (int j = 0; j < 4; ++j){ ak[i][j] = f32x4{0.f,0.f,0.f,0.f}; av[i][j] = f32x4{0.f,0.f,0.f,0.f}; }
        #pragma unroll
        for (int ks = 0; ks < 8; ++ks){
          int k0 = ks * 32 + l4 * 8;
          bf16x8 tf[4], kf[4], vf[4];
          #pragma unroll
          for (int i = 0; i < 4; ++i){
            tf[i] = *reinterpret_cast<const bf16x8*>(&A[(i*16 + l15) * 264 + k0]);   // f1' from LDS
            kf[i] = *reinterpret_cast<const bf16x8*>(W2 + 65536 + (size_t)((wd + i*16 + l15) * 256 + k0));
            vf[i] = *reinterpret_cast<const bf16x8*>(W2 + 131072 + (size_t)((wd + i*16 + l15) * 256 + k0));
          }
          __builtin_amdgcn_s_setprio(1);
          #pragma unroll
          for (int mi = 0; mi < 4; ++mi)
            #pragma unroll
            for (int ni = 0; ni < 4; ++ni){
              ak[mi][ni] = MFMA16(kf[mi], tf[ni], ak[mi][ni], 0, 0, 0);
              av[mi][ni] = MFMA16(tf[mi], vf[ni], av[mi][ni], 0, 0, 0);
            }
          __builtin_amdgcn_s_setprio(0);
        }
        #pragma unroll
        for (int mi = 0; mi < 4; ++mi){
          int d0 = wd + mi*16 + l4*4;
          #pragma unroll
          for (int ni = 0; ni < 4; ++ni)
            store_bf4(&B[(ni*16 + l15) * 264 + d0], ak[mi][ni]);   // K2 -> B
        }
      }
      __syncthreads();   // f1'(A) consumed; A free for Q2

      // ---- Q2 GEMM (tokens = f2 = Sy global) -> A ----
      {
        f32x4 aq[4][4];
        #pragma unroll
        for (int i = 0; i < 4; ++i)
          #pragma unroll
          for (int j = 0; j < 4; ++j) aq[i][j] = f32x4{0.f,0.f,0.f,0.f};
        #pragma unroll
        for (int ks = 0; ks < 8; ++ks){
          int k0 = ks * 32 + l4 * 8;
          bf16x8 tf[4], wf[4];
          #pragma unroll
          for (int i = 0; i < 4; ++i){
            tf[i] = *reinterpret_cast<const bf16x8*>(Sy + rowo[i] + k0);
            wf[i] = *reinterpret_cast<const bf16x8*>(W2 + (size_t)((wd + i*16 + l15) * 256 + k0));
          }
          __builtin_amdgcn_s_setprio(1);
          #pragma unroll
          for (int mi = 0; mi < 4; ++mi)
            #pragma unroll
            for (int ni = 0; ni < 4; ++ni)
              aq[mi][ni] = MFMA16(wf[mi], tf[ni], aq[mi][ni], 0, 0, 0);
          __builtin_amdgcn_s_setprio(0);
        }
        #pragma unroll
        for (int mi = 0; mi < 4; ++mi){
          int d0 = wd + mi*16 + l4*4;
          #pragma unroll
          for (int ni = 0; ni < 4; ++ni)
            store_bf4(&A[(ni*16 + l15) * 264 + d0], aq[mi][ni]);   // Q2 -> A
        }
      }
      __syncthreads();   // K2(B), Q2(A) visible

      // ---- S2^T[u][t]: a=K2(B), b=Q2(A) ----
      f32x4 s[4][2];
      #pragma unroll
      for (int i = 0; i < 4; ++i){ s[i][0] = f32x4{0.f,0.f,0.f,0.f}; s[i][1] = f32x4{0.f,0.f,0.f,0.f}; }
      #pragma unroll
      for (int ks = 0; ks < 4; ++ks){
        int k0 = h * 128 + ks * 32 + l4 * 8;
        bf16x8 a[4], bb[2];
        #pragma unroll
        for (int mi = 0; mi < 4; ++mi)
          a[mi] = *reinterpret_cast<const bf16x8*>(&B[(mi*16 + l15) * 264 + k0]);
        #pragma unroll
        for (int ni = 0; ni < 2; ++ni)
          bb[ni] = *reinterpret_cast<const bf16x8*>(&A[(tc*32 + ni*16 + l15) * 264 + k0]);
        __builtin_amdgcn_s_setprio(1);
        #pragma unroll
        for (int mi = 0; mi < 4; ++mi)
          #pragma unroll
          for (int ni = 0; ni < 2; ++ni)
            s[mi][ni] = MFMA16(a[mi], bb[ni], s[mi][ni], 0, 0, 0);
        __builtin_amdgcn_s_setprio(0);
      }
      __syncthreads();   // K2,Q2 consumed; A free for P2, B free for V2^T

      // ---- V2^T (regs) -> B ----
      #pragma unroll
      for (int mi = 0; mi < 4; ++mi){
        int u0 = mi*16 + l4*4;
        #pragma unroll
        for (int ni = 0; ni < 4; ++ni)
          store_bf4(&B[(wd + ni*16 + l15) * 72 + u0], av[mi][ni]);
      }
      // ---- softmax -> P2(A 72-view) ----
      #pragma unroll
      for (int ni = 0; ni < 2; ++ni){
        float m = s[0][ni][0];
        #pragma unroll
        for (int mi = 0; mi < 4; ++mi)
          #pragma unroll
          for (int reg = 0; reg < 4; ++reg) m = fmaxf(m, s[mi][ni][reg]);
        m = fmaxf(m, __shfl_xor(m, 16));
        m = fmaxf(m, __shfl_xor(m, 32));
        float sum = 0.f;
        #pragma unroll
        for (int mi = 0; mi < 4; ++mi)
          #pragma unroll
          for (int reg = 0; reg < 4; ++reg){
            float e = __expf((s[mi][ni][reg] - m) * SCL);
            s[mi][ni][reg] = e; sum += e;
          }
        sum += __shfl_xor(sum, 16);
        sum += __shfl_xor(sum, 32);
        float rs = 1.0f / sum;
        int t = tc*32 + ni*16 + l15;
        #pragma unroll
        for (int mi = 0; mi < 4; ++mi){
          f32x4 pv;
          #pragma unroll
          for (int reg = 0; reg < 4; ++reg) pv[reg] = s[mi][ni][reg] * rs;
          store_bf4(&A[h * 4608 + t * 72 + mi*16 + l4*4], pv);
        }
      }
      __syncthreads();   // P2(A), V2^T(B) visible

      // ---- O2^T = V2^T * P2^T ----
      f32x4 acc[4][4];
      #pragma unroll
      for (int i = 0; i < 4; ++i)
        #pragma unroll
        for (int j = 0; j < 4; ++j) acc[i][j] = f32x4{0.f,0.f,0.f,0.f};
      #pragma unroll
      for (int ks = 0; ks < 2; ++ks){
        int k0 = ks * 32 + l4 * 8;
        bf16x8 a[4], bb[4];
        #pragma unroll
        for (int mi = 0; mi < 4; ++mi)
          a[mi] = *reinterpret_cast<const bf16x8*>(&B[(wd + mi*16 + l15) * 72 + k0]);
        #pragma unroll
        for (int ni = 0; ni < 4; ++ni)
          bb[ni] = *reinterpret_cast<const bf16x8*>(&A[h * 4608 + (ni*16 + l15) * 72 + k0]);
        __builtin_amdgcn_s_setprio(1);
        #pragma unroll
        for (int mi = 0; mi < 4; ++mi)
          #pragma unroll
          for (int ni = 0; ni < 4; ++ni)
            acc[mi][ni] = MFMA16(a[mi], bb[ni], acc[mi][ni], 0, 0, 0);
        __builtin_amdgcn_s_setprio(0);
      }
      __syncthreads();   // P2 consumed; A free for O2
      #pragma unroll
      for (int mi = 0; mi < 4; ++mi){
        int c0 = wd + mi*16 + l4*4;
        #pragma unroll
        for (int ni = 0; ni < 4; ++ni)
          store_bf4(&A[(ni*16 + l15) * 264 + c0], acc[mi][ni]);
      }
      __syncthreads();   // O2(A) visible

      // ---- out2^T = Wo2 * o2^T ----
      #pragma unroll
      for (int i = 0; i < 4; ++i)
        #pragma unroll
        for (int j = 0; j < 4; ++j) acc[i][j] = f32x4{0.f,0.f,0.f,0.f};
      #pragma unroll
      for (int ks = 0; ks < 8; ++ks){
        int k0 = ks * 32 + l4 * 8;
        bf16x8 a[4], bb[4];
        #pragma unroll
        for (int mi = 0; mi < 4; ++mi)
          a[mi] = *reinterpret_cast<const bf16x8*>(W2 + 196608 + (size_t)((wd + mi*16 + l15) * 256 + k0));
        #pragma unroll
        for (int ni = 0; ni < 4; ++ni)
          bb[ni] = *reinterpret_cast<const bf16x8*>(&A[(ni*16 + l15) * 264 + k0]);
        __builtin_amdgcn_s_setprio(1);
        #pragma unroll
        for (int mi = 0; mi < 4; ++mi)
          #pragma unroll
          for (int ni = 0; ni < 4; ++ni)
            acc[mi][ni] = MFMA16(a[mi], bb[ni], acc[mi][ni], 0, 0, 0);
        __builtin_amdgcn_s_setprio(0);
      }
      __syncthreads();   // O2 consumed; A free for out2 tile
      #pragma unroll
      for (int mi = 0; mi < 4; ++mi){
        int c0 = wd + mi*16 + l4*4;
        #pragma unroll
        for (int ni = 0; ni < 4; ++ni)
          store_bf4(&A[(ni*16 + l15) * 264 + c0], acc[mi][ni]);
      }
      __syncthreads();   // out2(A) visible

      // ---- flush: f2' = relu(out2 + f2) -> Gt ----
      #pragma unroll
      for (int p = 0; p < 8; ++p){
        int id = p * 256 + tid;
        int t = id >> 5, c = (id & 31) * 8;
        size_t ro = ((size_t)g.winoff + (size_t)(t >> 3) * g.W + (t & 7)) * 256 + c;
        u16x8 ov = *reinterpret_cast<const u16x8*>(&A[t * 264 + c]);
        u16x8 rv = *reinterpret_cast<const u16x8*>(Sy + ro);
        u16x8 o;
        #pragma unroll
        for (int j = 0; j < 8; ++j)
          o[j] = f2bf(fmaxf(bf2f(ov[j]) + bf2f(rv[j]), 0.f));
        *reinterpret_cast<u16x8*>(GoutB + ro) = o;
      }
    }
  }
}

// ======================= round-1 fused fallback ==============================
__global__ __launch_bounds__(256, 1) void swin_phase(
    const float* __restrict__ g0, const float* __restrict__ g1,
    const float* __restrict__ g2, const float* __restrict__ g3,
    const unsigned short* __restrict__ wball,
    float* __restrict__ outb, int phase)
{
  __shared__ alignas(16) unsigned short R0[64*264];
  __shared__ alignas(16) unsigned short R1[64*264];
  __shared__ alignas(16) unsigned short R2[256*72];
  __shared__ alignas(16) unsigned short R3[64*264];

  int bid = blockIdx.x;
  WinGeo g = decode_win(bid);
  const float* feat = (g.lvl == 0) ? g0 : (g.lvl == 1) ? g1 : (g.lvl == 2) ? g2 : g3;
  size_t CHW = g.HW * 256;

  const float* xsrc; const float* ysrc; float* outp;
  if (phase == 0){
    xsrc = feat + (size_t)g.b * CHW + g.winoff;
    ysrc = feat + (size_t)(g.b + 2) * CHW + g.winoff;
    outp = outb + g.ooff + (size_t)g.b * CHW + g.winoff;
  } else {
    xsrc = feat + (size_t)(g.b + 2) * CHW + g.winoff;
    ysrc = outb + g.ooff + (size_t)g.b * CHW + g.winoff;
    outp = outb + g.ooff + (size_t)(g.b + 2) * CHW + g.winoff;
  }
  const unsigned short* Wq = wball + ((size_t)(phase * 16 + g.lvl * 4) << 16);
  const unsigned short* Wk = Wq + 65536;
  const unsigned short* Wv = Wq + 2 * 65536;
  const unsigned short* Wo = Wq + 3 * 65536;

  int tid = threadIdx.x;
  int w = tid >> 6, l = tid & 63, l15 = l & 15, l4 = l >> 4, wd = w * 64;
  int hi0 = l >> 3, wi0 = l & 7;

  {
    const float* p0 = ysrc + (size_t)hi0 * g.W + wi0;
    #pragma unroll
    for (int oc = 0; oc < 8; ++oc){
      int c0 = (oc * 4 + w) * 8;
      const float* p = p0 + (size_t)c0 * g.HW;
      u16x8 uv;
      #pragma unroll
      for (int j = 0; j < 8; ++j) uv[j] = f2bf(p[(size_t)j * g.HW]);
      *reinterpret_cast<u16x8*>(&R0[l * 264 + c0]) = uv;
    }
  }
  __syncthreads();
  {
    f32x4 acc[4][4];
    #pragma unroll
    for (int i = 0; i < 4; ++i)
      #pragma unroll
      for (int j = 0; j < 4; ++j) acc[i][j] = f32x4{0.f,0.f,0.f,0.f};
    #pragma unroll
    for (int ks = 0; ks < 8; ++ks){
      int k0 = ks * 32 + l4 * 8;
      bf16x8 a[4], bb[4];
      #pragma unroll
      for (int mi = 0; mi < 4; ++mi)
        a[mi] = *reinterpret_cast<const bf16x8*>(Wk + (size_t)((wd + mi*16 + l15) * 256 + k0));
      #pragma unroll
      for (int ni = 0; ni < 4; ++ni)
        bb[ni] = *reinterpret_cast<const bf16x8*>(&R0[(ni*16 + l15) * 264 + k0]);
      #pragma unroll
      for (int mi = 0; mi < 4; ++mi)
        #pragma unroll
        for (int ni = 0; ni < 4; ++ni)
          acc[mi][ni] = MFMA16(a[mi], bb[ni], acc[mi][ni], 0, 0, 0);
    }
    #pragma unroll
    for (int mi = 0; mi < 4; ++mi){
      int d0 = wd + mi*16 + l4*4;
      #pragma unroll
      for (int ni = 0; ni < 4; ++ni)
        store_bf4(&R1[(ni*16 + l15) * 264 + d0], acc[mi][ni]);
    }
  }
  {
    f32x4 acc[4][4];
    #pragma unroll
    for (int i = 0; i < 4; ++i)
      #pragma unroll
      for (int j = 0; j < 4; ++j) acc[i][j] = f32x4{0.f,0.f,0.f,0.f};
    #pragma unroll
    for (int ks = 0; ks < 8; ++ks){
      int k0 = ks * 32 + l4 * 8;
      bf16x8 a[4], bb[4];
      #pragma unroll
      for (int mi = 0; mi < 4; ++mi)
        a[mi] = *reinterpret_cast<const bf16x8*>(&R0[(mi*16 + l15) * 264 + k0]);
      #pragma unroll
      for (int ni = 0; ni < 4; ++ni)
        bb[ni] = *reinterpret_cast<const bf16x8*>(Wv + (size_t)((wd + ni*16 + l15) * 256 + k0));
      #pragma unroll
      for (int mi = 0; mi < 4; ++mi)
        #pragma unroll
        for (int ni = 0; ni < 4; ++ni)
          acc[mi][ni] = MFMA16(a[mi], bb[ni], acc[mi][ni], 0, 0, 0);
    }
    #pragma unroll
    for (int mi = 0; mi < 4; ++mi){
      int u0 = mi*16 + l4*4;
      #pragma unroll
      for (int ni = 0; ni < 4; ++ni)
        store_bf4(&R2[(wd + ni*16 + l15) * 72 + u0], acc[mi][ni]);
    }
  }
  __syncthreads();
  {
    const float* p0 = xsrc + (size_t)hi0 * g.W + wi0;
    #pragma unroll
    for (int oc = 0; oc < 8; ++oc){
      int c0 = (oc * 4 + w) * 8;
      const float* p = p0 + (size_t)c0 * g.HW;
      u16x8 uv;
      #pragma unroll
      for (int j = 0; j < 8; ++j) uv[j] = f2bf(p[(size_t)j * g.HW]);
      *reinterpret_cast<u16x8*>(&R0[l * 264 + c0]) = uv;
    }
  }
  __syncthreads();
  {
    f32x4 acc[4][4];
    #pragma unroll
    for (int i = 0; i < 4; ++i)
      #pragma unroll
      for (int j = 0; j < 4; ++j) acc[i][j] = f32x4{0.f,0.f,0.f,0.f};
    #pragma unroll
    for (int ks = 0; ks < 8; ++ks){
      int k0 = ks * 32 + l4 * 8;
      bf16x8 a[4], bb[4];
      #pragma unroll
      for (int mi = 0; mi < 4; ++mi)
        a[mi] = *reinterpret_cast<const bf16x8*>(Wq + (size_t)((wd + mi*16 + l15) * 256 + k0));
      #pragma unroll
      for (int ni = 0; ni < 4; ++ni)
        bb[ni] = *reinterpret_cast<const bf16x8*>(&R0[(ni*16 + l15) * 264 + k0]);
      #pragma unroll
      for (int mi = 0; mi < 4; ++mi)
        #pragma unroll
        for (int ni = 0; ni < 4; ++ni)
          acc[mi][ni] = MFMA16(a[mi], bb[ni], acc[mi][ni], 0, 0, 0);
    }
    #pragma unroll
    for (int mi = 0; mi < 4; ++mi){
      int d0 = wd + mi*16 + l4*4;
      #pragma unroll
      for (int ni = 0; ni < 4; ++ni)
        store_bf4(&R3[(ni*16 + l15) * 264 + d0], acc[mi][ni]);
    }
  }
  __syncthreads();

  int h = w >> 1, tc = w & 1;
  {
    f32x4 s[4][2];
    #pragma unroll
    for (int i = 0; i < 4; ++i){ s[i][0] = f32x4{0.f,0.f,0.f,0.f}; s[i][1] = f32x4{0.f,0.f,0.f,0.f}; }
    #pragma unroll
    for (int ks = 0; ks < 4; ++ks){
      int k0 = h * 128 + ks * 32 + l4 * 8;
      bf16x8 a[4], bb[2];
      #pragma unroll
      for (int mi = 0; mi < 4; ++mi)
        a[mi] = *reinterpret_cast<const bf16x8*>(&R1[(mi*16 + l15) * 264 + k0]);
      #pragma unroll
      for (int ni = 0; ni < 2; ++ni)
        bb[ni] = *reinterpret_cast<const bf16x8*>(&R3[(tc*32 + ni*16 + l15) * 264 + k0]);
      #pragma unroll
      for (int mi = 0; mi < 4; ++mi)
        #pragma unroll
        for (int ni = 0; ni < 2; ++ni)
          s[mi][ni] = MFMA16(a[mi], bb[ni], s[mi][ni], 0, 0, 0);
    }
    __syncthreads();
    const float SCL = 0.08838834764831845f;
    unsigned short* P = R1;
    #pragma unroll
    for (int ni = 0; ni < 2; ++ni){
      float m = s[0][ni][0];
      #pragma unroll
      for (int mi = 0; mi < 4; ++mi)
        #pragma unroll
        for (int reg = 0; reg < 4; ++reg) m = fmaxf(m, s[mi][ni][reg]);
      m = fmaxf(m, __shfl_xor(m, 16));
      m = fmaxf(m, __shfl_xor(m, 32));
      float sum = 0.f;
      #pragma unroll
      for (int mi = 0; mi < 4; ++mi)
        #pragma unroll
        for (int reg = 0; reg < 4; ++reg){
          float e = __expf((s[mi][ni][reg] - m) * SCL);
          s[mi][ni][reg] = e; sum += e;
        }
      sum += __shfl_xor(sum, 16);
      sum += __shfl_xor(sum, 32);
      float rs = 1.0f / sum;
      int t = tc*32 + ni*16 + l15;
      #pragma unroll
      for (int mi = 0; mi < 4; ++mi){
        f32x4 pv;
        #pragma unroll
        for (int reg = 0; reg < 4; ++reg) pv[reg] = s[mi][ni][reg] * rs;
        store_bf4(&P[h * 4608 + t * 72 + mi*16 + l4*4], pv);
      }
    }
  }
  __syncthreads();
  {
    int wdh = h * 128 + tc * 64;
    f32x4 acc[4][4];
    #pragma unroll
    for (int i = 0; i < 4; ++i)
      #pragma unroll
      for (int j = 0; j < 4; ++j) acc[i][j] = f32x4{0.f,0.f,0.f,0.f};
    const unsigned short* P = R1;
    #pragma unroll
    for (int ks = 0; ks < 2; ++ks){
      int k0 = ks * 32 + l4 * 8;
      bf16x8 a[4], bb[4];
      #pragma unroll
      for (int mi = 0; mi < 4; ++mi)
        a[mi] = *reinterpret_cast<const bf16x8*>(&R2[(wdh + mi*16 + l15) * 72 + k0]);
      #pragma unroll
      for (int ni = 0; ni < 4; ++ni)
        bb[ni] = *reinterpret_cast<const bf16x8*>(&P[h * 4608 + (ni*16 + l15) * 72 + k0]);
      #pragma unroll
      for (int mi = 0; mi < 4; ++mi)
        #pragma unroll
        for (int ni = 0; ni < 4; ++ni)
          acc[mi][ni] = MFMA16(a[mi], bb[ni], acc[mi][ni], 0, 0, 0);
    }
    #pragma unroll
    for (int mi = 0; mi < 4; ++mi){
      int c0 = wdh + mi*16 + l4*4;
      #pragma unroll
      for (int ni = 0; ni < 4; ++ni)
        store_bf4(&R0[(ni*16 + l15) * 264 + c0], acc[mi][ni]);
    }
  }
  __syncthreads();
  {
    f32x4 acc[4][4];
    #pragma unroll
    for (int i = 0; i < 4; ++i)
      #pragma unroll
      for (int j = 0; j < 4; ++j) acc[i][j] = f32x4{0.f,0.f,0.f,0.f};
    #pragma unroll
    for (int ks = 0; ks < 8; ++ks){
      int k0 = ks * 32 + l4 * 8;
      bf16x8 a[4], bb[4];
      #pragma unroll
      for (int mi = 0; mi < 4; ++mi)
        a[mi] = *reinterpret_cast<const bf16x8*>(Wo + (size_t)((wd + mi*16 + l15) * 256 + k0));
      #pragma unroll
      for (int ni = 0; ni < 4; ++ni)
        bb[ni] = *reinterpret_cast<const bf16x8*>(&R0[(ni*16 + l15) * 264 + k0]);
      #pragma unroll
      for (int mi = 0; mi < 4; ++mi)
        #pragma unroll
        for (int ni = 0; ni < 4; ++ni)
          acc[mi][ni] = MFMA16(a[mi], bb[ni], acc[mi][ni], 0, 0, 0);
    }
    #pragma unroll
    for (int mi = 0; mi < 4; ++mi){
      #pragma unroll
      for (int ni = 0; ni < 4; ++ni){
        int t = ni*16 + l15, thi = t >> 3, twi = t & 7;
        size_t base = (size_t)(wd + mi*16 + l4*4) * g.HW + (size_t)thi * g.W + twi;
        #pragma unroll
        for (int reg = 0; reg < 4; ++reg){
          float res = xsrc[base + (size_t)reg * g.HW];
          float v = acc[mi][ni][reg] + res;
          outp[base + (size_t)reg * g.HW] = fmaxf(v, 0.f);
        }
      }
    }
  }
}

extern "C" void kernel_launch(void* const* d_in, const int* in_sizes, int n_in,
                              void* d_out, int out_size, void* d_ws, size_t ws_size,
                              hipStream_t stream) {
  (void)in_sizes; (void)n_in; (void)out_size;
  const float* f0 = (const float*)d_in[0];
  const float* f1 = (const float*)d_in[1];
  const float* f2 = (const float*)d_in[2];
  const float* f3 = (const float*)d_in[3];
  const float* w1 = (const float*)d_in[4];
  const float* w2 = (const float*)d_in[5];
  float* out = (float*)d_out;

  unsigned short* wbf = (unsigned short*)d_ws;
  const size_t WBF_B = 4194304;       // 2*16*65536 bf16
  const size_t FT_B  = 44564480;      // 87040 tokens * 256 * 2B
  const size_t need  = WBF_B + 2 * FT_B;   // 93,323,264

  wcvt_kernel<<<2048, 256, 0, stream>>>(w1, w2, wbf);

  if (ws_size >= need){
    char* base = (char*)d_ws + WBF_B;
    unsigned short* Ft = (unsigned short*)(base);
    unsigned short* Gt = (unsigned short*)(base + FT_B);

    xpose_kernel<<<5440, 256, 0, stream>>>(f0, f1, f2, f3, Ft);
    swin_fused<<<512, 256, 0, stream>>>(Ft, wbf, Gt);
    untrans_kernel<<<5440, 256, 0, stream>>>(Gt, out);
  } else {
    swin_phase<<<680, 256, 0, stream>>>(f0, f1, f2, f3, wbf, out, 0);
    swin_phase<<<680, 256, 0, stream>>>(f0, f1, f2, f3, wbf, out, 1);
  }
}

// Round 12
// 215.904 us; speedup vs baseline: 1.1341x; 1.0214x over previous
//
#include <hip/hip_runtime.h>

// Swin cross-attention pipeline v12 for MI355X.
// v12 = v8 exactly (best measured: 199us; 256thr/4 waves/70.6KB LDS/2 blk/CU)
// with two isolated changes:
//  (1) s_setprio removed from swin_win (null-to-negative for lockstep
//      barrier-synced blocks per m190).
//  (2) KV and Q GEMM loops explicitly 2-stage register-pipelined: operand
//      double-buffer (48 VGPR/stage) forces next-iter global loads to issue
//      before current-iter MFMAs, covering the ~250-375ns token-load latency
//      that v8 exposed (MfmaUtil 8.5% with HBM 6%, VALU 8.8% = pure stall).
// LDS aliasing unchanged: A = K -> P -> O -> out ; B = Q -> V^T.

using bf16x8 = __attribute__((ext_vector_type(8))) __bf16;
using f32x4  = __attribute__((ext_vector_type(4))) float;
using u16x4  = __attribute__((ext_vector_type(4))) unsigned short;
using u16x8  = __attribute__((ext_vector_type(8))) unsigned short;

__device__ __forceinline__ unsigned short f2bf(float f){
  unsigned int x = __float_as_uint(f);
  x += 0x7FFFu + ((x >> 16) & 1u);          // RNE
  return (unsigned short)(x >> 16);
}
__device__ __forceinline__ float bf2f(unsigned short u){
  return __uint_as_float((unsigned int)u << 16);
}
__device__ __forceinline__ void store_bf4(unsigned short* dst, f32x4 v){
  u16x4 o;
  o[0]=f2bf(v[0]); o[1]=f2bf(v[1]); o[2]=f2bf(v[2]); o[3]=f2bf(v[3]);
  *reinterpret_cast<u16x4*>(dst) = o;
}

#define MFMA16 __builtin_amdgcn_mfma_f32_16x16x32_bf16

__global__ void wcvt_kernel(const float* __restrict__ w1,
                            const float* __restrict__ w2,
                            unsigned short* __restrict__ dst){
  int i = blockIdx.x * 256 + threadIdx.x;
  const float4* src = (i < 262144) ? (reinterpret_cast<const float4*>(w1) + i)
                                   : (reinterpret_cast<const float4*>(w2) + (i - 262144));
  float4 v = *src;
  u16x4 o; o[0]=f2bf(v.x); o[1]=f2bf(v.y); o[2]=f2bf(v.z); o[3]=f2bf(v.w);
  reinterpret_cast<u16x4*>(dst)[i] = o;
}

// ---- transpose fp32 [C,HW] -> bf16 Ft[token][c] -----------------------------
__global__ __launch_bounds__(256, 2) void xpose_kernel(
    const float* __restrict__ g0, const float* __restrict__ g1,
    const float* __restrict__ g2, const float* __restrict__ g3,
    unsigned short* __restrict__ Ft)
{
  __shared__ float T[64][65];
  int bid = blockIdx.x;
  int r; const float* feat; int Hl; size_t tbase;
  if (bid < 4096){ r = bid;        feat = g0; Hl = 128; tbase = 0; }
  else if (bid < 5120){ r = bid - 4096; feat = g1; Hl = 64;  tbase = 65536; }
  else if (bid < 5376){ r = bid - 5120; feat = g2; Hl = 32;  tbase = 81920; }
  else { r = bid - 5376; feat = g3; Hl = 16;  tbase = 86016; }
  size_t HW = (size_t)Hl * Hl;
  int hw64 = (int)(HW >> 6);
  int bat = r / (4 * hw64);
  int r2 = r - bat * 4 * hw64;
  int ct = r2 / hw64, hwt = r2 - ct * hw64;

  const float* src = feat + (size_t)bat * HW * 256 + (size_t)(ct * 64) * HW + (size_t)hwt * 64;
  int tid = threadIdx.x;
  int cq = tid >> 4, hw0 = (tid & 15) * 4;
  #pragma unroll
  for (int p = 0; p < 4; ++p){
    int c = p * 16 + cq;
    const float* sp = src + (size_t)c * HW + hw0;
    float4 v = *reinterpret_cast<const float4*>(sp);
    T[c][hw0] = v.x; T[c][hw0+1] = v.y; T[c][hw0+2] = v.z; T[c][hw0+3] = v.w;
  }
  __syncthreads();
  unsigned short* dst = Ft + (tbase + (size_t)bat * HW + (size_t)hwt * 64) * 256 + ct * 64;
  #pragma unroll
  for (int p = 0; p < 2; ++p){
    int id = p * 256 + tid;
    int t = id >> 3, c0 = (id & 7) * 8;
    u16x8 o;
    #pragma unroll
    for (int j = 0; j < 8; ++j) o[j] = f2bf(T[c0 + j][t]);
    *reinterpret_cast<u16x8*>(dst + (size_t)t * 256 + c0) = o;
  }
}

// ---- transpose back: Gt[token][c] bf16 -> fp32 out [C,HW], ALL 4 batches ----
__global__ __launch_bounds__(256, 2) void untrans_kernel(
    const unsigned short* __restrict__ Gt, float* __restrict__ outb)
{
  __shared__ float T[64][65];
  int bid = blockIdx.x;
  int r; int Hl; size_t tbase, ooff;
  if (bid < 4096){ r = bid;        Hl = 128; tbase = 0;     ooff = 0; }
  else if (bid < 5120){ r = bid - 4096; Hl = 64; tbase = 65536; ooff = 16777216; }
  else if (bid < 5376){ r = bid - 5120; Hl = 32; tbase = 81920; ooff = 20971520; }
  else { r = bid - 5376; Hl = 16; tbase = 86016; ooff = 22020096; }
  size_t HW = (size_t)Hl * Hl;
  int hw64 = (int)(HW >> 6);
  int bat = r / (4 * hw64);
  int r2 = r - bat * 4 * hw64;
  int ct = r2 / hw64, hwt = r2 - ct * hw64;

  const unsigned short* src = Gt + (tbase + (size_t)bat * HW + (size_t)hwt * 64) * 256 + ct * 64;
  int tid = threadIdx.x;
  #pragma unroll
  for (int p = 0; p < 2; ++p){
    int id = p * 256 + tid;
    int t = id >> 3, c0 = (id & 7) * 8;
    u16x8 v = *reinterpret_cast<const u16x8*>(src + (size_t)t * 256 + c0);
    #pragma unroll
    for (int j = 0; j < 8; ++j) T[t][c0 + j] = bf2f(v[j]);
  }
  __syncthreads();
  float* dst = outb + ooff + (size_t)bat * HW * 256 + (size_t)(ct * 64) * HW + (size_t)hwt * 64;
  int cq = tid >> 4, hw0 = (tid & 15) * 4;
  #pragma unroll
  for (int p = 0; p < 4; ++p){
    int c = p * 16 + cq;
    float4 v;
    v.x = T[hw0][c]; v.y = T[hw0+1][c]; v.z = T[hw0+2][c]; v.w = T[hw0+3][c];
    *reinterpret_cast<float4*>(dst + (size_t)c * HW + hw0) = v;
  }
}

// ---- window geometry --------------------------------------------------------
struct WinGeo { int H, W, b, lvl; size_t HW, winoff, tbase, ooff; };

__device__ __forceinline__ WinGeo decode_win(int win){
  WinGeo g; int wloc;
  if (win < 512){ g.lvl = 0; wloc = win;      g.H = 128; g.tbase = 0;     g.ooff = 0; }
  else if (win < 640){ g.lvl = 1; wloc = win - 512; g.H = 64; g.tbase = 65536; g.ooff = 16777216; }
  else if (win < 672){ g.lvl = 2; wloc = win - 640; g.H = 32; g.tbase = 81920; g.ooff = 20971520; }
  else { g.lvl = 3; wloc = win - 672; g.H = 16; g.tbase = 86016; g.ooff = 22020096; }
  g.W = g.H; g.HW = (size_t)g.H * g.W;
  int nww = g.H >> 3, npb = nww * nww;
  g.b = wloc / npb;
  int r = wloc - g.b * npb;
  int wh = r / nww, ww = r - wh * nww;
  g.winoff = (size_t)(wh * 8) * g.W + (size_t)(ww * 8);
  return g;
}

// ---- v12: fully fused per-window kernel, pipelined loads, no setprio --------
__global__ __launch_bounds__(256, 2) void swin_win(
    const unsigned short* __restrict__ Ft, const unsigned short* __restrict__ Gtin,
    const unsigned short* __restrict__ wball,
    unsigned short* __restrict__ Gt, int phase)
{
  __shared__ alignas(16) unsigned short A[64*264];   // K -> P -> O -> out
  __shared__ alignas(16) unsigned short B[256*72];   // Q ([64][264] view) -> V^T
  int win = blockIdx.x;
  WinGeo g = decode_win(win);
  int tid = threadIdx.x;
  int w = tid >> 6, l = tid & 63, l15 = l & 15, l4 = l >> 4, wd = w * 64;
  int h = w >> 1, tc = w & 1;

  int batx = (phase == 0) ? g.b : g.b + 2;
  const unsigned short* Sx = Ft + (g.tbase + (size_t)batx * g.HW) * 256;
  const unsigned short* Sy = (phase == 0)
      ? Ft + (g.tbase + (size_t)(g.b + 2) * g.HW) * 256
      : Gtin + (g.tbase + (size_t)g.b * g.HW) * 256;
  unsigned short* Gout = Gt + (g.tbase + (size_t)batx * g.HW) * 256;

  size_t rowo[4];
  #pragma unroll
  for (int ni = 0; ni < 4; ++ni){
    int t = ni * 16 + l15;
    rowo[ni] = ((size_t)g.winoff + (size_t)(t >> 3) * g.W + (t & 7)) * 256;
  }
  const unsigned short* Wbase = wball + ((size_t)(phase * 16 + g.lvl * 4) << 16);
  const unsigned short* Wq = Wbase;
  const unsigned short* Wk = Wbase + 65536;
  const unsigned short* Wv = Wbase + 131072;
  const unsigned short* Wo = Wbase + 196608;

  // ---- K & V GEMMs interleaved, shared Sy fragments, 2-stage pipelined ----
  f32x4 av[4][4];
  {
    f32x4 ak[4][4];
    #pragma unroll
    for (int i = 0; i < 4; ++i)
      #pragma unroll
      for (int j = 0; j < 4; ++j){ ak[i][j] = f32x4{0.f,0.f,0.f,0.f}; av[i][j] = f32x4{0.f,0.f,0.f,0.f}; }
    bf16x8 tf[2][4], kf[2][4], vf[2][4];
    {
      int k0 = l4 * 8;
      #pragma unroll
      for (int i = 0; i < 4; ++i){
        tf[0][i] = *reinterpret_cast<const bf16x8*>(Sy + rowo[i] + k0);
        kf[0][i] = *reinterpret_cast<const bf16x8*>(Wk + (size_t)((wd + i*16 + l15) * 256 + k0));
        vf[0][i] = *reinterpret_cast<const bf16x8*>(Wv + (size_t)((wd + i*16 + l15) * 256 + k0));
      }
    }
    #pragma unroll
    for (int ks = 0; ks < 8; ++ks){
      const int cur = ks & 1, nxt = cur ^ 1;
      if (ks < 7){
        int k1 = (ks + 1) * 32 + l4 * 8;
        #pragma unroll
        for (int i = 0; i < 4; ++i){
          tf[nxt][i] = *reinterpret_cast<const bf16x8*>(Sy + rowo[i] + k1);
          kf[nxt][i] = *reinterpret_cast<const bf16x8*>(Wk + (size_t)((wd + i*16 + l15) * 256 + k1));
          vf[nxt][i] = *reinterpret_cast<const bf16x8*>(Wv + (size_t)((wd + i*16 + l15) * 256 + k1));
        }
      }
      #pragma unroll
      for (int mi = 0; mi < 4; ++mi)
        #pragma unroll
        for (int ni = 0; ni < 4; ++ni){
          ak[mi][ni] = MFMA16(kf[cur][mi], tf[cur][ni], ak[mi][ni], 0, 0, 0);
          av[mi][ni] = MFMA16(tf[cur][mi], vf[cur][ni], av[mi][ni], 0, 0, 0);
        }
    }
    // K[u][d] -> A
    #pragma unroll
    for (int mi = 0; mi < 4; ++mi){
      int d0 = wd + mi*16 + l4*4;
      #pragma unroll
      for (int ni = 0; ni < 4; ++ni)
        store_bf4(&A[(ni*16 + l15) * 264 + d0], ak[mi][ni]);
    }
  }
  // av stays live in registers until after S.

  // ---- Q GEMM -> B ([64][264] view), 2-stage pipelined ----
  {
    f32x4 aq[4][4];
    #pragma unroll
    for (int i = 0; i < 4; ++i)
      #pragma unroll
      for (int j = 0; j < 4; ++j) aq[i][j] = f32x4{0.f,0.f,0.f,0.f};
    bf16x8 tf[2][4], wf[2][4];
    {
      int k0 = l4 * 8;
      #pragma unroll
      for (int i = 0; i < 4; ++i){
        tf[0][i] = *reinterpret_cast<const bf16x8*>(Sx + rowo[i] + k0);
        wf[0][i] = *reinterpret_cast<const bf16x8*>(Wq + (size_t)((wd + i*16 + l15) * 256 + k0));
      }
    }
    #pragma unroll
    for (int ks = 0; ks < 8; ++ks){
      const int cur = ks & 1, nxt = cur ^ 1;
      if (ks < 7){
        int k1 = (ks + 1) * 32 + l4 * 8;
        #pragma unroll
        for (int i = 0; i < 4; ++i){
          tf[nxt][i] = *reinterpret_cast<const bf16x8*>(Sx + rowo[i] + k1);
          wf[nxt][i] = *reinterpret_cast<const bf16x8*>(Wq + (size_t)((wd + i*16 + l15) * 256 + k1));
        }
      }
      #pragma unroll
      for (int mi = 0; mi < 4; ++mi)
        #pragma unroll
        for (int ni = 0; ni < 4; ++ni)
          aq[mi][ni] = MFMA16(wf[cur][mi], tf[cur][ni], aq[mi][ni], 0, 0, 0);
    }
    #pragma unroll
    for (int mi = 0; mi < 4; ++mi){
      int d0 = wd + mi*16 + l4*4;
      #pragma unroll
      for (int ni = 0; ni < 4; ++ni)
        store_bf4(&B[(ni*16 + l15) * 264 + d0], aq[mi][ni]);
    }
  }
  __syncthreads();   // sync0: K(A), Q(B) visible

  // ---- S^T[u][t] per head from LDS K,Q ----
  f32x4 s[4][2];
  #pragma unroll
  for (int i = 0; i < 4; ++i){ s[i][0] = f32x4{0.f,0.f,0.f,0.f}; s[i][1] = f32x4{0.f,0.f,0.f,0.f}; }
  #pragma unroll
  for (int ks = 0; ks < 4; ++ks){
    int k0 = h * 128 + ks * 32 + l4 * 8;
    bf16x8 a[4], bb[2];
    #pragma unroll
    for (int mi = 0; mi < 4; ++mi)
      a[mi] = *reinterpret_cast<const bf16x8*>(&A[(mi*16 + l15) * 264 + k0]);
    #pragma unroll
    for (int ni = 0; ni < 2; ++ni)
      bb[ni] = *reinterpret_cast<const bf16x8*>(&B[(tc*32 + ni*16 + l15) * 264 + k0]);
    #pragma unroll
    for (int mi = 0; mi < 4; ++mi)
      #pragma unroll
      for (int ni = 0; ni < 2; ++ni)
        s[mi][ni] = MFMA16(a[mi], bb[ni], s[mi][ni], 0, 0, 0);
  }
  __syncthreads();   // sync1: K,Q reads done; A free for P, B free for V^T

  // ---- V^T (from registers) -> B ----
  #pragma unroll
  for (int mi = 0; mi < 4; ++mi){
    int u0 = mi*16 + l4*4;
    #pragma unroll
    for (int ni = 0; ni < 4; ++ni)
      store_bf4(&B[(wd + ni*16 + l15) * 72 + u0], av[mi][ni]);
  }

  // ---- softmax over u (per column t), P -> A ----
  const float SCL = 0.08838834764831845f;   // 1/sqrt(128)
  #pragma unroll
  for (int ni = 0; ni < 2; ++ni){
    float m = s[0][ni][0];
    #pragma unroll
    for (int mi = 0; mi < 4; ++mi)
      #pragma unroll
      for (int reg = 0; reg < 4; ++reg) m = fmaxf(m, s[mi][ni][reg]);
    m = fmaxf(m, __shfl_xor(m, 16));
    m = fmaxf(m, __shfl_xor(m, 32));
    float sum = 0.f;
    #pragma unroll
    for (int mi = 0; mi < 4; ++mi)
      #pragma unroll
      for (int reg = 0; reg < 4; ++reg){
        float e = __expf((s[mi][ni][reg] - m) * SCL);
        s[mi][ni][reg] = e; sum += e;
      }
    sum += __shfl_xor(sum, 16);
    sum += __shfl_xor(sum, 32);
    float rs = 1.0f / sum;
    int t = tc*32 + ni*16 + l15;
    #pragma unroll
    for (int mi = 0; mi < 4; ++mi){
      f32x4 pv;
      #pragma unroll
      for (int reg = 0; reg < 4; ++reg) pv[reg] = s[mi][ni][reg] * rs;
      store_bf4(&A[h * 4608 + t * 72 + mi*16 + l4*4], pv);
    }
  }
  __syncthreads();   // sync2: P(A), V^T(B) visible

  // ---- O^T[c][t] = V^T * P^T (both from LDS) ----
  f32x4 acc[4][4];
  #pragma unroll
  for (int i = 0; i < 4; ++i)
    #pragma unroll
    for (int j = 0; j < 4; ++j) acc[i][j] = f32x4{0.f,0.f,0.f,0.f};
  #pragma unroll
  for (int ks = 0; ks < 2; ++ks){
    int k0 = ks * 32 + l4 * 8;
    bf16x8 a[4], bb[4];
    #pragma unroll
    for (int mi = 0; mi < 4; ++mi)
      a[mi] = *reinterpret_cast<const bf16x8*>(&B[(wd + mi*16 + l15) * 72 + k0]);
    #pragma unroll
    for (int ni = 0; ni < 4; ++ni)
      bb[ni] = *reinterpret_cast<const bf16x8*>(&A[h * 4608 + (ni*16 + l15) * 72 + k0]);
    #pragma unroll
    for (int mi = 0; mi < 4; ++mi)
      #pragma unroll
      for (int ni = 0; ni < 4; ++ni)
        acc[mi][ni] = MFMA16(a[mi], bb[ni], acc[mi][ni], 0, 0, 0);
  }
  __syncthreads();   // sync3: P reads done; A free for O
  #pragma unroll
  for (int mi = 0; mi < 4; ++mi){
    int c0 = wd + mi*16 + l4*4;
    #pragma unroll
    for (int ni = 0; ni < 4; ++ni)
      store_bf4(&A[(ni*16 + l15) * 264 + c0], acc[mi][ni]);
  }
  __syncthreads();   // sync4: O(A) visible

  // ---- out^T = Wo * o^T (Wo loads 2-stage pipelined) ----
  #pragma unroll
  for (int i = 0; i < 4; ++i)
    #pragma unroll
    for (int j = 0; j < 4; ++j) acc[i][j] = f32x4{0.f,0.f,0.f,0.f};
  {
    bf16x8 a2[2][4];
    {
      int k0 = l4 * 8;
      #pragma unroll
      for (int mi = 0; mi < 4; ++mi)
        a2[0][mi] = *reinterpret_cast<const bf16x8*>(Wo + (size_t)((wd + mi*16 + l15) * 256 + k0));
    }
    #pragma unroll
    for (int ks = 0; ks < 8; ++ks){
      const int cur = ks & 1, nxt = cur ^ 1;
      if (ks < 7){
        int k1 = (ks + 1) * 32 + l4 * 8;
        #pragma unroll
        for (int mi = 0; mi < 4; ++mi)
          a2[nxt][mi] = *reinterpret_cast<const bf16x8*>(Wo + (size_t)((wd + mi*16 + l15) * 256 + k1));
      }
      int k0 = ks * 32 + l4 * 8;
      bf16x8 bb[4];
      #pragma unroll
      for (int ni = 0; ni < 4; ++ni)
        bb[ni] = *reinterpret_cast<const bf16x8*>(&A[(ni*16 + l15) * 264 + k0]);
      #pragma unroll
      for (int mi = 0; mi < 4; ++mi)
        #pragma unroll
        for (int ni = 0; ni < 4; ++ni)
          acc[mi][ni] = MFMA16(a2[cur][mi], bb[ni], acc[mi][ni], 0, 0, 0);
    }
  }
  __syncthreads();   // sync5: O reads done; A free for out tile
  #pragma unroll
  for (int mi = 0; mi < 4; ++mi){
    int c0 = wd + mi*16 + l4*4;
    #pragma unroll
    for (int ni = 0; ni < 4; ++ni)
      store_bf4(&A[(ni*16 + l15) * 264 + c0], acc[mi][ni]);
  }
  __syncthreads();   // sync6: out(A) visible

  // ---- fused flush: out + residual, relu, 16B coalesced -> Gt ----
  #pragma unroll
  for (int p = 0; p < 8; ++p){
    int id = p * 256 + tid;
    int t = id >> 5, c = (id & 31) * 8;
    size_t ro = ((size_t)g.winoff + (size_t)(t >> 3) * g.W + (t & 7)) * 256 + c;
    u16x8 ov = *reinterpret_cast<const u16x8*>(&A[t * 264 + c]);
    u16x8 rv = *reinterpret_cast<const u16x8*>(Sx + ro);
    u16x8 o;
    #pragma unroll
    for (int j = 0; j < 8; ++j)
      o[j] = f2bf(fmaxf(bf2f(ov[j]) + bf2f(rv[j]), 0.f));
    *reinterpret_cast<u16x8*>(Gout + ro) = o;
  }
}

// ======================= round-1 fused fallback ==============================
__global__ __launch_bounds__(256, 1) void swin_phase(
    const float* __restrict__ g0, const float* __restrict__ g1,
    const float* __restrict__ g2, const float* __restrict__ g3,
    const unsigned short* __restrict__ wball,
    float* __restrict__ outb, int phase)
{
  __shared__ alignas(16) unsigned short R0[64*264];
  __shared__ alignas(16) unsigned short R1[64*264];
  __shared__ alignas(16) unsigned short R2[256*72];
  __shared__ alignas(16) unsigned short R3[64*264];

  int bid = blockIdx.x;
  WinGeo g = decode_win(bid);
  const float* feat = (g.lvl == 0) ? g0 : (g.lvl == 1) ? g1 : (g.lvl == 2) ? g2 : g3;
  size_t CHW = g.HW * 256;

  const float* xsrc; const float* ysrc; float* outp;
  if (phase == 0){
    xsrc = feat + (size_t)g.b * CHW + g.winoff;
    ysrc = feat + (size_t)(g.b + 2) * CHW + g.winoff;
    outp = outb + g.ooff + (size_t)g.b * CHW + g.winoff;
  } else {
    xsrc = feat + (size_t)(g.b + 2) * CHW + g.winoff;
    ysrc = outb + g.ooff + (size_t)g.b * CHW + g.winoff;
    outp = outb + g.ooff + (size_t)(g.b + 2) * CHW + g.winoff;
  }
  const unsigned short* Wq = wball + ((size_t)(phase * 16 + g.lvl * 4) << 16);
  const unsigned short* Wk = Wq + 65536;
  const unsigned short* Wv = Wq + 2 * 65536;
  const unsigned short* Wo = Wq + 3 * 65536;

  int tid = threadIdx.x;
  int w = tid >> 6, l = tid & 63, l15 = l & 15, l4 = l >> 4, wd = w * 64;
  int hi0 = l >> 3, wi0 = l & 7;

  {
    const float* p0 = ysrc + (size_t)hi0 * g.W + wi0;
    #pragma unroll
    for (int oc = 0; oc < 8; ++oc){
      int c0 = (oc * 4 + w) * 8;
      const float* p = p0 + (size_t)c0 * g.HW;
      u16x8 uv;
      #pragma unroll
      for (int j = 0; j < 8; ++j) uv[j] = f2bf(p[(size_t)j * g.HW]);
      *reinterpret_cast<u16x8*>(&R0[l * 264 + c0]) = uv;
    }
  }
  __syncthreads();
  {
    f32x4 acc[4][4];
    #pragma unroll
    for (int i = 0; i < 4; ++i)
      #pragma unroll
      for (int j = 0; j < 4; ++j) acc[i][j] = f32x4{0.f,0.f,0.f,0.f};
    #pragma unroll
    for (int ks = 0; ks < 8; ++ks){
      int k0 = ks * 32 + l4 * 8;
      bf16x8 a[4], bb[4];
      #pragma unroll
      for (int mi = 0; mi < 4; ++mi)
        a[mi] = *reinterpret_cast<const bf16x8*>(Wk + (size_t)((wd + mi*16 + l15) * 256 + k0));
      #pragma unroll
      for (int ni = 0; ni < 4; ++ni)
        bb[ni] = *reinterpret_cast<const bf16x8*>(&R0[(ni*16 + l15) * 264 + k0]);
      #pragma unroll
      for (int mi = 0; mi < 4; ++mi)
        #pragma unroll
        for (int ni = 0; ni < 4; ++ni)
          acc[mi][ni] = MFMA16(a[mi], bb[ni], acc[mi][ni], 0, 0, 0);
    }
    #pragma unroll
    for (int mi = 0; mi < 4; ++mi){
      int d0 = wd + mi*16 + l4*4;
      #pragma unroll
      for (int ni = 0; ni < 4; ++ni)
        store_bf4(&R1[(ni*16 + l15) * 264 + d0], acc[mi][ni]);
    }
  }
  {
    f32x4 acc[4][4];
    #pragma unroll
    for (int i = 0; i < 4; ++i)
      #pragma unroll
      for (int j = 0; j < 4; ++j) acc[i][j] = f32x4{0.f,0.f,0.f,0.f};
    #pragma unroll
    for (int ks = 0; ks < 8; ++ks){
      int k0 = ks * 32 + l4 * 8;
      bf16x8 a[4], bb[4];
      #pragma unroll
      for (int mi = 0; mi < 4; ++mi)
        a[mi] = *reinterpret_cast<const bf16x8*>(&R0[(mi*16 + l15) * 264 + k0]);
      #pragma unroll
      for (int ni = 0; ni < 4; ++ni)
        bb[ni] = *reinterpret_cast<const bf16x8*>(Wv + (size_t)((wd + ni*16 + l15) * 256 + k0));
      #pragma unroll
      for (int mi = 0; mi < 4; ++mi)
        #pragma unroll
        for (int ni = 0; ni < 4; ++ni)
          acc[mi][ni] = MFMA16(a[mi], bb[ni], acc[mi][ni], 0, 0, 0);
    }
    #pragma unroll
    for (int mi = 0; mi < 4; ++mi){
      int u0 = mi*16 + l4*4;
      #pragma unroll
      for (int ni = 0; ni < 4; ++ni)
        store_bf4(&R2[(wd + ni*16 + l15) * 72 + u0], acc[mi][ni]);
    }
  }
  __syncthreads();
  {
    const float* p0 = xsrc + (size_t)hi0 * g.W + wi0;
    #pragma unroll
    for (int oc = 0; oc < 8; ++oc){
      int c0 = (oc * 4 + w) * 8;
      const float* p = p0 + (size_t)c0 * g.HW;
      u16x8 uv;
      #pragma unroll
      for (int j = 0; j < 8; ++j) uv[j] = f2bf(p[(size_t)j * g.HW]);
      *reinterpret_cast<u16x8*>(&R0[l * 264 + c0]) = uv;
    }
  }
  __syncthreads();
  {
    f32x4 acc[4][4];
    #pragma unroll
    for (int i = 0; i < 4; ++i)
      #pragma unroll
      for (int j = 0; j < 4; ++j) acc[i][j] = f32x4{0.f,0.f,0.f,0.f};
    #pragma unroll
    for (int ks = 0; ks < 8; ++ks){
      int k0 = ks * 32 + l4 * 8;
      bf16x8 a[4], bb[4];
      #pragma unroll
      for (int mi = 0; mi < 4; ++mi)
        a[mi] = *reinterpret_cast<const bf16x8*>(Wq + (size_t)((wd + mi*16 + l15) * 256 + k0));
      #pragma unroll
      for (int ni = 0; ni < 4; ++ni)
        bb[ni] = *reinterpret_cast<const bf16x8*>(&R0[(ni*16 + l15) * 264 + k0]);
      #pragma unroll
      for (int mi = 0; mi < 4; ++mi)
        #pragma unroll
        for (int ni = 0; ni < 4; ++ni)
          acc[mi][ni] = MFMA16(a[mi], bb[ni], acc[mi][ni], 0, 0, 0);
    }
    #pragma unroll
    for (int mi = 0; mi < 4; ++mi){
      int d0 = wd + mi*16 + l4*4;
      #pragma unroll
      for (int ni = 0; ni < 4; ++ni)
        store_bf4(&R3[(ni*16 + l15) * 264 + d0], acc[mi][ni]);
    }
  }
  __syncthreads();

  int h = w >> 1, tc = w & 1;
  {
    f32x4 s[4][2];
    #pragma unroll
    for (int i = 0; i < 4; ++i){ s[i][0] = f32x4{0.f,0.f,0.f,0.f}; s[i][1] = f32x4{0.f,0.f,0.f,0.f}; }
    #pragma unroll
    for (int ks = 0; ks < 4; ++ks){
      int k0 = h * 128 + ks * 32 + l4 * 8;
      bf16x8 a[4], bb[2];
      #pragma unroll
      for (int mi = 0; mi < 4; ++mi)
        a[mi] = *reinterpret_cast<const bf16x8*>(&R1[(mi*16 + l15) * 264 + k0]);
      #pragma unroll
      for (int ni = 0; ni < 2; ++ni)
        bb[ni] = *reinterpret_cast<const bf16x8*>(&R3[(tc*32 + ni*16 + l15) * 264 + k0]);
      #pragma unroll
      for (int mi = 0; mi < 4; ++mi)
        #pragma unroll
        for (int ni = 0; ni < 2; ++ni)
          s[mi][ni] = MFMA16(a[mi], bb[ni], s[mi][ni], 0, 0, 0);
    }
    __syncthreads();
    const float SCL = 0.08838834764831845f;
    unsigned short* P = R1;
    #pragma unroll
    for (int ni = 0; ni < 2; ++ni){
      float m = s[0][ni][0];
      #pragma unroll
      for (int mi = 0; mi < 4; ++mi)
        #pragma unroll
        for (int reg = 0; reg < 4; ++reg) m = fmaxf(m, s[mi][ni][reg]);
      m = fmaxf(m, __shfl_xor(m, 16));
      m = fmaxf(m, __shfl_xor(m, 32));
      float sum = 0.f;
      #pragma unroll
      for (int mi = 0; mi < 4; ++mi)
        #pragma unroll
        for (int reg = 0; reg < 4; ++reg){
          float e = __expf((s[mi][ni][reg] - m) * SCL);
          s[mi][ni][reg] = e; sum += e;
        }
      sum += __shfl_xor(sum, 16);
      sum += __shfl_xor(sum, 32);
      float rs = 1.0f / sum;
      int t = tc*32 + ni*16 + l15;
      #pragma unroll
      for (int mi = 0; mi < 4; ++mi){
        f32x4 pv;
        #pragma unroll
        for (int reg = 0; reg < 4; ++reg) pv[reg] = s[mi][ni][reg] * rs;
        store_bf4(&P[h * 4608 + t * 72 + mi*16 + l4*4], pv);
      }
    }
  }
  __syncthreads();
  {
    int wdh = h * 128 + tc * 64;
    f32x4 acc[4][4];
    #pragma unroll
    for (int i = 0; i < 4; ++i)
      #pragma unroll
      for (int j = 0; j < 4; ++j) acc[i][j] = f32x4{0.f,0.f,0.f,0.f};
    const unsigned short* P = R1;
    #pragma unroll
    for (int ks = 0; ks < 2; ++ks){
      int k0 = ks * 32 + l4 * 8;
      bf16x8 a[4], bb[4];
      #pragma unroll
      for (int mi = 0; mi < 4; ++mi)
        a[mi] = *reinterpret_cast<const bf16x8*>(&R2[(wdh + mi*16 + l15) * 72 + k0]);
      #pragma unroll
      for (int ni = 0; ni < 4; ++ni)
        bb[ni] = *reinterpret_cast<const bf16x8*>(&P[h * 4608 + (ni*16 + l15) * 72 + k0]);
      #pragma unroll
      for (int mi = 0; mi < 4; ++mi)
        #pragma unroll
        for (int ni = 0; ni < 4; ++ni)
          acc[mi][ni] = MFMA16(a[mi], bb[ni], acc[mi][ni], 0, 0, 0);
    }
    #pragma unroll
    for (int mi = 0; mi < 4; ++mi){
      int c0 = wdh + mi*16 + l4*4;
      #pragma unroll
      for (int ni = 0; ni < 4; ++ni)
        store_bf4(&R0[(ni*16 + l15) * 264 + c0], acc[mi][ni]);
    }
  }
  __syncthreads();
  {
    f32x4 acc[4][4];
    #pragma unroll
    for (int i = 0; i < 4; ++i)
      #pragma unroll
      for (int j = 0; j < 4; ++j) acc[i][j] = f32x4{0.f,0.f,0.f,0.f};
    #pragma unroll
    for (int ks = 0; ks < 8; ++ks){
      int k0 = ks * 32 + l4 * 8;
      bf16x8 a[4], bb[4];
      #pragma unroll
      for (int mi = 0; mi < 4; ++mi)
        a[mi] = *reinterpret_cast<const bf16x8*>(Wo + (size_t)((wd + mi*16 + l15) * 256 + k0));
      #pragma unroll
      for (int ni = 0; ni < 4; ++ni)
        bb[ni] = *reinterpret_cast<const bf16x8*>(&R0[(ni*16 + l15) * 264 + k0]);
      #pragma unroll
      for (int mi = 0; mi < 4; ++mi)
        #pragma unroll
        for (int ni = 0; ni < 4; ++ni)
          acc[mi][ni] = MFMA16(a[mi], bb[ni], acc[mi][ni], 0, 0, 0);
    }
    #pragma unroll
    for (int mi = 0; mi < 4; ++mi){
      #pragma unroll
      for (int ni = 0; ni < 4; ++ni){
        int t = ni*16 + l15, thi = t >> 3, twi = t & 7;
        size_t base = (size_t)(wd + mi*16 + l4*4) * g.HW + (size_t)thi * g.W + twi;
        #pragma unroll
        for (int reg = 0; reg < 4; ++reg){
          float res = xsrc[base + (size_t)reg * g.HW];
          float v = acc[mi][ni][reg] + res;
          outp[base + (size_t)reg * g.HW] = fmaxf(v, 0.f);
        }
      }
    }
  }
}

extern "C" void kernel_launch(void* const* d_in, const int* in_sizes, int n_in,
                              void* d_out, int out_size, void* d_ws, size_t ws_size,
                              hipStream_t stream) {
  (void)in_sizes; (void)n_in; (void)out_size;
  const float* f0 = (const float*)d_in[0];
  const float* f1 = (const float*)d_in[1];
  const float* f2 = (const float*)d_in[2];
  const float* f3 = (const float*)d_in[3];
  const float* w1 = (const float*)d_in[4];
  const float* w2 = (const float*)d_in[5];
  float* out = (float*)d_out;

  unsigned short* wbf = (unsigned short*)d_ws;
  const size_t WBF_B = 4194304;       // 2*16*65536 bf16
  const size_t FT_B  = 44564480;      // 87040 tokens * 256 * 2B
  const size_t need  = WBF_B + 2 * FT_B;   // 93,323,264

  wcvt_kernel<<<2048, 256, 0, stream>>>(w1, w2, wbf);

  if (ws_size >= need){
    char* base = (char*)d_ws + WBF_B;
    unsigned short* Ft = (unsigned short*)(base);
    unsigned short* Gt = (unsigned short*)(base + FT_B);

    xpose_kernel<<<5440, 256, 0, stream>>>(f0, f1, f2, f3, Ft);
    for (int phase = 0; phase < 2; ++phase)
      swin_win<<<680, 256, 0, stream>>>(Ft, Gt, wbf, Gt, phase);
    untrans_kernel<<<5440, 256, 0, stream>>>(Gt, out);
  } else {
    swin_phase<<<680, 256, 0, stream>>>(f0, f1, f2, f3, wbf, out, 0);
    swin_phase<<<680, 256, 0, stream>>>(f0, f1, f2, f3, wbf, out, 1);
  }
}

// Round 13
// 206.762 us; speedup vs baseline: 1.1842x; 1.0442x over previous
//
#include <hip/hip_runtime.h>

// Swin cross-attention pipeline v13 for MI355X.
// v13 = v8 (best measured: 199us) with exactly two low-risk deltas:
//  (1) s_setprio removed from swin_win (lockstep barrier-synced waves; m190
//      shows setprio is null-to-negative in this regime). Isolated this time.
//  (2) Q GEMM moved BEFORE the K/V-interleaved GEMM: shrinks the av
//      accumulator live range (KV->S instead of KV->Q->S), freeing ~64 VGPRs
//      during the Q loop so the compiler can pipeline its loads naturally
//      (v12's manual double-buffer spilled: WRITE 22->41MB; this can't).
// Everything else byte-identical to v8. LDS: A = K -> P -> O -> out (33.8KB),
// B = Q([64][264] view) -> V^T (36.9KB), 70.6KB total, 2 blocks/CU.

using bf16x8 = __attribute__((ext_vector_type(8))) __bf16;
using f32x4  = __attribute__((ext_vector_type(4))) float;
using u16x4  = __attribute__((ext_vector_type(4))) unsigned short;
using u16x8  = __attribute__((ext_vector_type(8))) unsigned short;

__device__ __forceinline__ unsigned short f2bf(float f){
  unsigned int x = __float_as_uint(f);
  x += 0x7FFFu + ((x >> 16) & 1u);          // RNE
  return (unsigned short)(x >> 16);
}
__device__ __forceinline__ float bf2f(unsigned short u){
  return __uint_as_float((unsigned int)u << 16);
}
__device__ __forceinline__ void store_bf4(unsigned short* dst, f32x4 v){
  u16x4 o;
  o[0]=f2bf(v[0]); o[1]=f2bf(v[1]); o[2]=f2bf(v[2]); o[3]=f2bf(v[3]);
  *reinterpret_cast<u16x4*>(dst) = o;
}

#define MFMA16 __builtin_amdgcn_mfma_f32_16x16x32_bf16

__global__ void wcvt_kernel(const float* __restrict__ w1,
                            const float* __restrict__ w2,
                            unsigned short* __restrict__ dst){
  int i = blockIdx.x * 256 + threadIdx.x;
  const float4* src = (i < 262144) ? (reinterpret_cast<const float4*>(w1) + i)
                                   : (reinterpret_cast<const float4*>(w2) + (i - 262144));
  float4 v = *src;
  u16x4 o; o[0]=f2bf(v.x); o[1]=f2bf(v.y); o[2]=f2bf(v.z); o[3]=f2bf(v.w);
  reinterpret_cast<u16x4*>(dst)[i] = o;
}

// ---- transpose fp32 [C,HW] -> bf16 Ft[token][c] -----------------------------
__global__ __launch_bounds__(256, 2) void xpose_kernel(
    const float* __restrict__ g0, const float* __restrict__ g1,
    const float* __restrict__ g2, const float* __restrict__ g3,
    unsigned short* __restrict__ Ft)
{
  __shared__ float T[64][65];
  int bid = blockIdx.x;
  int r; const float* feat; int Hl; size_t tbase;
  if (bid < 4096){ r = bid;        feat = g0; Hl = 128; tbase = 0; }
  else if (bid < 5120){ r = bid - 4096; feat = g1; Hl = 64;  tbase = 65536; }
  else if (bid < 5376){ r = bid - 5120; feat = g2; Hl = 32;  tbase = 81920; }
  else { r = bid - 5376; feat = g3; Hl = 16;  tbase = 86016; }
  size_t HW = (size_t)Hl * Hl;
  int hw64 = (int)(HW >> 6);
  int bat = r / (4 * hw64);
  int r2 = r - bat * 4 * hw64;
  int ct = r2 / hw64, hwt = r2 - ct * hw64;

  const float* src = feat + (size_t)bat * HW * 256 + (size_t)(ct * 64) * HW + (size_t)hwt * 64;
  int tid = threadIdx.x;
  int cq = tid >> 4, hw0 = (tid & 15) * 4;
  #pragma unroll
  for (int p = 0; p < 4; ++p){
    int c = p * 16 + cq;
    const float* sp = src + (size_t)c * HW + hw0;
    float4 v = *reinterpret_cast<const float4*>(sp);
    T[c][hw0] = v.x; T[c][hw0+1] = v.y; T[c][hw0+2] = v.z; T[c][hw0+3] = v.w;
  }
  __syncthreads();
  unsigned short* dst = Ft + (tbase + (size_t)bat * HW + (size_t)hwt * 64) * 256 + ct * 64;
  #pragma unroll
  for (int p = 0; p < 2; ++p){
    int id = p * 256 + tid;
    int t = id >> 3, c0 = (id & 7) * 8;
    u16x8 o;
    #pragma unroll
    for (int j = 0; j < 8; ++j) o[j] = f2bf(T[c0 + j][t]);
    *reinterpret_cast<u16x8*>(dst + (size_t)t * 256 + c0) = o;
  }
}

// ---- transpose back: Gt[token][c] bf16 -> fp32 out [C,HW], ALL 4 batches ----
__global__ __launch_bounds__(256, 2) void untrans_kernel(
    const unsigned short* __restrict__ Gt, float* __restrict__ outb)
{
  __shared__ float T[64][65];
  int bid = blockIdx.x;
  int r; int Hl; size_t tbase, ooff;
  if (bid < 4096){ r = bid;        Hl = 128; tbase = 0;     ooff = 0; }
  else if (bid < 5120){ r = bid - 4096; Hl = 64; tbase = 65536; ooff = 16777216; }
  else if (bid < 5376){ r = bid - 5120; Hl = 32; tbase = 81920; ooff = 20971520; }
  else { r = bid - 5376; Hl = 16; tbase = 86016; ooff = 22020096; }
  size_t HW = (size_t)Hl * Hl;
  int hw64 = (int)(HW >> 6);
  int bat = r / (4 * hw64);
  int r2 = r - bat * 4 * hw64;
  int ct = r2 / hw64, hwt = r2 - ct * hw64;

  const unsigned short* src = Gt + (tbase + (size_t)bat * HW + (size_t)hwt * 64) * 256 + ct * 64;
  int tid = threadIdx.x;
  #pragma unroll
  for (int p = 0; p < 2; ++p){
    int id = p * 256 + tid;
    int t = id >> 3, c0 = (id & 7) * 8;
    u16x8 v = *reinterpret_cast<const u16x8*>(src + (size_t)t * 256 + c0);
    #pragma unroll
    for (int j = 0; j < 8; ++j) T[t][c0 + j] = bf2f(v[j]);
  }
  __syncthreads();
  float* dst = outb + ooff + (size_t)bat * HW * 256 + (size_t)(ct * 64) * HW + (size_t)hwt * 64;
  int cq = tid >> 4, hw0 = (tid & 15) * 4;
  #pragma unroll
  for (int p = 0; p < 4; ++p){
    int c = p * 16 + cq;
    float4 v;
    v.x = T[hw0][c]; v.y = T[hw0+1][c]; v.z = T[hw0+2][c]; v.w = T[hw0+3][c];
    *reinterpret_cast<float4*>(dst + (size_t)c * HW + hw0) = v;
  }
}

// ---- window geometry --------------------------------------------------------
struct WinGeo { int H, W, b, lvl; size_t HW, winoff, tbase, ooff; };

__device__ __forceinline__ WinGeo decode_win(int win){
  WinGeo g; int wloc;
  if (win < 512){ g.lvl = 0; wloc = win;      g.H = 128; g.tbase = 0;     g.ooff = 0; }
  else if (win < 640){ g.lvl = 1; wloc = win - 512; g.H = 64; g.tbase = 65536; g.ooff = 16777216; }
  else if (win < 672){ g.lvl = 2; wloc = win - 640; g.H = 32; g.tbase = 81920; g.ooff = 20971520; }
  else { g.lvl = 3; wloc = win - 672; g.H = 16; g.tbase = 86016; g.ooff = 22020096; }
  g.W = g.H; g.HW = (size_t)g.H * g.W;
  int nww = g.H >> 3, npb = nww * nww;
  g.b = wloc / npb;
  int r = wloc - g.b * npb;
  int wh = r / nww, ww = r - wh * nww;
  g.winoff = (size_t)(wh * 8) * g.W + (size_t)(ww * 8);
  return g;
}

// ---- v13: fully fused per-window kernel (v8 order tweak, no setprio) --------
__global__ __launch_bounds__(256, 2) void swin_win(
    const unsigned short* __restrict__ Ft, const unsigned short* __restrict__ Gtin,
    const unsigned short* __restrict__ wball,
    unsigned short* __restrict__ Gt, int phase)
{
  __shared__ alignas(16) unsigned short A[64*264];   // K -> P -> O -> out
  __shared__ alignas(16) unsigned short B[256*72];   // Q ([64][264] view) -> V^T
  int win = blockIdx.x;
  WinGeo g = decode_win(win);
  int tid = threadIdx.x;
  int w = tid >> 6, l = tid & 63, l15 = l & 15, l4 = l >> 4, wd = w * 64;
  int h = w >> 1, tc = w & 1;

  int batx = (phase == 0) ? g.b : g.b + 2;
  const unsigned short* Sx = Ft + (g.tbase + (size_t)batx * g.HW) * 256;
  const unsigned short* Sy = (phase == 0)
      ? Ft + (g.tbase + (size_t)(g.b + 2) * g.HW) * 256
      : Gtin + (g.tbase + (size_t)g.b * g.HW) * 256;
  unsigned short* Gout = Gt + (g.tbase + (size_t)batx * g.HW) * 256;

  size_t rowo[4];
  #pragma unroll
  for (int ni = 0; ni < 4; ++ni){
    int t = ni * 16 + l15;
    rowo[ni] = ((size_t)g.winoff + (size_t)(t >> 3) * g.W + (t & 7)) * 256;
  }
  const unsigned short* Wbase = wball + ((size_t)(phase * 16 + g.lvl * 4) << 16);
  const unsigned short* Wq = Wbase;
  const unsigned short* Wk = Wbase + 65536;
  const unsigned short* Wv = Wbase + 131072;
  const unsigned short* Wo = Wbase + 196608;

  // ---- Q GEMM first (low register pressure; compiler pipelines freely) ----
  {
    f32x4 aq[4][4];
    #pragma unroll
    for (int i = 0; i < 4; ++i)
      #pragma unroll
      for (int j = 0; j < 4; ++j) aq[i][j] = f32x4{0.f,0.f,0.f,0.f};
    #pragma unroll
    for (int ks = 0; ks < 8; ++ks){
      int k0 = ks * 32 + l4 * 8;
      bf16x8 tf[4], wf[4];
      #pragma unroll
      for (int i = 0; i < 4; ++i){
        tf[i] = *reinterpret_cast<const bf16x8*>(Sx + rowo[i] + k0);
        wf[i] = *reinterpret_cast<const bf16x8*>(Wq + (size_t)((wd + i*16 + l15) * 256 + k0));
      }
      #pragma unroll
      for (int mi = 0; mi < 4; ++mi)
        #pragma unroll
        for (int ni = 0; ni < 4; ++ni)
          aq[mi][ni] = MFMA16(wf[mi], tf[ni], aq[mi][ni], 0, 0, 0);
    }
    #pragma unroll
    for (int mi = 0; mi < 4; ++mi){
      int d0 = wd + mi*16 + l4*4;
      #pragma unroll
      for (int ni = 0; ni < 4; ++ni)
        store_bf4(&B[(ni*16 + l15) * 264 + d0], aq[mi][ni]);
    }
  }

  // ---- K & V GEMMs interleaved, shared Sy fragments ----
  f32x4 av[4][4];
  {
    f32x4 ak[4][4];
    #pragma unroll
    for (int i = 0; i < 4; ++i)
      #pragma unroll
      for (int j = 0; j < 4; ++j){ ak[i][j] = f32x4{0.f,0.f,0.f,0.f}; av[i][j] = f32x4{0.f,0.f,0.f,0.f}; }
    #pragma unroll
    for (int ks = 0; ks < 8; ++ks){
      int k0 = ks * 32 + l4 * 8;
      bf16x8 tf[4], kf[4], vf[4];
      #pragma unroll
      for (int i = 0; i < 4; ++i){
        tf[i] = *reinterpret_cast<const bf16x8*>(Sy + rowo[i] + k0);
        kf[i] = *reinterpret_cast<const bf16x8*>(Wk + (size_t)((wd + i*16 + l15) * 256 + k0));
        vf[i] = *reinterpret_cast<const bf16x8*>(Wv + (size_t)((wd + i*16 + l15) * 256 + k0));
      }
      #pragma unroll
      for (int mi = 0; mi < 4; ++mi)
        #pragma unroll
        for (int ni = 0; ni < 4; ++ni){
          ak[mi][ni] = MFMA16(kf[mi], tf[ni], ak[mi][ni], 0, 0, 0);
          av[mi][ni] = MFMA16(tf[mi], vf[ni], av[mi][ni], 0, 0, 0);
        }
    }
    // K[u][d] -> A
    #pragma unroll
    for (int mi = 0; mi < 4; ++mi){
      int d0 = wd + mi*16 + l4*4;
      #pragma unroll
      for (int ni = 0; ni < 4; ++ni)
        store_bf4(&A[(ni*16 + l15) * 264 + d0], ak[mi][ni]);
    }
  }
  __syncthreads();   // sync0: K(A), Q(B) visible

  // ---- S^T[u][t] per head from LDS K,Q ----
  f32x4 s[4][2];
  #pragma unroll
  for (int i = 0; i < 4; ++i){ s[i][0] = f32x4{0.f,0.f,0.f,0.f}; s[i][1] = f32x4{0.f,0.f,0.f,0.f}; }
  #pragma unroll
  for (int ks = 0; ks < 4; ++ks){
    int k0 = h * 128 + ks * 32 + l4 * 8;
    bf16x8 a[4], bb[2];
    #pragma unroll
    for (int mi = 0; mi < 4; ++mi)
      a[mi] = *reinterpret_cast<const bf16x8*>(&A[(mi*16 + l15) * 264 + k0]);
    #pragma unroll
    for (int ni = 0; ni < 2; ++ni)
      bb[ni] = *reinterpret_cast<const bf16x8*>(&B[(tc*32 + ni*16 + l15) * 264 + k0]);
    #pragma unroll
    for (int mi = 0; mi < 4; ++mi)
      #pragma unroll
      for (int ni = 0; ni < 2; ++ni)
        s[mi][ni] = MFMA16(a[mi], bb[ni], s[mi][ni], 0, 0, 0);
  }
  __syncthreads();   // sync1: K,Q reads done; A free for P, B free for V^T

  // ---- V^T (from registers) -> B ----
  #pragma unroll
  for (int mi = 0; mi < 4; ++mi){
    int u0 = mi*16 + l4*4;
    #pragma unroll
    for (int ni = 0; ni < 4; ++ni)
      store_bf4(&B[(wd + ni*16 + l15) * 72 + u0], av[mi][ni]);
  }

  // ---- softmax over u (per column t), P -> A ----
  const float SCL = 0.08838834764831845f;   // 1/sqrt(128)
  #pragma unroll
  for (int ni = 0; ni < 2; ++ni){
    float m = s[0][ni][0];
    #pragma unroll
    for (int mi = 0; mi < 4; ++mi)
      #pragma unroll
      for (int reg = 0; reg < 4; ++reg) m = fmaxf(m, s[mi][ni][reg]);
    m = fmaxf(m, __shfl_xor(m, 16));
    m = fmaxf(m, __shfl_xor(m, 32));
    float sum = 0.f;
    #pragma unroll
    for (int mi = 0; mi < 4; ++mi)
      #pragma unroll
      for (int reg = 0; reg < 4; ++reg){
        float e = __expf((s[mi][ni][reg] - m) * SCL);
        s[mi][ni][reg] = e; sum += e;
      }
    sum += __shfl_xor(sum, 16);
    sum += __shfl_xor(sum, 32);
    float rs = 1.0f / sum;
    int t = tc*32 + ni*16 + l15;
    #pragma unroll
    for (int mi = 0; mi < 4; ++mi){
      f32x4 pv;
      #pragma unroll
      for (int reg = 0; reg < 4; ++reg) pv[reg] = s[mi][ni][reg] * rs;
      store_bf4(&A[h * 4608 + t * 72 + mi*16 + l4*4], pv);
    }
  }
  __syncthreads();   // sync2: P(A), V^T(B) visible

  // ---- O^T[c][t] = V^T * P^T (both from LDS) ----
  f32x4 acc[4][4];
  #pragma unroll
  for (int i = 0; i < 4; ++i)
    #pragma unroll
    for (int j = 0; j < 4; ++j) acc[i][j] = f32x4{0.f,0.f,0.f,0.f};
  #pragma unroll
  for (int ks = 0; ks < 2; ++ks){
    int k0 = ks * 32 + l4 * 8;
    bf16x8 a[4], bb[4];
    #pragma unroll
    for (int mi = 0; mi < 4; ++mi)
      a[mi] = *reinterpret_cast<const bf16x8*>(&B[(wd + mi*16 + l15) * 72 + k0]);
    #pragma unroll
    for (int ni = 0; ni < 4; ++ni)
      bb[ni] = *reinterpret_cast<const bf16x8*>(&A[h * 4608 + (ni*16 + l15) * 72 + k0]);
    #pragma unroll
    for (int mi = 0; mi < 4; ++mi)
      #pragma unroll
      for (int ni = 0; ni < 4; ++ni)
        acc[mi][ni] = MFMA16(a[mi], bb[ni], acc[mi][ni], 0, 0, 0);
  }
  __syncthreads();   // sync3: P reads done; A free for O
  #pragma unroll
  for (int mi = 0; mi < 4; ++mi){
    int c0 = wd + mi*16 + l4*4;
    #pragma unroll
    for (int ni = 0; ni < 4; ++ni)
      store_bf4(&A[(ni*16 + l15) * 264 + c0], acc[mi][ni]);
  }
  __syncthreads();   // sync4: O(A) visible

  // ---- out^T = Wo * o^T ----
  #pragma unroll
  for (int i = 0; i < 4; ++i)
    #pragma unroll
    for (int j = 0; j < 4; ++j) acc[i][j] = f32x4{0.f,0.f,0.f,0.f};
  #pragma unroll
  for (int ks = 0; ks < 8; ++ks){
    int k0 = ks * 32 + l4 * 8;
    bf16x8 a[4], bb[4];
    #pragma unroll
    for (int mi = 0; mi < 4; ++mi)
      a[mi] = *reinterpret_cast<const bf16x8*>(Wo + (size_t)((wd + mi*16 + l15) * 256 + k0));
    #pragma unroll
    for (int ni = 0; ni < 4; ++ni)
      bb[ni] = *reinterpret_cast<const bf16x8*>(&A[(ni*16 + l15) * 264 + k0]);
    #pragma unroll
    for (int mi = 0; mi < 4; ++mi)
      #pragma unroll
      for (int ni = 0; ni < 4; ++ni)
        acc[mi][ni] = MFMA16(a[mi], bb[ni], acc[mi][ni], 0, 0, 0);
  }
  __syncthreads();   // sync5: O reads done; A free for out tile
  #pragma unroll
  for (int mi = 0; mi < 4; ++mi){
    int c0 = wd + mi*16 + l4*4;
    #pragma unroll
    for (int ni = 0; ni < 4; ++ni)
      store_bf4(&A[(ni*16 + l15) * 264 + c0], acc[mi][ni]);
  }
  __syncthreads();   // sync6: out(A) visible

  // ---- fused flush: out + residual, relu, 16B coalesced -> Gt ----
  #pragma unroll
  for (int p = 0; p < 8; ++p){
    int id = p * 256 + tid;
    int t = id >> 5, c = (id & 31) * 8;
    size_t ro = ((size_t)g.winoff + (size_t)(t >> 3) * g.W + (t & 7)) * 256 + c;
    u16x8 ov = *reinterpret_cast<const u16x8*>(&A[t * 264 + c]);
    u16x8 rv = *reinterpret_cast<const u16x8*>(Sx + ro);
    u16x8 o;
    #pragma unroll
    for (int j = 0; j < 8; ++j)
      o[j] = f2bf(fmaxf(bf2f(ov[j]) + bf2f(rv[j]), 0.f));
    *reinterpret_cast<u16x8*>(Gout + ro) = o;
  }
}

// ======================= round-1 fused fallback ==============================
__global__ __launch_bounds__(256, 1) void swin_phase(
    const float* __restrict__ g0, const float* __restrict__ g1,
    const float* __restrict__ g2, const float* __restrict__ g3,
    const unsigned short* __restrict__ wball,
    float* __restrict__ outb, int phase)
{
  __shared__ alignas(16) unsigned short R0[64*264];
  __shared__ alignas(16) unsigned short R1[64*264];
  __shared__ alignas(16) unsigned short R2[256*72];
  __shared__ alignas(16) unsigned short R3[64*264];

  int bid = blockIdx.x;
  WinGeo g = decode_win(bid);
  const float* feat = (g.lvl == 0) ? g0 : (g.lvl == 1) ? g1 : (g.lvl == 2) ? g2 : g3;
  size_t CHW = g.HW * 256;

  const float* xsrc; const float* ysrc; float* outp;
  if (phase == 0){
    xsrc = feat + (size_t)g.b * CHW + g.winoff;
    ysrc = feat + (size_t)(g.b + 2) * CHW + g.winoff;
    outp = outb + g.ooff + (size_t)g.b * CHW + g.winoff;
  } else {
    xsrc = feat + (size_t)(g.b + 2) * CHW + g.winoff;
    ysrc = outb + g.ooff + (size_t)g.b * CHW + g.winoff;
    outp = outb + g.ooff + (size_t)(g.b + 2) * CHW + g.winoff;
  }
  const unsigned short* Wq = wball + ((size_t)(phase * 16 + g.lvl * 4) << 16);
  const unsigned short* Wk = Wq + 65536;
  const unsigned short* Wv = Wq + 2 * 65536;
  const unsigned short* Wo = Wq + 3 * 65536;

  int tid = threadIdx.x;
  int w = tid >> 6, l = tid & 63, l15 = l & 15, l4 = l >> 4, wd = w * 64;
  int hi0 = l >> 3, wi0 = l & 7;

  {
    const float* p0 = ysrc + (size_t)hi0 * g.W + wi0;
    #pragma unroll
    for (int oc = 0; oc < 8; ++oc){
      int c0 = (oc * 4 + w) * 8;
      const float* p = p0 + (size_t)c0 * g.HW;
      u16x8 uv;
      #pragma unroll
      for (int j = 0; j < 8; ++j) uv[j] = f2bf(p[(size_t)j * g.HW]);
      *reinterpret_cast<u16x8*>(&R0[l * 264 + c0]) = uv;
    }
  }
  __syncthreads();
  {
    f32x4 acc[4][4];
    #pragma unroll
    for (int i = 0; i < 4; ++i)
      #pragma unroll
      for (int j = 0; j < 4; ++j) acc[i][j] = f32x4{0.f,0.f,0.f,0.f};
    #pragma unroll
    for (int ks = 0; ks < 8; ++ks){
      int k0 = ks * 32 + l4 * 8;
      bf16x8 a[4], bb[4];
      #pragma unroll
      for (int mi = 0; mi < 4; ++mi)
        a[mi] = *reinterpret_cast<const bf16x8*>(Wk + (size_t)((wd + mi*16 + l15) * 256 + k0));
      #pragma unroll
      for (int ni = 0; ni < 4; ++ni)
        bb[ni] = *reinterpret_cast<const bf16x8*>(&R0[(ni*16 + l15) * 264 + k0]);
      #pragma unroll
      for (int mi = 0; mi < 4; ++mi)
        #pragma unroll
        for (int ni = 0; ni < 4; ++ni)
          acc[mi][ni] = MFMA16(a[mi], bb[ni], acc[mi][ni], 0, 0, 0);
    }
    #pragma unroll
    for (int mi = 0; mi < 4; ++mi){
      int d0 = wd + mi*16 + l4*4;
      #pragma unroll
      for (int ni = 0; ni < 4; ++ni)
        store_bf4(&R1[(ni*16 + l15) * 264 + d0], acc[mi][ni]);
    }
  }
  {
    f32x4 acc[4][4];
    #pragma unroll
    for (int i = 0; i < 4; ++i)
      #pragma unroll
      for (int j = 0; j < 4; ++j) acc[i][j] = f32x4{0.f,0.f,0.f,0.f};
    #pragma unroll
    for (int ks = 0; ks < 8; ++ks){
      int k0 = ks * 32 + l4 * 8;
      bf16x8 a[4], bb[4];
      #pragma unroll
      for (int mi = 0; mi < 4; ++mi)
        a[mi] = *reinterpret_cast<const bf16x8*>(&R0[(mi*16 + l15) * 264 + k0]);
      #pragma unroll
      for (int ni = 0; ni < 4; ++ni)
        bb[ni] = *reinterpret_cast<const bf16x8*>(Wv + (size_t)((wd + ni*16 + l15) * 256 + k0));
      #pragma unroll
      for (int mi = 0; mi < 4; ++mi)
        #pragma unroll
        for (int ni = 0; ni < 4; ++ni)
          acc[mi][ni] = MFMA16(a[mi], bb[ni], acc[mi][ni], 0, 0, 0);
    }
    #pragma unroll
    for (int mi = 0; mi < 4; ++mi){
      int u0 = mi*16 + l4*4;
      #pragma unroll
      for (int ni = 0; ni < 4; ++ni)
        store_bf4(&R2[(wd + ni*16 + l15) * 72 + u0], acc[mi][ni]);
    }
  }
  __syncthreads();
  {
    const float* p0 = xsrc + (size_t)hi0 * g.W + wi0;
    #pragma unroll
    for (int oc = 0; oc < 8; ++oc){
      int c0 = (oc * 4 + w) * 8;
      const float* p = p0 + (size_t)c0 * g.HW;
      u16x8 uv;
      #pragma unroll
      for (int j = 0; j < 8; ++j) uv[j] = f2bf(p[(size_t)j * g.HW]);
      *reinterpret_cast<u16x8*>(&R0[l * 264 + c0]) = uv;
    }
  }
  __syncthreads();
  {
    f32x4 acc[4][4];
    #pragma unroll
    for (int i = 0; i < 4; ++i)
      #pragma unroll
      for (int j = 0; j < 4; ++j) acc[i][j] = f32x4{0.f,0.f,0.f,0.f};
    #pragma unroll
    for (int ks = 0; ks < 8; ++ks){
      int k0 = ks * 32 + l4 * 8;
      bf16x8 a[4], bb[4];
      #pragma unroll
      for (int mi = 0; mi < 4; ++mi)
        a[mi] = *reinterpret_cast<const bf16x8*>(Wq + (size_t)((wd + mi*16 + l15) * 256 + k0));
      #pragma unroll
      for (int ni = 0; ni < 4; ++ni)
        bb[ni] = *reinterpret_cast<const bf16x8*>(&R0[(ni*16 + l15) * 264 + k0]);
      #pragma unroll
      for (int mi = 0; mi < 4; ++mi)
        #pragma unroll
        for (int ni = 0; ni < 4; ++ni)
          acc[mi][ni] = MFMA16(a[mi], bb[ni], acc[mi][ni], 0, 0, 0);
    }
    #pragma unroll
    for (int mi = 0; mi < 4; ++mi){
      int d0 = wd + mi*16 + l4*4;
      #pragma unroll
      for (int ni = 0; ni < 4; ++ni)
        store_bf4(&R3[(ni*16 + l15) * 264 + d0], acc[mi][ni]);
    }
  }
  __syncthreads();

  int h = w >> 1, tc = w & 1;
  {
    f32x4 s[4][2];
    #pragma unroll
    for (int i = 0; i < 4; ++i){ s[i][0] = f32x4{0.f,0.f,0.f,0.f}; s[i][1] = f32x4{0.f,0.f,0.f,0.f}; }
    #pragma unroll
    for (int ks = 0; ks < 4; ++ks){
      int k0 = h * 128 + ks * 32 + l4 * 8;
      bf16x8 a[4], bb[2];
      #pragma unroll
      for (int mi = 0; mi < 4; ++mi)
        a[mi] = *reinterpret_cast<const bf16x8*>(&R1[(mi*16 + l15) * 264 + k0]);
      #pragma unroll
      for (int ni = 0; ni < 2; ++ni)
        bb[ni] = *reinterpret_cast<const bf16x8*>(&R3[(tc*32 + ni*16 + l15) * 264 + k0]);
      #pragma unroll
      for (int mi = 0; mi < 4; ++mi)
        #pragma unroll
        for (int ni = 0; ni < 2; ++ni)
          s[mi][ni] = MFMA16(a[mi], bb[ni], s[mi][ni], 0, 0, 0);
    }
    __syncthreads();
    const float SCL = 0.08838834764831845f;
    unsigned short* P = R1;
    #pragma unroll
    for (int ni = 0; ni < 2; ++ni){
      float m = s[0][ni][0];
      #pragma unroll
      for (int mi = 0; mi < 4; ++mi)
        #pragma unroll
        for (int reg = 0; reg < 4; ++reg) m = fmaxf(m, s[mi][ni][reg]);
      m = fmaxf(m, __shfl_xor(m, 16));
      m = fmaxf(m, __shfl_xor(m, 32));
      float sum = 0.f;
      #pragma unroll
      for (int mi = 0; mi < 4; ++mi)
        #pragma unroll
        for (int reg = 0; reg < 4; ++reg){
          float e = __expf((s[mi][ni][reg] - m) * SCL);
          s[mi][ni][reg] = e; sum += e;
        }
      sum += __shfl_xor(sum, 16);
      sum += __shfl_xor(sum, 32);
      float rs = 1.0f / sum;
      int t = tc*32 + ni*16 + l15;
      #pragma unroll
      for (int mi = 0; mi < 4; ++mi){
        f32x4 pv;
        #pragma unroll
        for (int reg = 0; reg < 4; ++reg) pv[reg] = s[mi][ni][reg] * rs;
        store_bf4(&P[h * 4608 + t * 72 + mi*16 + l4*4], pv);
      }
    }
  }
  __syncthreads();
  {
    int wdh = h * 128 + tc * 64;
    f32x4 acc[4][4];
    #pragma unroll
    for (int i = 0; i < 4; ++i)
      #pragma unroll
      for (int j = 0; j < 4; ++j) acc[i][j] = f32x4{0.f,0.f,0.f,0.f};
    const unsigned short* P = R1;
    #pragma unroll
    for (int ks = 0; ks < 2; ++ks){
      int k0 = ks * 32 + l4 * 8;
      bf16x8 a[4], bb[4];
      #pragma unroll
      for (int mi = 0; mi < 4; ++mi)
        a[mi] = *reinterpret_cast<const bf16x8*>(&R2[(wdh + mi*16 + l15) * 72 + k0]);
      #pragma unroll
      for (int ni = 0; ni < 4; ++ni)
        bb[ni] = *reinterpret_cast<const bf16x8*>(&P[h * 4608 + (ni*16 + l15) * 72 + k0]);
      #pragma unroll
      for (int mi = 0; mi < 4; ++mi)
        #pragma unroll
        for (int ni = 0; ni < 4; ++ni)
          acc[mi][ni] = MFMA16(a[mi], bb[ni], acc[mi][ni], 0, 0, 0);
    }
    #pragma unroll
    for (int mi = 0; mi < 4; ++mi){
      int c0 = wdh + mi*16 + l4*4;
      #pragma unroll
      for (int ni = 0; ni < 4; ++ni)
        store_bf4(&R0[(ni*16 + l15) * 264 + c0], acc[mi][ni]);
    }
  }
  __syncthreads();
  {
    f32x4 acc[4][4];
    #pragma unroll
    for (int i = 0; i < 4; ++i)
      #pragma unroll
      for (int j = 0; j < 4; ++j) acc[i][j] = f32x4{0.f,0.f,0.f,0.f};
    #pragma unroll
    for (int ks = 0; ks < 8; ++ks){
      int k0 = ks * 32 + l4 * 8;
      bf16x8 a[4], bb[4];
      #pragma unroll
      for (int mi = 0; mi < 4; ++mi)
        a[mi] = *reinterpret_cast<const bf16x8*>(Wo + (size_t)((wd + mi*16 + l15) * 256 + k0));
      #pragma unroll
      for (int ni = 0; ni < 4; ++ni)
        bb[ni] = *reinterpret_cast<const bf16x8*>(&R0[(ni*16 + l15) * 264 + k0]);
      #pragma unroll
      for (int mi = 0; mi < 4; ++mi)
        #pragma unroll
        for (int ni = 0; ni < 4; ++ni)
          acc[mi][ni] = MFMA16(a[mi], bb[ni], acc[mi][ni], 0, 0, 0);
    }
    #pragma unroll
    for (int mi = 0; mi < 4; ++mi){
      #pragma unroll
      for (int ni = 0; ni < 4; ++ni){
        int t = ni*16 + l15, thi = t >> 3, twi = t & 7;
        size_t base = (size_t)(wd + mi*16 + l4*4) * g.HW + (size_t)thi * g.W + twi;
        #pragma unroll
        for (int reg = 0; reg < 4; ++reg){
          float res = xsrc[base + (size_t)reg * g.HW];
          float v = acc[mi][ni][reg] + res;
          outp[base + (size_t)reg * g.HW] = fmaxf(v, 0.f);
        }
      }
    }
  }
}

extern "C" void kernel_launch(void* const* d_in, const int* in_sizes, int n_in,
                              void* d_out, int out_size, void* d_ws, size_t ws_size,
                              hipStream_t stream) {
  (void)in_sizes; (void)n_in; (void)out_size;
  const float* f0 = (const float*)d_in[0];
  const float* f1 = (const float*)d_in[1];
  const float* f2 = (const float*)d_in[2];
  const float* f3 = (const float*)d_in[3];
  const float* w1 = (const float*)d_in[4];
  const float* w2 = (const float*)d_in[5];
  float* out = (float*)d_out;

  unsigned short* wbf = (unsigned short*)d_ws;
  const size_t WBF_B = 4194304;       // 2*16*65536 bf16
  const size_t FT_B  = 44564480;      // 87040 tokens * 256 * 2B
  const size_t need  = WBF_B + 2 * FT_B;   // 93,323,264

  wcvt_kernel<<<2048, 256, 0, stream>>>(w1, w2, wbf);

  if (ws_size >= need){
    char* base = (char*)d_ws + WBF_B;
    unsigned short* Ft = (unsigned short*)(base);
    unsigned short* Gt = (unsigned short*)(base + FT_B);

    xpose_kernel<<<5440, 256, 0, stream>>>(f0, f1, f2, f3, Ft);
    for (int phase = 0; phase < 2; ++phase)
      swin_win<<<680, 256, 0, stream>>>(Ft, Gt, wbf, Gt, phase);
    untrans_kernel<<<5440, 256, 0, stream>>>(Gt, out);
  } else {
    swin_phase<<<680, 256, 0, stream>>>(f0, f1, f2, f3, wbf, out, 0);
    swin_phase<<<680, 256, 0, stream>>>(f0, f1, f2, f3, wbf, out, 1);
  }
}

// Round 14
// 198.959 us; speedup vs baseline: 1.2307x; 1.0392x over previous
//
#include <hip/hip_runtime.h>

// Swin cross-attention pipeline v14 for MI355X = v8 restored byte-exact.
// v8 (R8) measured 199us, the session best. Rounds 9-13 isolated and rejected:
// 512-thread blocks (spill), K+Q load merge (chain lengthening), phase fusion
// + static balance (idle CUs), manual dbuf pipelining (spill), setprio removal
// (regression: our 2-independent-blocks/CU regime is m191's attn regime where
// setprio(1) around MFMA helps inter-block arbitration, not m190's lockstep).
// Structure: xpose -> [swin_win x2 phases] -> untrans; swin_win fuses
// QKV-proj + attention + Wo-proj per window, LDS A/B aliased, 2 blocks/CU.

using bf16x8 = __attribute__((ext_vector_type(8))) __bf16;
using f32x4  = __attribute__((ext_vector_type(4))) float;
using u16x4  = __attribute__((ext_vector_type(4))) unsigned short;
using u16x8  = __attribute__((ext_vector_type(8))) unsigned short;

__device__ __forceinline__ unsigned short f2bf(float f){
  unsigned int x = __float_as_uint(f);
  x += 0x7FFFu + ((x >> 16) & 1u);          // RNE
  return (unsigned short)(x >> 16);
}
__device__ __forceinline__ float bf2f(unsigned short u){
  return __uint_as_float((unsigned int)u << 16);
}
__device__ __forceinline__ void store_bf4(unsigned short* dst, f32x4 v){
  u16x4 o;
  o[0]=f2bf(v[0]); o[1]=f2bf(v[1]); o[2]=f2bf(v[2]); o[3]=f2bf(v[3]);
  *reinterpret_cast<u16x4*>(dst) = o;
}

#define MFMA16 __builtin_amdgcn_mfma_f32_16x16x32_bf16

__global__ void wcvt_kernel(const float* __restrict__ w1,
                            const float* __restrict__ w2,
                            unsigned short* __restrict__ dst){
  int i = blockIdx.x * 256 + threadIdx.x;
  const float4* src = (i < 262144) ? (reinterpret_cast<const float4*>(w1) + i)
                                   : (reinterpret_cast<const float4*>(w2) + (i - 262144));
  float4 v = *src;
  u16x4 o; o[0]=f2bf(v.x); o[1]=f2bf(v.y); o[2]=f2bf(v.z); o[3]=f2bf(v.w);
  reinterpret_cast<u16x4*>(dst)[i] = o;
}

// ---- transpose fp32 [C,HW] -> bf16 Ft[token][c] -----------------------------
__global__ __launch_bounds__(256, 2) void xpose_kernel(
    const float* __restrict__ g0, const float* __restrict__ g1,
    const float* __restrict__ g2, const float* __restrict__ g3,
    unsigned short* __restrict__ Ft)
{
  __shared__ float T[64][65];
  int bid = blockIdx.x;
  int r; const float* feat; int Hl; size_t tbase;
  if (bid < 4096){ r = bid;        feat = g0; Hl = 128; tbase = 0; }
  else if (bid < 5120){ r = bid - 4096; feat = g1; Hl = 64;  tbase = 65536; }
  else if (bid < 5376){ r = bid - 5120; feat = g2; Hl = 32;  tbase = 81920; }
  else { r = bid - 5376; feat = g3; Hl = 16;  tbase = 86016; }
  size_t HW = (size_t)Hl * Hl;
  int hw64 = (int)(HW >> 6);
  int bat = r / (4 * hw64);
  int r2 = r - bat * 4 * hw64;
  int ct = r2 / hw64, hwt = r2 - ct * hw64;

  const float* src = feat + (size_t)bat * HW * 256 + (size_t)(ct * 64) * HW + (size_t)hwt * 64;
  int tid = threadIdx.x;
  int cq = tid >> 4, hw0 = (tid & 15) * 4;
  #pragma unroll
  for (int p = 0; p < 4; ++p){
    int c = p * 16 + cq;
    const float* sp = src + (size_t)c * HW + hw0;
    float4 v = *reinterpret_cast<const float4*>(sp);
    T[c][hw0] = v.x; T[c][hw0+1] = v.y; T[c][hw0+2] = v.z; T[c][hw0+3] = v.w;
  }
  __syncthreads();
  unsigned short* dst = Ft + (tbase + (size_t)bat * HW + (size_t)hwt * 64) * 256 + ct * 64;
  #pragma unroll
  for (int p = 0; p < 2; ++p){
    int id = p * 256 + tid;
    int t = id >> 3, c0 = (id & 7) * 8;
    u16x8 o;
    #pragma unroll
    for (int j = 0; j < 8; ++j) o[j] = f2bf(T[c0 + j][t]);
    *reinterpret_cast<u16x8*>(dst + (size_t)t * 256 + c0) = o;
  }
}

// ---- transpose back: Gt[token][c] bf16 -> fp32 out [C,HW], ALL 4 batches ----
__global__ __launch_bounds__(256, 2) void untrans_kernel(
    const unsigned short* __restrict__ Gt, float* __restrict__ outb)
{
  __shared__ float T[64][65];
  int bid = blockIdx.x;
  int r; int Hl; size_t tbase, ooff;
  if (bid < 4096){ r = bid;        Hl = 128; tbase = 0;     ooff = 0; }
  else if (bid < 5120){ r = bid - 4096; Hl = 64; tbase = 65536; ooff = 16777216; }
  else if (bid < 5376){ r = bid - 5120; Hl = 32; tbase = 81920; ooff = 20971520; }
  else { r = bid - 5376; Hl = 16; tbase = 86016; ooff = 22020096; }
  size_t HW = (size_t)Hl * Hl;
  int hw64 = (int)(HW >> 6);
  int bat = r / (4 * hw64);
  int r2 = r - bat * 4 * hw64;
  int ct = r2 / hw64, hwt = r2 - ct * hw64;

  const unsigned short* src = Gt + (tbase + (size_t)bat * HW + (size_t)hwt * 64) * 256 + ct * 64;
  int tid = threadIdx.x;
  #pragma unroll
  for (int p = 0; p < 2; ++p){
    int id = p * 256 + tid;
    int t = id >> 3, c0 = (id & 7) * 8;
    u16x8 v = *reinterpret_cast<const u16x8*>(src + (size_t)t * 256 + c0);
    #pragma unroll
    for (int j = 0; j < 8; ++j) T[t][c0 + j] = bf2f(v[j]);
  }
  __syncthreads();
  float* dst = outb + ooff + (size_t)bat * HW * 256 + (size_t)(ct * 64) * HW + (size_t)hwt * 64;
  int cq = tid >> 4, hw0 = (tid & 15) * 4;
  #pragma unroll
  for (int p = 0; p < 4; ++p){
    int c = p * 16 + cq;
    float4 v;
    v.x = T[hw0][c]; v.y = T[hw0+1][c]; v.z = T[hw0+2][c]; v.w = T[hw0+3][c];
    *reinterpret_cast<float4*>(dst + (size_t)c * HW + hw0) = v;
  }
}

// ---- window geometry --------------------------------------------------------
struct WinGeo { int H, W, b, lvl; size_t HW, winoff, tbase, ooff; };

__device__ __forceinline__ WinGeo decode_win(int win){
  WinGeo g; int wloc;
  if (win < 512){ g.lvl = 0; wloc = win;      g.H = 128; g.tbase = 0;     g.ooff = 0; }
  else if (win < 640){ g.lvl = 1; wloc = win - 512; g.H = 64; g.tbase = 65536; g.ooff = 16777216; }
  else if (win < 672){ g.lvl = 2; wloc = win - 640; g.H = 32; g.tbase = 81920; g.ooff = 20971520; }
  else { g.lvl = 3; wloc = win - 672; g.H = 16; g.tbase = 86016; g.ooff = 22020096; }
  g.W = g.H; g.HW = (size_t)g.H * g.W;
  int nww = g.H >> 3, npb = nww * nww;
  g.b = wloc / npb;
  int r = wloc - g.b * npb;
  int wh = r / nww, ww = r - wh * nww;
  g.winoff = (size_t)(wh * 8) * g.W + (size_t)(ww * 8);
  return g;
}

// ---- v8: fully fused per-window kernel --------------------------------------
__global__ __launch_bounds__(256, 2) void swin_win(
    const unsigned short* __restrict__ Ft, const unsigned short* __restrict__ Gtin,
    const unsigned short* __restrict__ wball,
    unsigned short* __restrict__ Gt, int phase)
{
  __shared__ alignas(16) unsigned short A[64*264];   // K -> P -> O -> out
  __shared__ alignas(16) unsigned short B[256*72];   // Q ([64][264] view) -> V^T
  int win = blockIdx.x;
  WinGeo g = decode_win(win);
  int tid = threadIdx.x;
  int w = tid >> 6, l = tid & 63, l15 = l & 15, l4 = l >> 4, wd = w * 64;
  int h = w >> 1, tc = w & 1;

  int batx = (phase == 0) ? g.b : g.b + 2;
  const unsigned short* Sx = Ft + (g.tbase + (size_t)batx * g.HW) * 256;
  const unsigned short* Sy = (phase == 0)
      ? Ft + (g.tbase + (size_t)(g.b + 2) * g.HW) * 256
      : Gtin + (g.tbase + (size_t)g.b * g.HW) * 256;
  unsigned short* Gout = Gt + (g.tbase + (size_t)batx * g.HW) * 256;

  size_t rowo[4];
  #pragma unroll
  for (int ni = 0; ni < 4; ++ni){
    int t = ni * 16 + l15;
    rowo[ni] = ((size_t)g.winoff + (size_t)(t >> 3) * g.W + (t & 7)) * 256;
  }
  const unsigned short* Wbase = wball + ((size_t)(phase * 16 + g.lvl * 4) << 16);
  const unsigned short* Wq = Wbase;
  const unsigned short* Wk = Wbase + 65536;
  const unsigned short* Wv = Wbase + 131072;
  const unsigned short* Wo = Wbase + 196608;

  // ---- K & V GEMMs interleaved, shared Sy fragments (Sy read ONCE) ----
  f32x4 av[4][4];
  {
    f32x4 ak[4][4];
    #pragma unroll
    for (int i = 0; i < 4; ++i)
      #pragma unroll
      for (int j = 0; j < 4; ++j){ ak[i][j] = f32x4{0.f,0.f,0.f,0.f}; av[i][j] = f32x4{0.f,0.f,0.f,0.f}; }
    #pragma unroll
    for (int ks = 0; ks < 8; ++ks){
      int k0 = ks * 32 + l4 * 8;
      bf16x8 tf[4], kf[4], vf[4];
      #pragma unroll
      for (int i = 0; i < 4; ++i){
        tf[i] = *reinterpret_cast<const bf16x8*>(Sy + rowo[i] + k0);
        kf[i] = *reinterpret_cast<const bf16x8*>(Wk + (size_t)((wd + i*16 + l15) * 256 + k0));
        vf[i] = *reinterpret_cast<const bf16x8*>(Wv + (size_t)((wd + i*16 + l15) * 256 + k0));
      }
      __builtin_amdgcn_s_setprio(1);
      #pragma unroll
      for (int mi = 0; mi < 4; ++mi)
        #pragma unroll
        for (int ni = 0; ni < 4; ++ni){
          ak[mi][ni] = MFMA16(kf[mi], tf[ni], ak[mi][ni], 0, 0, 0);
          av[mi][ni] = MFMA16(tf[mi], vf[ni], av[mi][ni], 0, 0, 0);
        }
      __builtin_amdgcn_s_setprio(0);
    }
    // K[u][d] -> A
    #pragma unroll
    for (int mi = 0; mi < 4; ++mi){
      int d0 = wd + mi*16 + l4*4;
      #pragma unroll
      for (int ni = 0; ni < 4; ++ni)
        store_bf4(&A[(ni*16 + l15) * 264 + d0], ak[mi][ni]);
    }
  }
  // av stays live in registers until after S.

  // ---- Q GEMM -> B ([64][264] view) ----
  {
    f32x4 aq[4][4];
    #pragma unroll
    for (int i = 0; i < 4; ++i)
      #pragma unroll
      for (int j = 0; j < 4; ++j) aq[i][j] = f32x4{0.f,0.f,0.f,0.f};
    #pragma unroll
    for (int ks = 0; ks < 8; ++ks){
      int k0 = ks * 32 + l4 * 8;
      bf16x8 tf[4], wf[4];
      #pragma unroll
      for (int i = 0; i < 4; ++i){
        tf[i] = *reinterpret_cast<const bf16x8*>(Sx + rowo[i] + k0);
        wf[i] = *reinterpret_cast<const bf16x8*>(Wq + (size_t)((wd + i*16 + l15) * 256 + k0));
      }
      __builtin_amdgcn_s_setprio(1);
      #pragma unroll
      for (int mi = 0; mi < 4; ++mi)
        #pragma unroll
        for (int ni = 0; ni < 4; ++ni)
          aq[mi][ni] = MFMA16(wf[mi], tf[ni], aq[mi][ni], 0, 0, 0);
      __builtin_amdgcn_s_setprio(0);
    }
    #pragma unroll
    for (int mi = 0; mi < 4; ++mi){
      int d0 = wd + mi*16 + l4*4;
      #pragma unroll
      for (int ni = 0; ni < 4; ++ni)
        store_bf4(&B[(ni*16 + l15) * 264 + d0], aq[mi][ni]);
    }
  }
  __syncthreads();   // sync0: K(A), Q(B) visible

  // ---- S^T[u][t] per head from LDS K,Q ----
  f32x4 s[4][2];
  #pragma unroll
  for (int i = 0; i < 4; ++i){ s[i][0] = f32x4{0.f,0.f,0.f,0.f}; s[i][1] = f32x4{0.f,0.f,0.f,0.f}; }
  #pragma unroll
  for (int ks = 0; ks < 4; ++ks){
    int k0 = h * 128 + ks * 32 + l4 * 8;
    bf16x8 a[4], bb[2];
    #pragma unroll
    for (int mi = 0; mi < 4; ++mi)
      a[mi] = *reinterpret_cast<const bf16x8*>(&A[(mi*16 + l15) * 264 + k0]);
    #pragma unroll
    for (int ni = 0; ni < 2; ++ni)
      bb[ni] = *reinterpret_cast<const bf16x8*>(&B[(tc*32 + ni*16 + l15) * 264 + k0]);
    __builtin_amdgcn_s_setprio(1);
    #pragma unroll
    for (int mi = 0; mi < 4; ++mi)
      #pragma unroll
      for (int ni = 0; ni < 2; ++ni)
        s[mi][ni] = MFMA16(a[mi], bb[ni], s[mi][ni], 0, 0, 0);
    __builtin_amdgcn_s_setprio(0);
  }
  __syncthreads();   // sync1: K,Q reads done; A free for P, B free for V^T

  // ---- V^T (from registers) -> B ----
  #pragma unroll
  for (int mi = 0; mi < 4; ++mi){
    int u0 = mi*16 + l4*4;
    #pragma unroll
    for (int ni = 0; ni < 4; ++ni)
      store_bf4(&B[(wd + ni*16 + l15) * 72 + u0], av[mi][ni]);
  }

  // ---- softmax over u (per column t), P -> A ----
  const float SCL = 0.08838834764831845f;   // 1/sqrt(128)
  #pragma unroll
  for (int ni = 0; ni < 2; ++ni){
    float m = s[0][ni][0];
    #pragma unroll
    for (int mi = 0; mi < 4; ++mi)
      #pragma unroll
      for (int reg = 0; reg < 4; ++reg) m = fmaxf(m, s[mi][ni][reg]);
    m = fmaxf(m, __shfl_xor(m, 16));
    m = fmaxf(m, __shfl_xor(m, 32));
    float sum = 0.f;
    #pragma unroll
    for (int mi = 0; mi < 4; ++mi)
      #pragma unroll
      for (int reg = 0; reg < 4; ++reg){
        float e = __expf((s[mi][ni][reg] - m) * SCL);
        s[mi][ni][reg] = e; sum += e;
      }
    sum += __shfl_xor(sum, 16);
    sum += __shfl_xor(sum, 32);
    float rs = 1.0f / sum;
    int t = tc*32 + ni*16 + l15;
    #pragma unroll
    for (int mi = 0; mi < 4; ++mi){
      f32x4 pv;
      #pragma unroll
      for (int reg = 0; reg < 4; ++reg) pv[reg] = s[mi][ni][reg] * rs;
      store_bf4(&A[h * 4608 + t * 72 + mi*16 + l4*4], pv);
    }
  }
  __syncthreads();   // sync2: P(A), V^T(B) visible

  // ---- O^T[c][t] = V^T * P^T (both from LDS) ----
  f32x4 acc[4][4];
  #pragma unroll
  for (int i = 0; i < 4; ++i)
    #pragma unroll
    for (int j = 0; j < 4; ++j) acc[i][j] = f32x4{0.f,0.f,0.f,0.f};
  #pragma unroll
  for (int ks = 0; ks < 2; ++ks){
    int k0 = ks * 32 + l4 * 8;
    bf16x8 a[4], bb[4];
    #pragma unroll
    for (int mi = 0; mi < 4; ++mi)
      a[mi] = *reinterpret_cast<const bf16x8*>(&B[(wd + mi*16 + l15) * 72 + k0]);
    #pragma unroll
    for (int ni = 0; ni < 4; ++ni)
      bb[ni] = *reinterpret_cast<const bf16x8*>(&A[h * 4608 + (ni*16 + l15) * 72 + k0]);
    __builtin_amdgcn_s_setprio(1);
    #pragma unroll
    for (int mi = 0; mi < 4; ++mi)
      #pragma unroll
      for (int ni = 0; ni < 4; ++ni)
        acc[mi][ni] = MFMA16(a[mi], bb[ni], acc[mi][ni], 0, 0, 0);
    __builtin_amdgcn_s_setprio(0);
  }
  __syncthreads();   // sync3: P reads done; A free for O
  #pragma unroll
  for (int mi = 0; mi < 4; ++mi){
    int c0 = wd + mi*16 + l4*4;
    #pragma unroll
    for (int ni = 0; ni < 4; ++ni)
      store_bf4(&A[(ni*16 + l15) * 264 + c0], acc[mi][ni]);
  }
  __syncthreads();   // sync4: O(A) visible

  // ---- out^T = Wo * o^T ----
  #pragma unroll
  for (int i = 0; i < 4; ++i)
    #pragma unroll
    for (int j = 0; j < 4; ++j) acc[i][j] = f32x4{0.f,0.f,0.f,0.f};
  #pragma unroll
  for (int ks = 0; ks < 8; ++ks){
    int k0 = ks * 32 + l4 * 8;
    bf16x8 a[4], bb[4];
    #pragma unroll
    for (int mi = 0; mi < 4; ++mi)
      a[mi] = *reinterpret_cast<const bf16x8*>(Wo + (size_t)((wd + mi*16 + l15) * 256 + k0));
    #pragma unroll
    for (int ni = 0; ni < 4; ++ni)
      bb[ni] = *reinterpret_cast<const bf16x8*>(&A[(ni*16 + l15) * 264 + k0]);
    __builtin_amdgcn_s_setprio(1);
    #pragma unroll
    for (int mi = 0; mi < 4; ++mi)
      #pragma unroll
      for (int ni = 0; ni < 4; ++ni)
        acc[mi][ni] = MFMA16(a[mi], bb[ni], acc[mi][ni], 0, 0, 0);
    __builtin_amdgcn_s_setprio(0);
  }
  __syncthreads();   // sync5: O reads done; A free for out tile
  #pragma unroll
  for (int mi = 0; mi < 4; ++mi){
    int c0 = wd + mi*16 + l4*4;
    #pragma unroll
    for (int ni = 0; ni < 4; ++ni)
      store_bf4(&A[(ni*16 + l15) * 264 + c0], acc[mi][ni]);
  }
  __syncthreads();   // sync6: out(A) visible

  // ---- fused flush: out + residual, relu, 16B coalesced -> Gt ----
  #pragma unroll
  for (int p = 0; p < 8; ++p){
    int id = p * 256 + tid;
    int t = id >> 5, c = (id & 31) * 8;
    size_t ro = ((size_t)g.winoff + (size_t)(t >> 3) * g.W + (t & 7)) * 256 + c;
    u16x8 ov = *reinterpret_cast<const u16x8*>(&A[t * 264 + c]);
    u16x8 rv = *reinterpret_cast<const u16x8*>(Sx + ro);
    u16x8 o;
    #pragma unroll
    for (int j = 0; j < 8; ++j)
      o[j] = f2bf(fmaxf(bf2f(ov[j]) + bf2f(rv[j]), 0.f));
    *reinterpret_cast<u16x8*>(Gout + ro) = o;
  }
}

// ======================= round-1 fused fallback ==============================
__global__ __launch_bounds__(256, 1) void swin_phase(
    const float* __restrict__ g0, const float* __restrict__ g1,
    const float* __restrict__ g2, const float* __restrict__ g3,
    const unsigned short* __restrict__ wball,
    float* __restrict__ outb, int phase)
{
  __shared__ alignas(16) unsigned short R0[64*264];
  __shared__ alignas(16) unsigned short R1[64*264];
  __shared__ alignas(16) unsigned short R2[256*72];
  __shared__ alignas(16) unsigned short R3[64*264];

  int bid = blockIdx.x;
  WinGeo g = decode_win(bid);
  const float* feat = (g.lvl == 0) ? g0 : (g.lvl == 1) ? g1 : (g.lvl == 2) ? g2 : g3;
  size_t CHW = g.HW * 256;

  const float* xsrc; const float* ysrc; float* outp;
  if (phase == 0){
    xsrc = feat + (size_t)g.b * CHW + g.winoff;
    ysrc = feat + (size_t)(g.b + 2) * CHW + g.winoff;
    outp = outb + g.ooff + (size_t)g.b * CHW + g.winoff;
  } else {
    xsrc = feat + (size_t)(g.b + 2) * CHW + g.winoff;
    ysrc = outb + g.ooff + (size_t)g.b * CHW + g.winoff;
    outp = outb + g.ooff + (size_t)(g.b + 2) * CHW + g.winoff;
  }
  const unsigned short* Wq = wball + ((size_t)(phase * 16 + g.lvl * 4) << 16);
  const unsigned short* Wk = Wq + 65536;
  const unsigned short* Wv = Wq + 2 * 65536;
  const unsigned short* Wo = Wq + 3 * 65536;

  int tid = threadIdx.x;
  int w = tid >> 6, l = tid & 63, l15 = l & 15, l4 = l >> 4, wd = w * 64;
  int hi0 = l >> 3, wi0 = l & 7;

  {
    const float* p0 = ysrc + (size_t)hi0 * g.W + wi0;
    #pragma unroll
    for (int oc = 0; oc < 8; ++oc){
      int c0 = (oc * 4 + w) * 8;
      const float* p = p0 + (size_t)c0 * g.HW;
      u16x8 uv;
      #pragma unroll
      for (int j = 0; j < 8; ++j) uv[j] = f2bf(p[(size_t)j * g.HW]);
      *reinterpret_cast<u16x8*>(&R0[l * 264 + c0]) = uv;
    }
  }
  __syncthreads();
  {
    f32x4 acc[4][4];
    #pragma unroll
    for (int i = 0; i < 4; ++i)
      #pragma unroll
      for (int j = 0; j < 4; ++j) acc[i][j] = f32x4{0.f,0.f,0.f,0.f};
    #pragma unroll
    for (int ks = 0; ks < 8; ++ks){
      int k0 = ks * 32 + l4 * 8;
      bf16x8 a[4], bb[4];
      #pragma unroll
      for (int mi = 0; mi < 4; ++mi)
        a[mi] = *reinterpret_cast<const bf16x8*>(Wk + (size_t)((wd + mi*16 + l15) * 256 + k0));
      #pragma unroll
      for (int ni = 0; ni < 4; ++ni)
        bb[ni] = *reinterpret_cast<const bf16x8*>(&R0[(ni*16 + l15) * 264 + k0]);
      #pragma unroll
      for (int mi = 0; mi < 4; ++mi)
        #pragma unroll
        for (int ni = 0; ni < 4; ++ni)
          acc[mi][ni] = MFMA16(a[mi], bb[ni], acc[mi][ni], 0, 0, 0);
    }
    #pragma unroll
    for (int mi = 0; mi < 4; ++mi){
      int d0 = wd + mi*16 + l4*4;
      #pragma unroll
      for (int ni = 0; ni < 4; ++ni)
        store_bf4(&R1[(ni*16 + l15) * 264 + d0], acc[mi][ni]);
    }
  }
  {
    f32x4 acc[4][4];
    #pragma unroll
    for (int i = 0; i < 4; ++i)
      #pragma unroll
      for (int j = 0; j < 4; ++j) acc[i][j] = f32x4{0.f,0.f,0.f,0.f};
    #pragma unroll
    for (int ks = 0; ks < 8; ++ks){
      int k0 = ks * 32 + l4 * 8;
      bf16x8 a[4], bb[4];
      #pragma unroll
      for (int mi = 0; mi < 4; ++mi)
        a[mi] = *reinterpret_cast<const bf16x8*>(&R0[(mi*16 + l15) * 264 + k0]);
      #pragma unroll
      for (int ni = 0; ni < 4; ++ni)
        bb[ni] = *reinterpret_cast<const bf16x8*>(Wv + (size_t)((wd + ni*16 + l15) * 256 + k0));
      #pragma unroll
      for (int mi = 0; mi < 4; ++mi)
        #pragma unroll
        for (int ni = 0; ni < 4; ++ni)
          acc[mi][ni] = MFMA16(a[mi], bb[ni], acc[mi][ni], 0, 0, 0);
    }
    #pragma unroll
    for (int mi = 0; mi < 4; ++mi){
      int u0 = mi*16 + l4*4;
      #pragma unroll
      for (int ni = 0; ni < 4; ++ni)
        store_bf4(&R2[(wd + ni*16 + l15) * 72 + u0], acc[mi][ni]);
    }
  }
  __syncthreads();
  {
    const float* p0 = xsrc + (size_t)hi0 * g.W + wi0;
    #pragma unroll
    for (int oc = 0; oc < 8; ++oc){
      int c0 = (oc * 4 + w) * 8;
      const float* p = p0 + (size_t)c0 * g.HW;
      u16x8 uv;
      #pragma unroll
      for (int j = 0; j < 8; ++j) uv[j] = f2bf(p[(size_t)j * g.HW]);
      *reinterpret_cast<u16x8*>(&R0[l * 264 + c0]) = uv;
    }
  }
  __syncthreads();
  {
    f32x4 acc[4][4];
    #pragma unroll
    for (int i = 0; i < 4; ++i)
      #pragma unroll
      for (int j = 0; j < 4; ++j) acc[i][j] = f32x4{0.f,0.f,0.f,0.f};
    #pragma unroll
    for (int ks = 0; ks < 8; ++ks){
      int k0 = ks * 32 + l4 * 8;
      bf16x8 a[4], bb[4];
      #pragma unroll
      for (int mi = 0; mi < 4; ++mi)
        a[mi] = *reinterpret_cast<const bf16x8*>(Wq + (size_t)((wd + mi*16 + l15) * 256 + k0));
      #pragma unroll
      for (int ni = 0; ni < 4; ++ni)
        bb[ni] = *reinterpret_cast<const bf16x8*>(&R0[(ni*16 + l15) * 264 + k0]);
      #pragma unroll
      for (int mi = 0; mi < 4; ++mi)
        #pragma unroll
        for (int ni = 0; ni < 4; ++ni)
          acc[mi][ni] = MFMA16(a[mi], bb[ni], acc[mi][ni], 0, 0, 0);
    }
    #pragma unroll
    for (int mi = 0; mi < 4; ++mi){
      int d0 = wd + mi*16 + l4*4;
      #pragma unroll
      for (int ni = 0; ni < 4; ++ni)
        store_bf4(&R3[(ni*16 + l15) * 264 + d0], acc[mi][ni]);
    }
  }
  __syncthreads();

  int h = w >> 1, tc = w & 1;
  {
    f32x4 s[4][2];
    #pragma unroll
    for (int i = 0; i < 4; ++i){ s[i][0] = f32x4{0.f,0.f,0.f,0.f}; s[i][1] = f32x4{0.f,0.f,0.f,0.f}; }
    #pragma unroll
    for (int ks = 0; ks < 4; ++ks){
      int k0 = h * 128 + ks * 32 + l4 * 8;
      bf16x8 a[4], bb[2];
      #pragma unroll
      for (int mi = 0; mi < 4; ++mi)
        a[mi] = *reinterpret_cast<const bf16x8*>(&R1[(mi*16 + l15) * 264 + k0]);
      #pragma unroll
      for (int ni = 0; ni < 2; ++ni)
        bb[ni] = *reinterpret_cast<const bf16x8*>(&R3[(tc*32 + ni*16 + l15) * 264 + k0]);
      #pragma unroll
      for (int mi = 0; mi < 4; ++mi)
        #pragma unroll
        for (int ni = 0; ni < 2; ++ni)
          s[mi][ni] = MFMA16(a[mi], bb[ni], s[mi][ni], 0, 0, 0);
    }
    __syncthreads();
    const float SCL = 0.08838834764831845f;
    unsigned short* P = R1;
    #pragma unroll
    for (int ni = 0; ni < 2; ++ni){
      float m = s[0][ni][0];
      #pragma unroll
      for (int mi = 0; mi < 4; ++mi)
        #pragma unroll
        for (int reg = 0; reg < 4; ++reg) m = fmaxf(m, s[mi][ni][reg]);
      m = fmaxf(m, __shfl_xor(m, 16));
      m = fmaxf(m, __shfl_xor(m, 32));
      float sum = 0.f;
      #pragma unroll
      for (int mi = 0; mi < 4; ++mi)
        #pragma unroll
        for (int reg = 0; reg < 4; ++reg){
          float e = __expf((s[mi][ni][reg] - m) * SCL);
          s[mi][ni][reg] = e; sum += e;
        }
      sum += __shfl_xor(sum, 16);
      sum += __shfl_xor(sum, 32);
      float rs = 1.0f / sum;
      int t = tc*32 + ni*16 + l15;
      #pragma unroll
      for (int mi = 0; mi < 4; ++mi){
        f32x4 pv;
        #pragma unroll
        for (int reg = 0; reg < 4; ++reg) pv[reg] = s[mi][ni][reg] * rs;
        store_bf4(&P[h * 4608 + t * 72 + mi*16 + l4*4], pv);
      }
    }
  }
  __syncthreads();
  {
    int wdh = h * 128 + tc * 64;
    f32x4 acc[4][4];
    #pragma unroll
    for (int i = 0; i < 4; ++i)
      #pragma unroll
      for (int j = 0; j < 4; ++j) acc[i][j] = f32x4{0.f,0.f,0.f,0.f};
    const unsigned short* P = R1;
    #pragma unroll
    for (int ks = 0; ks < 2; ++ks){
      int k0 = ks * 32 + l4 * 8;
      bf16x8 a[4], bb[4];
      #pragma unroll
      for (int mi = 0; mi < 4; ++mi)
        a[mi] = *reinterpret_cast<const bf16x8*>(&R2[(wdh + mi*16 + l15) * 72 + k0]);
      #pragma unroll
      for (int ni = 0; ni < 4; ++ni)
        bb[ni] = *reinterpret_cast<const bf16x8*>(&P[h * 4608 + (ni*16 + l15) * 72 + k0]);
      #pragma unroll
      for (int mi = 0; mi < 4; ++mi)
        #pragma unroll
        for (int ni = 0; ni < 4; ++ni)
          acc[mi][ni] = MFMA16(a[mi], bb[ni], acc[mi][ni], 0, 0, 0);
    }
    #pragma unroll
    for (int mi = 0; mi < 4; ++mi){
      int c0 = wdh + mi*16 + l4*4;
      #pragma unroll
      for (int ni = 0; ni < 4; ++ni)
        store_bf4(&R0[(ni*16 + l15) * 264 + c0], acc[mi][ni]);
    }
  }
  __syncthreads();
  {
    f32x4 acc[4][4];
    #pragma unroll
    for (int i = 0; i < 4; ++i)
      #pragma unroll
      for (int j = 0; j < 4; ++j) acc[i][j] = f32x4{0.f,0.f,0.f,0.f};
    #pragma unroll
    for (int ks = 0; ks < 8; ++ks){
      int k0 = ks * 32 + l4 * 8;
      bf16x8 a[4], bb[4];
      #pragma unroll
      for (int mi = 0; mi < 4; ++mi)
        a[mi] = *reinterpret_cast<const bf16x8*>(Wo + (size_t)((wd + mi*16 + l15) * 256 + k0));
      #pragma unroll
      for (int ni = 0; ni < 4; ++ni)
        bb[ni] = *reinterpret_cast<const bf16x8*>(&R0[(ni*16 + l15) * 264 + k0]);
      #pragma unroll
      for (int mi = 0; mi < 4; ++mi)
        #pragma unroll
        for (int ni = 0; ni < 4; ++ni)
          acc[mi][ni] = MFMA16(a[mi], bb[ni], acc[mi][ni], 0, 0, 0);
    }
    #pragma unroll
    for (int mi = 0; mi < 4; ++mi){
      #pragma unroll
      for (int ni = 0; ni < 4; ++ni){
        int t = ni*16 + l15, thi = t >> 3, twi = t & 7;
        size_t base = (size_t)(wd + mi*16 + l4*4) * g.HW + (size_t)thi * g.W + twi;
        #pragma unroll
        for (int reg = 0; reg < 4; ++reg){
          float res = xsrc[base + (size_t)reg * g.HW];
          float v = acc[mi][ni][reg] + res;
          outp[base + (size_t)reg * g.HW] = fmaxf(v, 0.f);
        }
      }
    }
  }
}

extern "C" void kernel_launch(void* const* d_in, const int* in_sizes, int n_in,
                              void* d_out, int out_size, void* d_ws, size_t ws_size,
                              hipStream_t stream) {
  (void)in_sizes; (void)n_in; (void)out_size;
  const float* f0 = (const float*)d_in[0];
  const float* f1 = (const float*)d_in[1];
  const float* f2 = (const float*)d_in[2];
  const float* f3 = (const float*)d_in[3];
  const float* w1 = (const float*)d_in[4];
  const float* w2 = (const float*)d_in[5];
  float* out = (float*)d_out;

  unsigned short* wbf = (unsigned short*)d_ws;
  const size_t WBF_B = 4194304;       // 2*16*65536 bf16
  const size_t FT_B  = 44564480;      // 87040 tokens * 256 * 2B
  const size_t need  = WBF_B + 2 * FT_B;   // 93,323,264

  wcvt_kernel<<<2048, 256, 0, stream>>>(w1, w2, wbf);

  if (ws_size >= need){
    char* base = (char*)d_ws + WBF_B;
    unsigned short* Ft = (unsigned short*)(base);
    unsigned short* Gt = (unsigned short*)(base + FT_B);

    xpose_kernel<<<5440, 256, 0, stream>>>(f0, f1, f2, f3, Ft);
    for (int phase = 0; phase < 2; ++phase)
      swin_win<<<680, 256, 0, stream>>>(Ft, Gt, wbf, Gt, phase);
    untrans_kernel<<<5440, 256, 0, stream>>>(Gt, out);
  } else {
    swin_phase<<<680, 256, 0, stream>>>(f0, f1, f2, f3, wbf, out, 0);
    swin_phase<<<680, 256, 0, stream>>>(f0, f1, f2, f3, wbf, out, 1);
  }
}

// Round 15
// 198.954 us; speedup vs baseline: 1.2307x; 1.0000x over previous
//
#include <hip/hip_runtime.h>

// Swin cross-attention pipeline v15 for MI355X.
// v15 = v14/v8 (confirmed 199us) with ONE low-risk delta: xpose/untrans
// raised from launch_bounds(256,2) to (256,4). These are short-bodied
// memory-latency kernels (4 loads + LDS transpose + 2 stores per thread,
// 16.6KB LDS) that were needlessly capped at 2 blocks/CU; 4 blocks/CU
// doubles outstanding-load parallelism. Register budget 64 is ample
// (~30-40 VGPR bodies). swin_win byte-identical to v8 (every structural
// neighbor measured and rejected in R9-R13).

using bf16x8 = __attribute__((ext_vector_type(8))) __bf16;
using f32x4  = __attribute__((ext_vector_type(4))) float;
using u16x4  = __attribute__((ext_vector_type(4))) unsigned short;
using u16x8  = __attribute__((ext_vector_type(8))) unsigned short;

__device__ __forceinline__ unsigned short f2bf(float f){
  unsigned int x = __float_as_uint(f);
  x += 0x7FFFu + ((x >> 16) & 1u);          // RNE
  return (unsigned short)(x >> 16);
}
__device__ __forceinline__ float bf2f(unsigned short u){
  return __uint_as_float((unsigned int)u << 16);
}
__device__ __forceinline__ void store_bf4(unsigned short* dst, f32x4 v){
  u16x4 o;
  o[0]=f2bf(v[0]); o[1]=f2bf(v[1]); o[2]=f2bf(v[2]); o[3]=f2bf(v[3]);
  *reinterpret_cast<u16x4*>(dst) = o;
}

#define MFMA16 __builtin_amdgcn_mfma_f32_16x16x32_bf16

__global__ void wcvt_kernel(const float* __restrict__ w1,
                            const float* __restrict__ w2,
                            unsigned short* __restrict__ dst){
  int i = blockIdx.x * 256 + threadIdx.x;
  const float4* src = (i < 262144) ? (reinterpret_cast<const float4*>(w1) + i)
                                   : (reinterpret_cast<const float4*>(w2) + (i - 262144));
  float4 v = *src;
  u16x4 o; o[0]=f2bf(v.x); o[1]=f2bf(v.y); o[2]=f2bf(v.z); o[3]=f2bf(v.w);
  reinterpret_cast<u16x4*>(dst)[i] = o;
}

// ---- transpose fp32 [C,HW] -> bf16 Ft[token][c] -----------------------------
__global__ __launch_bounds__(256, 4) void xpose_kernel(
    const float* __restrict__ g0, const float* __restrict__ g1,
    const float* __restrict__ g2, const float* __restrict__ g3,
    unsigned short* __restrict__ Ft)
{
  __shared__ float T[64][65];
  int bid = blockIdx.x;
  int r; const float* feat; int Hl; size_t tbase;
  if (bid < 4096){ r = bid;        feat = g0; Hl = 128; tbase = 0; }
  else if (bid < 5120){ r = bid - 4096; feat = g1; Hl = 64;  tbase = 65536; }
  else if (bid < 5376){ r = bid - 5120; feat = g2; Hl = 32;  tbase = 81920; }
  else { r = bid - 5376; feat = g3; Hl = 16;  tbase = 86016; }
  size_t HW = (size_t)Hl * Hl;
  int hw64 = (int)(HW >> 6);
  int bat = r / (4 * hw64);
  int r2 = r - bat * 4 * hw64;
  int ct = r2 / hw64, hwt = r2 - ct * hw64;

  const float* src = feat + (size_t)bat * HW * 256 + (size_t)(ct * 64) * HW + (size_t)hwt * 64;
  int tid = threadIdx.x;
  int cq = tid >> 4, hw0 = (tid & 15) * 4;
  #pragma unroll
  for (int p = 0; p < 4; ++p){
    int c = p * 16 + cq;
    const float* sp = src + (size_t)c * HW + hw0;
    float4 v = *reinterpret_cast<const float4*>(sp);
    T[c][hw0] = v.x; T[c][hw0+1] = v.y; T[c][hw0+2] = v.z; T[c][hw0+3] = v.w;
  }
  __syncthreads();
  unsigned short* dst = Ft + (tbase + (size_t)bat * HW + (size_t)hwt * 64) * 256 + ct * 64;
  #pragma unroll
  for (int p = 0; p < 2; ++p){
    int id = p * 256 + tid;
    int t = id >> 3, c0 = (id & 7) * 8;
    u16x8 o;
    #pragma unroll
    for (int j = 0; j < 8; ++j) o[j] = f2bf(T[c0 + j][t]);
    *reinterpret_cast<u16x8*>(dst + (size_t)t * 256 + c0) = o;
  }
}

// ---- transpose back: Gt[token][c] bf16 -> fp32 out [C,HW], ALL 4 batches ----
__global__ __launch_bounds__(256, 4) void untrans_kernel(
    const unsigned short* __restrict__ Gt, float* __restrict__ outb)
{
  __shared__ float T[64][65];
  int bid = blockIdx.x;
  int r; int Hl; size_t tbase, ooff;
  if (bid < 4096){ r = bid;        Hl = 128; tbase = 0;     ooff = 0; }
  else if (bid < 5120){ r = bid - 4096; Hl = 64; tbase = 65536; ooff = 16777216; }
  else if (bid < 5376){ r = bid - 5120; Hl = 32; tbase = 81920; ooff = 20971520; }
  else { r = bid - 5376; Hl = 16; tbase = 86016; ooff = 22020096; }
  size_t HW = (size_t)Hl * Hl;
  int hw64 = (int)(HW >> 6);
  int bat = r / (4 * hw64);
  int r2 = r - bat * 4 * hw64;
  int ct = r2 / hw64, hwt = r2 - ct * hw64;

  const unsigned short* src = Gt + (tbase + (size_t)bat * HW + (size_t)hwt * 64) * 256 + ct * 64;
  int tid = threadIdx.x;
  #pragma unroll
  for (int p = 0; p < 2; ++p){
    int id = p * 256 + tid;
    int t = id >> 3, c0 = (id & 7) * 8;
    u16x8 v = *reinterpret_cast<const u16x8*>(src + (size_t)t * 256 + c0);
    #pragma unroll
    for (int j = 0; j < 8; ++j) T[t][c0 + j] = bf2f(v[j]);
  }
  __syncthreads();
  float* dst = outb + ooff + (size_t)bat * HW * 256 + (size_t)(ct * 64) * HW + (size_t)hwt * 64;
  int cq = tid >> 4, hw0 = (tid & 15) * 4;
  #pragma unroll
  for (int p = 0; p < 4; ++p){
    int c = p * 16 + cq;
    float4 v;
    v.x = T[hw0][c]; v.y = T[hw0+1][c]; v.z = T[hw0+2][c]; v.w = T[hw0+3][c];
    *reinterpret_cast<float4*>(dst + (size_t)c * HW + hw0) = v;
  }
}

// ---- window geometry --------------------------------------------------------
struct WinGeo { int H, W, b, lvl; size_t HW, winoff, tbase, ooff; };

__device__ __forceinline__ WinGeo decode_win(int win){
  WinGeo g; int wloc;
  if (win < 512){ g.lvl = 0; wloc = win;      g.H = 128; g.tbase = 0;     g.ooff = 0; }
  else if (win < 640){ g.lvl = 1; wloc = win - 512; g.H = 64; g.tbase = 65536; g.ooff = 16777216; }
  else if (win < 672){ g.lvl = 2; wloc = win - 640; g.H = 32; g.tbase = 81920; g.ooff = 20971520; }
  else { g.lvl = 3; wloc = win - 672; g.H = 16; g.tbase = 86016; g.ooff = 22020096; }
  g.W = g.H; g.HW = (size_t)g.H * g.W;
  int nww = g.H >> 3, npb = nww * nww;
  g.b = wloc / npb;
  int r = wloc - g.b * npb;
  int wh = r / nww, ww = r - wh * nww;
  g.winoff = (size_t)(wh * 8) * g.W + (size_t)(ww * 8);
  return g;
}

// ---- v8: fully fused per-window kernel --------------------------------------
__global__ __launch_bounds__(256, 2) void swin_win(
    const unsigned short* __restrict__ Ft, const unsigned short* __restrict__ Gtin,
    const unsigned short* __restrict__ wball,
    unsigned short* __restrict__ Gt, int phase)
{
  __shared__ alignas(16) unsigned short A[64*264];   // K -> P -> O -> out
  __shared__ alignas(16) unsigned short B[256*72];   // Q ([64][264] view) -> V^T
  int win = blockIdx.x;
  WinGeo g = decode_win(win);
  int tid = threadIdx.x;
  int w = tid >> 6, l = tid & 63, l15 = l & 15, l4 = l >> 4, wd = w * 64;
  int h = w >> 1, tc = w & 1;

  int batx = (phase == 0) ? g.b : g.b + 2;
  const unsigned short* Sx = Ft + (g.tbase + (size_t)batx * g.HW) * 256;
  const unsigned short* Sy = (phase == 0)
      ? Ft + (g.tbase + (size_t)(g.b + 2) * g.HW) * 256
      : Gtin + (g.tbase + (size_t)g.b * g.HW) * 256;
  unsigned short* Gout = Gt + (g.tbase + (size_t)batx * g.HW) * 256;

  size_t rowo[4];
  #pragma unroll
  for (int ni = 0; ni < 4; ++ni){
    int t = ni * 16 + l15;
    rowo[ni] = ((size_t)g.winoff + (size_t)(t >> 3) * g.W + (t & 7)) * 256;
  }
  const unsigned short* Wbase = wball + ((size_t)(phase * 16 + g.lvl * 4) << 16);
  const unsigned short* Wq = Wbase;
  const unsigned short* Wk = Wbase + 65536;
  const unsigned short* Wv = Wbase + 131072;
  const unsigned short* Wo = Wbase + 196608;

  // ---- K & V GEMMs interleaved, shared Sy fragments (Sy read ONCE) ----
  f32x4 av[4][4];
  {
    f32x4 ak[4][4];
    #pragma unroll
    for (int i = 0; i < 4; ++i)
      #pragma unroll
      for (int j = 0; j < 4; ++j){ ak[i][j] = f32x4{0.f,0.f,0.f,0.f}; av[i][j] = f32x4{0.f,0.f,0.f,0.f}; }
    #pragma unroll
    for (int ks = 0; ks < 8; ++ks){
      int k0 = ks * 32 + l4 * 8;
      bf16x8 tf[4], kf[4], vf[4];
      #pragma unroll
      for (int i = 0; i < 4; ++i){
        tf[i] = *reinterpret_cast<const bf16x8*>(Sy + rowo[i] + k0);
        kf[i] = *reinterpret_cast<const bf16x8*>(Wk + (size_t)((wd + i*16 + l15) * 256 + k0));
        vf[i] = *reinterpret_cast<const bf16x8*>(Wv + (size_t)((wd + i*16 + l15) * 256 + k0));
      }
      __builtin_amdgcn_s_setprio(1);
      #pragma unroll
      for (int mi = 0; mi < 4; ++mi)
        #pragma unroll
        for (int ni = 0; ni < 4; ++ni){
          ak[mi][ni] = MFMA16(kf[mi], tf[ni], ak[mi][ni], 0, 0, 0);
          av[mi][ni] = MFMA16(tf[mi], vf[ni], av[mi][ni], 0, 0, 0);
        }
      __builtin_amdgcn_s_setprio(0);
    }
    // K[u][d] -> A
    #pragma unroll
    for (int mi = 0; mi < 4; ++mi){
      int d0 = wd + mi*16 + l4*4;
      #pragma unroll
      for (int ni = 0; ni < 4; ++ni)
        store_bf4(&A[(ni*16 + l15) * 264 + d0], ak[mi][ni]);
    }
  }
  // av stays live in registers until after S.

  // ---- Q GEMM -> B ([64][264] view) ----
  {
    f32x4 aq[4][4];
    #pragma unroll
    for (int i = 0; i < 4; ++i)
      #pragma unroll
      for (int j = 0; j < 4; ++j) aq[i][j] = f32x4{0.f,0.f,0.f,0.f};
    #pragma unroll
    for (int ks = 0; ks < 8; ++ks){
      int k0 = ks * 32 + l4 * 8;
      bf16x8 tf[4], wf[4];
      #pragma unroll
      for (int i = 0; i < 4; ++i){
        tf[i] = *reinterpret_cast<const bf16x8*>(Sx + rowo[i] + k0);
        wf[i] = *reinterpret_cast<const bf16x8*>(Wq + (size_t)((wd + i*16 + l15) * 256 + k0));
      }
      __builtin_amdgcn_s_setprio(1);
      #pragma unroll
      for (int mi = 0; mi < 4; ++mi)
        #pragma unroll
        for (int ni = 0; ni < 4; ++ni)
          aq[mi][ni] = MFMA16(wf[mi], tf[ni], aq[mi][ni], 0, 0, 0);
      __builtin_amdgcn_s_setprio(0);
    }
    #pragma unroll
    for (int mi = 0; mi < 4; ++mi){
      int d0 = wd + mi*16 + l4*4;
      #pragma unroll
      for (int ni = 0; ni < 4; ++ni)
        store_bf4(&B[(ni*16 + l15) * 264 + d0], aq[mi][ni]);
    }
  }
  __syncthreads();   // sync0: K(A), Q(B) visible

  // ---- S^T[u][t] per head from LDS K,Q ----
  f32x4 s[4][2];
  #pragma unroll
  for (int i = 0; i < 4; ++i){ s[i][0] = f32x4{0.f,0.f,0.f,0.f}; s[i][1] = f32x4{0.f,0.f,0.f,0.f}; }
  #pragma unroll
  for (int ks = 0; ks < 4; ++ks){
    int k0 = h * 128 + ks * 32 + l4 * 8;
    bf16x8 a[4], bb[2];
    #pragma unroll
    for (int mi = 0; mi < 4; ++mi)
      a[mi] = *reinterpret_cast<const bf16x8*>(&A[(mi*16 + l15) * 264 + k0]);
    #pragma unroll
    for (int ni = 0; ni < 2; ++ni)
      bb[ni] = *reinterpret_cast<const bf16x8*>(&B[(tc*32 + ni*16 + l15) * 264 + k0]);
    __builtin_amdgcn_s_setprio(1);
    #pragma unroll
    for (int mi = 0; mi < 4; ++mi)
      #pragma unroll
      for (int ni = 0; ni < 2; ++ni)
        s[mi][ni] = MFMA16(a[mi], bb[ni], s[mi][ni], 0, 0, 0);
    __builtin_amdgcn_s_setprio(0);
  }
  __syncthreads();   // sync1: K,Q reads done; A free for P, B free for V^T

  // ---- V^T (from registers) -> B ----
  #pragma unroll
  for (int mi = 0; mi < 4; ++mi){
    int u0 = mi*16 + l4*4;
    #pragma unroll
    for (int ni = 0; ni < 4; ++ni)
      store_bf4(&B[(wd + ni*16 + l15) * 72 + u0], av[mi][ni]);
  }

  // ---- softmax over u (per column t), P -> A ----
  const float SCL = 0.08838834764831845f;   // 1/sqrt(128)
  #pragma unroll
  for (int ni = 0; ni < 2; ++ni){
    float m = s[0][ni][0];
    #pragma unroll
    for (int mi = 0; mi < 4; ++mi)
      #pragma unroll
      for (int reg = 0; reg < 4; ++reg) m = fmaxf(m, s[mi][ni][reg]);
    m = fmaxf(m, __shfl_xor(m, 16));
    m = fmaxf(m, __shfl_xor(m, 32));
    float sum = 0.f;
    #pragma unroll
    for (int mi = 0; mi < 4; ++mi)
      #pragma unroll
      for (int reg = 0; reg < 4; ++reg){
        float e = __expf((s[mi][ni][reg] - m) * SCL);
        s[mi][ni][reg] = e; sum += e;
      }
    sum += __shfl_xor(sum, 16);
    sum += __shfl_xor(sum, 32);
    float rs = 1.0f / sum;
    int t = tc*32 + ni*16 + l15;
    #pragma unroll
    for (int mi = 0; mi < 4; ++mi){
      f32x4 pv;
      #pragma unroll
      for (int reg = 0; reg < 4; ++reg) pv[reg] = s[mi][ni][reg] * rs;
      store_bf4(&A[h * 4608 + t * 72 + mi*16 + l4*4], pv);
    }
  }
  __syncthreads();   // sync2: P(A), V^T(B) visible

  // ---- O^T[c][t] = V^T * P^T (both from LDS) ----
  f32x4 acc[4][4];
  #pragma unroll
  for (int i = 0; i < 4; ++i)
    #pragma unroll
    for (int j = 0; j < 4; ++j) acc[i][j] = f32x4{0.f,0.f,0.f,0.f};
  #pragma unroll
  for (int ks = 0; ks < 2; ++ks){
    int k0 = ks * 32 + l4 * 8;
    bf16x8 a[4], bb[4];
    #pragma unroll
    for (int mi = 0; mi < 4; ++mi)
      a[mi] = *reinterpret_cast<const bf16x8*>(&B[(wd + mi*16 + l15) * 72 + k0]);
    #pragma unroll
    for (int ni = 0; ni < 4; ++ni)
      bb[ni] = *reinterpret_cast<const bf16x8*>(&A[h * 4608 + (ni*16 + l15) * 72 + k0]);
    __builtin_amdgcn_s_setprio(1);
    #pragma unroll
    for (int mi = 0; mi < 4; ++mi)
      #pragma unroll
      for (int ni = 0; ni < 4; ++ni)
        acc[mi][ni] = MFMA16(a[mi], bb[ni], acc[mi][ni], 0, 0, 0);
    __builtin_amdgcn_s_setprio(0);
  }
  __syncthreads();   // sync3: P reads done; A free for O
  #pragma unroll
  for (int mi = 0; mi < 4; ++mi){
    int c0 = wd + mi*16 + l4*4;
    #pragma unroll
    for (int ni = 0; ni < 4; ++ni)
      store_bf4(&A[(ni*16 + l15) * 264 + c0], acc[mi][ni]);
  }
  __syncthreads();   // sync4: O(A) visible

  // ---- out^T = Wo * o^T ----
  #pragma unroll
  for (int i = 0; i < 4; ++i)
    #pragma unroll
    for (int j = 0; j < 4; ++j) acc[i][j] = f32x4{0.f,0.f,0.f,0.f};
  #pragma unroll
  for (int ks = 0; ks < 8; ++ks){
    int k0 = ks * 32 + l4 * 8;
    bf16x8 a[4], bb[4];
    #pragma unroll
    for (int mi = 0; mi < 4; ++mi)
      a[mi] = *reinterpret_cast<const bf16x8*>(Wo + (size_t)((wd + mi*16 + l15) * 256 + k0));
    #pragma unroll
    for (int ni = 0; ni < 4; ++ni)
      bb[ni] = *reinterpret_cast<const bf16x8*>(&A[(ni*16 + l15) * 264 + k0]);
    __builtin_amdgcn_s_setprio(1);
    #pragma unroll
    for (int mi = 0; mi < 4; ++mi)
      #pragma unroll
      for (int ni = 0; ni < 4; ++ni)
        acc[mi][ni] = MFMA16(a[mi], bb[ni], acc[mi][ni], 0, 0, 0);
    __builtin_amdgcn_s_setprio(0);
  }
  __syncthreads();   // sync5: O reads done; A free for out tile
  #pragma unroll
  for (int mi = 0; mi < 4; ++mi){
    int c0 = wd + mi*16 + l4*4;
    #pragma unroll
    for (int ni = 0; ni < 4; ++ni)
      store_bf4(&A[(ni*16 + l15) * 264 + c0], acc[mi][ni]);
  }
  __syncthreads();   // sync6: out(A) visible

  // ---- fused flush: out + residual, relu, 16B coalesced -> Gt ----
  #pragma unroll
  for (int p = 0; p < 8; ++p){
    int id = p * 256 + tid;
    int t = id >> 5, c = (id & 31) * 8;
    size_t ro = ((size_t)g.winoff + (size_t)(t >> 3) * g.W + (t & 7)) * 256 + c;
    u16x8 ov = *reinterpret_cast<const u16x8*>(&A[t * 264 + c]);
    u16x8 rv = *reinterpret_cast<const u16x8*>(Sx + ro);
    u16x8 o;
    #pragma unroll
    for (int j = 0; j < 8; ++j)
      o[j] = f2bf(fmaxf(bf2f(ov[j]) + bf2f(rv[j]), 0.f));
    *reinterpret_cast<u16x8*>(Gout + ro) = o;
  }
}

// ======================= round-1 fused fallback ==============================
__global__ __launch_bounds__(256, 1) void swin_phase(
    const float* __restrict__ g0, const float* __restrict__ g1,
    const float* __restrict__ g2, const float* __restrict__ g3,
    const unsigned short* __restrict__ wball,
    float* __restrict__ outb, int phase)
{
  __shared__ alignas(16) unsigned short R0[64*264];
  __shared__ alignas(16) unsigned short R1[64*264];
  __shared__ alignas(16) unsigned short R2[256*72];
  __shared__ alignas(16) unsigned short R3[64*264];

  int bid = blockIdx.x;
  WinGeo g = decode_win(bid);
  const float* feat = (g.lvl == 0) ? g0 : (g.lvl == 1) ? g1 : (g.lvl == 2) ? g2 : g3;
  size_t CHW = g.HW * 256;

  const float* xsrc; const float* ysrc; float* outp;
  if (phase == 0){
    xsrc = feat + (size_t)g.b * CHW + g.winoff;
    ysrc = feat + (size_t)(g.b + 2) * CHW + g.winoff;
    outp = outb + g.ooff + (size_t)g.b * CHW + g.winoff;
  } else {
    xsrc = feat + (size_t)(g.b + 2) * CHW + g.winoff;
    ysrc = outb + g.ooff + (size_t)g.b * CHW + g.winoff;
    outp = outb + g.ooff + (size_t)(g.b + 2) * CHW + g.winoff;
  }
  const unsigned short* Wq = wball + ((size_t)(phase * 16 + g.lvl * 4) << 16);
  const unsigned short* Wk = Wq + 65536;
  const unsigned short* Wv = Wq + 2 * 65536;
  const unsigned short* Wo = Wq + 3 * 65536;

  int tid = threadIdx.x;
  int w = tid >> 6, l = tid & 63, l15 = l & 15, l4 = l >> 4, wd = w * 64;
  int hi0 = l >> 3, wi0 = l & 7;

  {
    const float* p0 = ysrc + (size_t)hi0 * g.W + wi0;
    #pragma unroll
    for (int oc = 0; oc < 8; ++oc){
      int c0 = (oc * 4 + w) * 8;
      const float* p = p0 + (size_t)c0 * g.HW;
      u16x8 uv;
      #pragma unroll
      for (int j = 0; j < 8; ++j) uv[j] = f2bf(p[(size_t)j * g.HW]);
      *reinterpret_cast<u16x8*>(&R0[l * 264 + c0]) = uv;
    }
  }
  __syncthreads();
  {
    f32x4 acc[4][4];
    #pragma unroll
    for (int i = 0; i < 4; ++i)
      #pragma unroll
      for (int j = 0; j < 4; ++j) acc[i][j] = f32x4{0.f,0.f,0.f,0.f};
    #pragma unroll
    for (int ks = 0; ks < 8; ++ks){
      int k0 = ks * 32 + l4 * 8;
      bf16x8 a[4], bb[4];
      #pragma unroll
      for (int mi = 0; mi < 4; ++mi)
        a[mi] = *reinterpret_cast<const bf16x8*>(Wk + (size_t)((wd + mi*16 + l15) * 256 + k0));
      #pragma unroll
      for (int ni = 0; ni < 4; ++ni)
        bb[ni] = *reinterpret_cast<const bf16x8*>(&R0[(ni*16 + l15) * 264 + k0]);
      #pragma unroll
      for (int mi = 0; mi < 4; ++mi)
        #pragma unroll
        for (int ni = 0; ni < 4; ++ni)
          acc[mi][ni] = MFMA16(a[mi], bb[ni], acc[mi][ni], 0, 0, 0);
    }
    #pragma unroll
    for (int mi = 0; mi < 4; ++mi){
      int d0 = wd + mi*16 + l4*4;
      #pragma unroll
      for (int ni = 0; ni < 4; ++ni)
        store_bf4(&R1[(ni*16 + l15) * 264 + d0], acc[mi][ni]);
    }
  }
  {
    f32x4 acc[4][4];
    #pragma unroll
    for (int i = 0; i < 4; ++i)
      #pragma unroll
      for (int j = 0; j < 4; ++j) acc[i][j] = f32x4{0.f,0.f,0.f,0.f};
    #pragma unroll
    for (int ks = 0; ks < 8; ++ks){
      int k0 = ks * 32 + l4 * 8;
      bf16x8 a[4], bb[4];
      #pragma unroll
      for (int mi = 0; mi < 4; ++mi)
        a[mi] = *reinterpret_cast<const bf16x8*>(&R0[(mi*16 + l15) * 264 + k0]);
      #pragma unroll
      for (int ni = 0; ni < 4; ++ni)
        bb[ni] = *reinterpret_cast<const bf16x8*>(Wv + (size_t)((wd + ni*16 + l15) * 256 + k0));
      #pragma unroll
      for (int mi = 0; mi < 4; ++mi)
        #pragma unroll
        for (int ni = 0; ni < 4; ++ni)
          acc[mi][ni] = MFMA16(a[mi], bb[ni], acc[mi][ni], 0, 0, 0);
    }
    #pragma unroll
    for (int mi = 0; mi < 4; ++mi){
      int u0 = mi*16 + l4*4;
      #pragma unroll
      for (int ni = 0; ni < 4; ++ni)
        store_bf4(&R2[(wd + ni*16 + l15) * 72 + u0], acc[mi][ni]);
    }
  }
  __syncthreads();
  {
    const float* p0 = xsrc + (size_t)hi0 * g.W + wi0;
    #pragma unroll
    for (int oc = 0; oc < 8; ++oc){
      int c0 = (oc * 4 + w) * 8;
      const float* p = p0 + (size_t)c0 * g.HW;
      u16x8 uv;
      #pragma unroll
      for (int j = 0; j < 8; ++j) uv[j] = f2bf(p[(size_t)j * g.HW]);
      *reinterpret_cast<u16x8*>(&R0[l * 264 + c0]) = uv;
    }
  }
  __syncthreads();
  {
    f32x4 acc[4][4];
    #pragma unroll
    for (int i = 0; i < 4; ++i)
      #pragma unroll
      for (int j = 0; j < 4; ++j) acc[i][j] = f32x4{0.f,0.f,0.f,0.f};
    #pragma unroll
    for (int ks = 0; ks < 8; ++ks){
      int k0 = ks * 32 + l4 * 8;
      bf16x8 a[4], bb[4];
      #pragma unroll
      for (int mi = 0; mi < 4; ++mi)
        a[mi] = *reinterpret_cast<const bf16x8*>(Wq + (size_t)((wd + mi*16 + l15) * 256 + k0));
      #pragma unroll
      for (int ni = 0; ni < 4; ++ni)
        bb[ni] = *reinterpret_cast<const bf16x8*>(&R0[(ni*16 + l15) * 264 + k0]);
      #pragma unroll
      for (int mi = 0; mi < 4; ++mi)
        #pragma unroll
        for (int ni = 0; ni < 4; ++ni)
          acc[mi][ni] = MFMA16(a[mi], bb[ni], acc[mi][ni], 0, 0, 0);
    }
    #pragma unroll
    for (int mi = 0; mi < 4; ++mi){
      int d0 = wd + mi*16 + l4*4;
      #pragma unroll
      for (int ni = 0; ni < 4; ++ni)
        store_bf4(&R3[(ni*16 + l15) * 264 + d0], acc[mi][ni]);
    }
  }
  __syncthreads();

  int h = w >> 1, tc = w & 1;
  {
    f32x4 s[4][2];
    #pragma unroll
    for (int i = 0; i < 4; ++i){ s[i][0] = f32x4{0.f,0.f,0.f,0.f}; s[i][1] = f32x4{0.f,0.f,0.f,0.f}; }
    #pragma unroll
    for (int ks = 0; ks < 4; ++ks){
      int k0 = h * 128 + ks * 32 + l4 * 8;
      bf16x8 a[4], bb[2];
      #pragma unroll
      for (int mi = 0; mi < 4; ++mi)
        a[mi] = *reinterpret_cast<const bf16x8*>(&R1[(mi*16 + l15) * 264 + k0]);
      #pragma unroll
      for (int ni = 0; ni < 2; ++ni)
        bb[ni] = *reinterpret_cast<const bf16x8*>(&R3[(tc*32 + ni*16 + l15) * 264 + k0]);
      #pragma unroll
      for (int mi = 0; mi < 4; ++mi)
        #pragma unroll
        for (int ni = 0; ni < 2; ++ni)
          s[mi][ni] = MFMA16(a[mi], bb[ni], s[mi][ni], 0, 0, 0);
    }
    __syncthreads();
    const float SCL = 0.08838834764831845f;
    unsigned short* P = R1;
    #pragma unroll
    for (int ni = 0; ni < 2; ++ni){
      float m = s[0][ni][0];
      #pragma unroll
      for (int mi = 0; mi < 4; ++mi)
        #pragma unroll
        for (int reg = 0; reg < 4; ++reg) m = fmaxf(m, s[mi][ni][reg]);
      m = fmaxf(m, __shfl_xor(m, 16));
      m = fmaxf(m, __shfl_xor(m, 32));
      float sum = 0.f;
      #pragma unroll
      for (int mi = 0; mi < 4; ++mi)
        #pragma unroll
        for (int reg = 0; reg < 4; ++reg){
          float e = __expf((s[mi][ni][reg] - m) * SCL);
          s[mi][ni][reg] = e; sum += e;
        }
      sum += __shfl_xor(sum, 16);
      sum += __shfl_xor(sum, 32);
      float rs = 1.0f / sum;
      int t = tc*32 + ni*16 + l15;
      #pragma unroll
      for (int mi = 0; mi < 4; ++mi){
        f32x4 pv;
        #pragma unroll
        for (int reg = 0; reg < 4; ++reg) pv[reg] = s[mi][ni][reg] * rs;
        store_bf4(&P[h * 4608 + t * 72 + mi*16 + l4*4], pv);
      }
    }
  }
  __syncthreads();
  {
    int wdh = h * 128 + tc * 64;
    f32x4 acc[4][4];
    #pragma unroll
    for (int i = 0; i < 4; ++i)
      #pragma unroll
      for (int j = 0; j < 4; ++j) acc[i][j] = f32x4{0.f,0.f,0.f,0.f};
    const unsigned short* P = R1;
    #pragma unroll
    for (int ks = 0; ks < 2; ++ks){
      int k0 = ks * 32 + l4 * 8;
      bf16x8 a[4], bb[4];
      #pragma unroll
      for (int mi = 0; mi < 4; ++mi)
        a[mi] = *reinterpret_cast<const bf16x8*>(&R2[(wdh + mi*16 + l15) * 72 + k0]);
      #pragma unroll
      for (int ni = 0; ni < 4; ++ni)
        bb[ni] = *reinterpret_cast<const bf16x8*>(&P[h * 4608 + (ni*16 + l15) * 72 + k0]);
      #pragma unroll
      for (int mi = 0; mi < 4; ++mi)
        #pragma unroll
        for (int ni = 0; ni < 4; ++ni)
          acc[mi][ni] = MFMA16(a[mi], bb[ni], acc[mi][ni], 0, 0, 0);
    }
    #pragma unroll
    for (int mi = 0; mi < 4; ++mi){
      int c0 = wdh + mi*16 + l4*4;
      #pragma unroll
      for (int ni = 0; ni < 4; ++ni)
        store_bf4(&R0[(ni*16 + l15) * 264 + c0], acc[mi][ni]);
    }
  }
  __syncthreads();
  {
    f32x4 acc[4][4];
    #pragma unroll
    for (int i = 0; i < 4; ++i)
      #pragma unroll
      for (int j = 0; j < 4; ++j) acc[i][j] = f32x4{0.f,0.f,0.f,0.f};
    #pragma unroll
    for (int ks = 0; ks < 8; ++ks){
      int k0 = ks * 32 + l4 * 8;
      bf16x8 a[4], bb[4];
      #pragma unroll
      for (int mi = 0; mi < 4; ++mi)
        a[mi] = *reinterpret_cast<const bf16x8*>(Wo + (size_t)((wd + mi*16 + l15) * 256 + k0));
      #pragma unroll
      for (int ni = 0; ni < 4; ++ni)
        bb[ni] = *reinterpret_cast<const bf16x8*>(&R0[(ni*16 + l15) * 264 + k0]);
      #pragma unroll
      for (int mi = 0; mi < 4; ++mi)
        #pragma unroll
        for (int ni = 0; ni < 4; ++ni)
          acc[mi][ni] = MFMA16(a[mi], bb[ni], acc[mi][ni], 0, 0, 0);
    }
    #pragma unroll
    for (int mi = 0; mi < 4; ++mi){
      #pragma unroll
      for (int ni = 0; ni < 4; ++ni){
        int t = ni*16 + l15, thi = t >> 3, twi = t & 7;
        size_t base = (size_t)(wd + mi*16 + l4*4) * g.HW + (size_t)thi * g.W + twi;
        #pragma unroll
        for (int reg = 0; reg < 4; ++reg){
          float res = xsrc[base + (size_t)reg * g.HW];
          float v = acc[mi][ni][reg] + res;
          outp[base + (size_t)reg * g.HW] = fmaxf(v, 0.f);
        }
      }
    }
  }
}

extern "C" void kernel_launch(void* const* d_in, const int* in_sizes, int n_in,
                              void* d_out, int out_size, void* d_ws, size_t ws_size,
                              hipStream_t stream) {
  (void)in_sizes; (void)n_in; (void)out_size;
  const float* f0 = (const float*)d_in[0];
  const float* f1 = (const float*)d_in[1];
  const float* f2 = (const float*)d_in[2];
  const float* f3 = (const float*)d_in[3];
  const float* w1 = (const float*)d_in[4];
  const float* w2 = (const float*)d_in[5];
  float* out = (float*)d_out;

  unsigned short* wbf = (unsigned short*)d_ws;
  const size_t WBF_B = 4194304;       // 2*16*65536 bf16
  const size_t FT_B  = 44564480;      // 87040 tokens * 256 * 2B
  const size_t need  = WBF_B + 2 * FT_B;   // 93,323,264

  wcvt_kernel<<<2048, 256, 0, stream>>>(w1, w2, wbf);

  if (ws_size >= need){
    char* base = (char*)d_ws + WBF_B;
    unsigned short* Ft = (unsigned short*)(base);
    unsigned short* Gt = (unsigned short*)(base + FT_B);

    xpose_kernel<<<5440, 256, 0, stream>>>(f0, f1, f2, f3, Ft);
    for (int phase = 0; phase < 2; ++phase)
      swin_win<<<680, 256, 0, stream>>>(Ft, Gt, wbf, Gt, phase);
    untrans_kernel<<<5440, 256, 0, stream>>>(Gt, out);
  } else {
    swin_phase<<<680, 256, 0, stream>>>(f0, f1, f2, f3, wbf, out, 0);
    swin_phase<<<680, 256, 0, stream>>>(f0, f1, f2, f3, wbf, out, 1);
  }
}